// Round 1
// 1121.549 us; speedup vs baseline: 1.1202x; 1.1202x over previous
//
#include <hip/hip_runtime.h>
#include <hip/hip_bf16.h>
#include <cmath>

using bf16 = __hip_bfloat16;
typedef __bf16 v8bf __attribute__((ext_vector_type(8)));
typedef float  v4f  __attribute__((ext_vector_type(4)));

__device__ __forceinline__ float bf2f(bf16 x) { return __bfloat162float(x); }
__device__ __forceinline__ bf16  f2bf(float x) { return __float2bfloat16(x); }

// async global->LDS, 16B per lane (lds dest = wave-uniform base + lane*16)
__device__ __forceinline__ void gll16(const bf16* g, bf16* l) {
    __builtin_amdgcn_global_load_lds(
        (const __attribute__((address_space(1))) unsigned int*)g,
        (__attribute__((address_space(3))) unsigned int*)l, 16, 0, 0);
}

__device__ __forceinline__ float ldin(const void* p, size_t i, int isf32) {
    if (isf32) return ((const float*)p)[i];
    return bf2f(((const bf16*)p)[i]);
}

__device__ __forceinline__ float wave_sum(float v) {
#pragma unroll
    for (int o = 32; o > 0; o >>= 1) v += __shfl_xor(v, o, 64);
    return v;
}
__device__ __forceinline__ float wave_max(float v) {
#pragma unroll
    for (int o = 32; o > 0; o >>= 1) v = fmaxf(v, __shfl_xor(v, o, 64));
    return v;
}
__device__ __forceinline__ float block_sum(float v, float* sm) {
    v = wave_sum(v);
    int lane = threadIdx.x & 63, w = threadIdx.x >> 6;
    __syncthreads();
    if (lane == 0) sm[w] = v;
    __syncthreads();
    return (sm[0] + sm[1]) + (sm[2] + sm[3]);
}
__device__ __forceinline__ float block_max(float v, float* sm) {
    v = wave_max(v);
    int lane = threadIdx.x & 63, w = threadIdx.x >> 6;
    __syncthreads();
    if (lane == 0) sm[w] = v;
    __syncthreads();
    return fmaxf(fmaxf(sm[0], sm[1]), fmaxf(sm[2], sm[3]));
}

// ---------------- dtype detector -------------------------------------------
__global__ void detect_k(const unsigned short* __restrict__ x, int* __restrict__ flag)
{
    __shared__ int s;
    int t = threadIdx.x;
    if (t == 0) s = 0;
    __syncthreads();
    int bad = 0;
    for (int i = t; i < 4096; i += 256) {
        int e = (x[i] >> 7) & 0xFF;
        if (e >= 147) bad++;
    }
    atomicAdd(&s, bad);
    __syncthreads();
    if (t == 0) *flag = (s > 64) ? 1 : 0;
}

// ---------------- MFMA GEMM 128x128 (async LDS staging) ----------------------
__global__ __launch_bounds__(256)
void gemm_bt(const bf16* __restrict__ A, const bf16* __restrict__ BT,
             bf16* __restrict__ C, int M, int N, int K, int lda)
{
    __shared__ bf16 As[128 * 32];
    __shared__ bf16 Bs[128 * 32];
    const int t = threadIdx.x;
    const int lane = t & 63;
    const int wave = t >> 6;
    const int wm = (wave >> 1) * 64;
    const int wn = (wave & 1) * 64;
    const int bm = blockIdx.x * 128;
    const int bn = blockIdx.y * 128;
    const int fr = lane & 15;
    const int fk = (lane >> 4) * 8;

    v4f acc[4][4];
#pragma unroll
    for (int i = 0; i < 4; ++i)
#pragma unroll
        for (int j = 0; j < 4; ++j) { v4f z = {0.f, 0.f, 0.f, 0.f}; acc[i][j] = z; }

    for (int k0 = 0; k0 < K; k0 += 32) {
#pragma unroll
        for (int r = 0; r < 2; ++r) {
            int c = t + 256 * r;
            int row = c >> 2;
            int koff = (c & 3) * 8;
            gll16(A + (size_t)(bm + row) * lda + k0 + koff, &As[c * 8]);
            gll16(BT + (size_t)(bn + row) * K + k0 + koff, &Bs[c * 8]);
        }
        __syncthreads();
        v8bf af[4], bfr[4];
#pragma unroll
        for (int mt = 0; mt < 4; ++mt)
            af[mt] = *(const v8bf*)(&As[(wm + mt * 16 + fr) * 32 + fk]);
#pragma unroll
        for (int nt = 0; nt < 4; ++nt)
            bfr[nt] = *(const v8bf*)(&Bs[(wn + nt * 16 + fr) * 32 + fk]);
#pragma unroll
        for (int mt = 0; mt < 4; ++mt)
#pragma unroll
            for (int nt = 0; nt < 4; ++nt)
                acc[mt][nt] = __builtin_amdgcn_mfma_f32_16x16x32_bf16(
                    af[mt], bfr[nt], acc[mt][nt], 0, 0, 0);
        __syncthreads();
    }
    const int r0 = (lane >> 4) * 4;
#pragma unroll
    for (int mt = 0; mt < 4; ++mt)
#pragma unroll
        for (int nt = 0; nt < 4; ++nt)
#pragma unroll
            for (int r = 0; r < 4; ++r) {
                int row = bm + wm + mt * 16 + r0 + r;
                int col = bn + wn + nt * 16 + fr;
                C[(size_t)row * N + col] = f2bf(acc[mt][nt][r]);
            }
}

// ---------------- MFMA GEMM 64x128 tile (async LDS staging) ------------------
__global__ __launch_bounds__(256)
void gemm64(const bf16* __restrict__ A, const bf16* __restrict__ BT,
            bf16* __restrict__ C, int M, int N, int K, int lda)
{
    __shared__ bf16 As[64 * 32];
    __shared__ bf16 Bs[128 * 32];
    const int t = threadIdx.x;
    const int lane = t & 63;
    const int wave = t >> 6;
    const int wm = (wave >> 1) * 32;
    const int wn = (wave & 1) * 64;
    const int bm = blockIdx.x * 64;
    const int bn = blockIdx.y * 128;
    const int fr = lane & 15;
    const int fk = (lane >> 4) * 8;

    v4f acc[2][4];
#pragma unroll
    for (int i = 0; i < 2; ++i)
#pragma unroll
        for (int j = 0; j < 4; ++j) { v4f z = {0.f, 0.f, 0.f, 0.f}; acc[i][j] = z; }

    for (int k0 = 0; k0 < K; k0 += 32) {
        {
            int row = t >> 2, koff = (t & 3) * 8;
            gll16(A + (size_t)(bm + row) * lda + k0 + koff, &As[t * 8]);
        }
#pragma unroll
        for (int r = 0; r < 2; ++r) {
            int c = t + 256 * r;
            int row = c >> 2, koff = (c & 3) * 8;
            gll16(BT + (size_t)(bn + row) * K + k0 + koff, &Bs[c * 8]);
        }
        __syncthreads();
        v8bf af[2], bfr[4];
#pragma unroll
        for (int mt = 0; mt < 2; ++mt)
            af[mt] = *(const v8bf*)(&As[(wm + mt * 16 + fr) * 32 + fk]);
#pragma unroll
        for (int nt = 0; nt < 4; ++nt)
            bfr[nt] = *(const v8bf*)(&Bs[(wn + nt * 16 + fr) * 32 + fk]);
#pragma unroll
        for (int mt = 0; mt < 2; ++mt)
#pragma unroll
            for (int nt = 0; nt < 4; ++nt)
                acc[mt][nt] = __builtin_amdgcn_mfma_f32_16x16x32_bf16(
                    af[mt], bfr[nt], acc[mt][nt], 0, 0, 0);
        __syncthreads();
    }
    const int r0 = (lane >> 4) * 4;
#pragma unroll
    for (int mt = 0; mt < 2; ++mt)
#pragma unroll
        for (int nt = 0; nt < 4; ++nt)
#pragma unroll
            for (int r = 0; r < 4; ++r) {
                int row = bm + wm + mt * 16 + r0 + r;
                int col = bn + wn + nt * 16 + fr;
                C[(size_t)row * N + col] = f2bf(acc[mt][nt][r]);
            }
}

// ---- gemm64 with flag-selected output dtype (final projection) --------------
__global__ __launch_bounds__(256)
void gemm64_out(const bf16* __restrict__ A, const bf16* __restrict__ BT,
                void* __restrict__ C, int M, int N, int K, int lda,
                const int* __restrict__ flag)
{
    __shared__ bf16 As[64 * 32];
    __shared__ bf16 Bs[128 * 32];
    const int f = *flag;
    const int t = threadIdx.x;
    const int lane = t & 63;
    const int wave = t >> 6;
    const int wm = (wave >> 1) * 32;
    const int wn = (wave & 1) * 64;
    const int bm = blockIdx.x * 64;
    const int bn = blockIdx.y * 128;
    const int fr = lane & 15;
    const int fk = (lane >> 4) * 8;

    v4f acc[2][4];
#pragma unroll
    for (int i = 0; i < 2; ++i)
#pragma unroll
        for (int j = 0; j < 4; ++j) { v4f z = {0.f, 0.f, 0.f, 0.f}; acc[i][j] = z; }

    for (int k0 = 0; k0 < K; k0 += 32) {
        {
            int row = t >> 2, koff = (t & 3) * 8;
            gll16(A + (size_t)(bm + row) * lda + k0 + koff, &As[t * 8]);
        }
#pragma unroll
        for (int r = 0; r < 2; ++r) {
            int c = t + 256 * r;
            int row = c >> 2, koff = (c & 3) * 8;
            gll16(BT + (size_t)(bn + row) * K + k0 + koff, &Bs[c * 8]);
        }
        __syncthreads();
        v8bf af[2], bfr[4];
#pragma unroll
        for (int mt = 0; mt < 2; ++mt)
            af[mt] = *(const v8bf*)(&As[(wm + mt * 16 + fr) * 32 + fk]);
#pragma unroll
        for (int nt = 0; nt < 4; ++nt)
            bfr[nt] = *(const v8bf*)(&Bs[(wn + nt * 16 + fr) * 32 + fk]);
#pragma unroll
        for (int mt = 0; mt < 2; ++mt)
#pragma unroll
            for (int nt = 0; nt < 4; ++nt)
                acc[mt][nt] = __builtin_amdgcn_mfma_f32_16x16x32_bf16(
                    af[mt], bfr[nt], acc[mt][nt], 0, 0, 0);
        __syncthreads();
    }
    const int r0 = (lane >> 4) * 4;
#pragma unroll
    for (int mt = 0; mt < 2; ++mt)
#pragma unroll
        for (int nt = 0; nt < 4; ++nt)
#pragma unroll
            for (int r = 0; r < 4; ++r) {
                int row = bm + wm + mt * 16 + r0 + r;
                int col = bn + wn + nt * 16 + fr;
                if (f) ((float*)C)[(size_t)row * N + col] = acc[mt][nt][r];
                else   ((bf16*)C)[(size_t)row * N + col] = f2bf(acc[mt][nt][r]);
            }
}

// ---------------- transpose w/ separate z-strides ----------------------------
__global__ __launch_bounds__(256)
void transpose2_k(const void* __restrict__ in, bf16* __restrict__ out, int R, int C,
                  size_t inZ, size_t outZ, const int* __restrict__ flag)
{
    __shared__ bf16 tile[32][33];
    int f = *flag;
    size_t ioff = (size_t)blockIdx.z * inZ;
    bf16* dst = out + (size_t)blockIdx.z * outZ;
    int c0 = blockIdx.x * 32, r0 = blockIdx.y * 32;
    int tx = threadIdx.x, ty = threadIdx.y;
#pragma unroll
    for (int i = 0; i < 32; i += 8)
        tile[ty + i][tx] = f2bf(ldin(in, ioff + (size_t)(r0 + ty + i) * C + c0 + tx, f));
    __syncthreads();
#pragma unroll
    for (int i = 0; i < 32; i += 8)
        dst[(size_t)(c0 + ty + i) * R + r0 + tx] = tile[tx][ty + i];
}

// ---------------- x = in; xn = LN(x)*g --------------------------------------
__global__ __launch_bounds__(256)
void xinit_ln_k(const void* __restrict__ in, const void* __restrict__ g,
                const int* __restrict__ flag, float* __restrict__ x, bf16* __restrict__ xn)
{
    __shared__ float sm[4];
    int f = *flag;
    int row = blockIdx.x, t = threadIdx.x;
    float v0 = ldin(in, (size_t)row * 512 + t, f);
    float v1 = ldin(in, (size_t)row * 512 + t + 256, f);
    x[(size_t)row * 512 + t] = v0;
    x[(size_t)row * 512 + t + 256] = v1;
    float mean = block_sum(v0 + v1, sm) * (1.f / 512.f);
    float d0 = v0 - mean, d1 = v1 - mean;
    float var = block_sum(d0 * d0 + d1 * d1, sm) * (1.f / 512.f);
    float rstd = rsqrtf(var + 1e-5f);
    xn[(size_t)row * 512 + t]       = f2bf(d0 * rstd * ldin(g, t, f));
    xn[(size_t)row * 512 + t + 256] = f2bf(d1 * rstd * ldin(g, t + 256, f));
}

// ---------------- x += LN(t)*g1 ; xn = LN(x)*g2 ------------------------------
__global__ __launch_bounds__(256)
void addln_ln_k(const bf16* __restrict__ tin, const void* __restrict__ g1, int g1off,
                const void* __restrict__ g2, int g2off, const int* __restrict__ flag,
                float* __restrict__ x, bf16* __restrict__ xn)
{
    __shared__ float sm[4];
    int f = *flag;
    int row = blockIdx.x, t = threadIdx.x;
    const bf16* tr = tin + (size_t)row * 512;
    float v0 = bf2f(tr[t]), v1 = bf2f(tr[t + 256]);
    float mean = block_sum(v0 + v1, sm) * (1.f / 512.f);
    float d0 = v0 - mean, d1 = v1 - mean;
    float var = block_sum(d0 * d0 + d1 * d1, sm) * (1.f / 512.f);
    float rstd = rsqrtf(var + 1e-5f);
    float nx0 = x[(size_t)row * 512 + t]       + d0 * rstd * ldin(g1, g1off + t, f);
    float nx1 = x[(size_t)row * 512 + t + 256] + d1 * rstd * ldin(g1, g1off + t + 256, f);
    x[(size_t)row * 512 + t]       = nx0;
    x[(size_t)row * 512 + t + 256] = nx1;
    float mean2 = block_sum(nx0 + nx1, sm) * (1.f / 512.f);
    float e0 = nx0 - mean2, e1 = nx1 - mean2;
    float var2 = block_sum(e0 * e0 + e1 * e1, sm) * (1.f / 512.f);
    float rstd2 = rsqrtf(var2 + 1e-5f);
    xn[(size_t)row * 512 + t]       = f2bf(e0 * rstd2 * ldin(g2, g2off + t, f));
    xn[(size_t)row * 512 + t + 256] = f2bf(e1 * rstd2 * ldin(g2, g2off + t + 256, f));
}

// ---------------- x += t ; xn = (stable? stableLN : LN)(x)*g -----------------
__global__ __launch_bounds__(256)
void add_ln_k(const bf16* __restrict__ tin, const void* __restrict__ g, int goff,
              const int* __restrict__ flag, int stable,
              float* __restrict__ x, bf16* __restrict__ xn)
{
    __shared__ float sm[4];
    int f = *flag;
    int row = blockIdx.x, t = threadIdx.x;
    float nx0 = x[(size_t)row * 512 + t]       + bf2f(tin[(size_t)row * 512 + t]);
    float nx1 = x[(size_t)row * 512 + t + 256] + bf2f(tin[(size_t)row * 512 + t + 256]);
    x[(size_t)row * 512 + t]       = nx0;
    x[(size_t)row * 512 + t + 256] = nx1;
    float v0 = nx0, v1 = nx1;
    if (stable) {
        float mx = block_max(fmaxf(v0, v1), sm);
        v0 /= mx; v1 /= mx;
    }
    float mean = block_sum(v0 + v1, sm) * (1.f / 512.f);
    float d0 = v0 - mean, d1 = v1 - mean;
    float var = block_sum(d0 * d0 + d1 * d1, sm) * (1.f / 512.f);
    float rstd = rsqrtf(var + 1e-5f);
    xn[(size_t)row * 512 + t]       = f2bf(d0 * rstd * ldin(g, goff + t, f));
    xn[(size_t)row * 512 + t + 256] = f2bf(d1 * rstd * ldin(g, goff + t + 256, f));
}

// ---------------- silu gate --------------------------------------------------
__global__ __launch_bounds__(256)
void silu_k(bf16* __restrict__ u)
{
    size_t i = (size_t)blockIdx.x * 256 + threadIdx.x;
    size_t r = i >> 11;
    int c = (int)(i & 2047);
    float a = bf2f(u[r * 4096 + c]);
    float gg = bf2f(u[r * 4096 + 2048 + c]);
    u[r * 4096 + c] = f2bf(a * (gg / (1.f + expf(-gg))));
}

// ---------------- rel-pos bias table (pre-offset by -16: fixed softmax max) --
// qn,kn are l2-normalized to norm 4 => s = qn.kn <= 16 (Cauchy-Schwarz), and
// |bias| << 1, so exp(s + bias - 16) <= ~1.11. Softmax is shift-invariant, so
// folding the -16 here lets attention skip online-max tracking entirely.
__global__ __launch_bounds__(256)
void bias_k(const void* __restrict__ rpe, const int* __restrict__ flag, float* __restrict__ tab)
{
    int f = *flag;
    int idx = blockIdx.x * 256 + threadIdx.x;
    if (idx >= 8 * 1025) return;
    int h = idx / 1025, dist = idx % 1025;
    int bkt;
    if (dist < 16) bkt = dist;
    else {
        bkt = 16 + (int)(logf((float)dist / 16.f) / logf(8.f) * 16.f);
        if (bkt > 31) bkt = 31;
    }
    tab[idx] = ldin(rpe, bkt * 8 + h, f) - 16.f;
}

// ---------------- q prep (qkv stride 640) ------------------------------------
__global__ __launch_bounds__(256)
void qprep_k(const bf16* __restrict__ qkv, bf16* __restrict__ Q)
{
    int rid = blockIdx.x * 4 + (threadIdx.x >> 6);
    int lane = threadIdx.x & 63;
    int h = rid & 7;
    int n = (rid >> 3) & 1023;
    int b = rid >> 13;
    float v = bf2f(qkv[(size_t)((b << 10) | n) * 640 + h * 64 + lane]) * 16.f;
    if (lane < 32) {
        int p = lane >> 1;
        float ang = (float)n * expf((float)p * -0.5756462732f);
        float c = cosf(ang), s = sinf(ang);
        float other = __shfl_xor(v, 1, 64);
        float rot = (lane & 1) ? other : -other;
        v = v * c + rot * s;
    }
    float nrm = sqrtf(wave_sum(v * v));
    v = v / fmaxf(nrm, 1e-12f) * 4.f;
    Q[(((size_t)(b * 8 + h)) * 1024 + n) * 64 + lane] = f2bf(v);
}

// ---- k/v prep (qkv stride 640): K[b][j][d], Vt[b][d][j]; zero pad j>=1025 ---
__global__ __launch_bounds__(256)
void kvprep_k(const bf16* __restrict__ qkv, const void* __restrict__ nkv, int nkoff,
              const int* __restrict__ flag, bf16* __restrict__ K, bf16* __restrict__ Vt)
{
    int f = *flag;
    int rid = blockIdx.x * 4 + (threadIdx.x >> 6);
    if (rid >= 4 * 1088) return;
    int lane = threadIdx.x & 63;
    int j = rid % 1088;
    int b = rid / 1088;
    if (j >= 1025) {
        K[((size_t)b * 1088 + j) * 64 + lane] = f2bf(0.f);
        Vt[((size_t)b * 64 + lane) * 1088 + j] = f2bf(0.f);
        return;
    }
    float kv, vv;
    if (j == 0) {
        kv = ldin(nkv, nkoff + lane, f);
        vv = ldin(nkv, nkoff + 64 + lane, f);
    } else {
        int n = j - 1;
        const bf16* src = qkv + (size_t)(b * 1024 + n) * 640 + 512;
        kv = bf2f(src[lane]);
        vv = bf2f(src[64 + lane]);
        if (lane < 32) {
            int p = lane >> 1;
            float ang = (float)n * expf((float)p * -0.5756462732f);
            float c = cosf(ang), s = sinf(ang);
            float other = __shfl_xor(kv, 1, 64);
            float rot = (lane & 1) ? other : -other;
            kv = kv * c + rot * s;
        }
    }
    float nrm = sqrtf(wave_sum(kv * kv));
    kv = kv / fmaxf(nrm, 1e-12f) * 4.f;
    K[((size_t)b * 1088 + j) * 64 + lane] = f2bf(kv);
    Vt[((size_t)b * 64 + lane) * 1088 + j] = f2bf(vv);
}

// ---------------- MFMA flash attention, K-SPLIT (S=4), FIXED-MAX softmax -----
// grid (B*H=32, 16 qtiles, 4 splits), block 256 = 4 waves (16 q-rows each).
// Bias table is pre-offset by -16 (guaranteed score upper bound), so no online
// max / rescale / per-chunk row-sum reductions: p = exp(s + bias'), l is a
// per-lane f32 partial reduced once at the end. K/V are prefetched into
// registers one chunk ahead (latency hidden under compute). Partials are
// plain sums; combine just adds.
__global__ __launch_bounds__(256)
void attn_mfma(const bf16* __restrict__ Q, const bf16* __restrict__ Kg,
               const bf16* __restrict__ Vtg, const float* __restrict__ bias,
               bf16* __restrict__ Op, float* __restrict__ ml)
{
    __shared__ bf16 Ks[64][72];
    __shared__ bf16 Vts[64][72];
    __shared__ bf16 Ps[4][16][72];
    __shared__ float bs[1088];
    const int bh = blockIdx.x, b = bh >> 3, h = bh & 7;
    const int yy = (int)gridDim.y - 1 - (int)blockIdx.y;   // longest first
    const int sp = blockIdx.z;
    const int i0 = yy * 64;
    const int t = threadIdx.x, lane = t & 63, w = t >> 6;
    const int col = lane & 15, quad = lane >> 4, fk = quad * 8;
    const float* bt = bias + h * 1025;
    const bf16* Kb = Kg + (size_t)b * 1088 * 64;
    const bf16* Vb = Vtg + (size_t)b * 64 * 1088;

    // stage bias row into LDS: dist range needed is [0, i0+63]
    for (int idx = t; idx < i0 + 64; idx += 256) bs[idx] = bt[idx];

    v8bf qf[2];
    const bf16* qrow = Q + ((size_t)bh * 1024 + i0 + w * 16 + col) * 64;
    qf[0] = *(const v8bf*)(qrow + fk);
    qf[1] = *(const v8bf*)(qrow + 32 + fk);

    v4f oacc[4];
#pragma unroll
    for (int dt = 0; dt < 4; ++dt) { v4f z = {0.f,0.f,0.f,0.f}; oacc[dt] = z; }
    float lpart[4] = {0.f, 0.f, 0.f, 0.f};

    const int nch = yy + 2;
    const int rr0 = t >> 3, co0 = (t & 7) * 8;          // rep 0 staging coords
    const int rr1 = (t + 256) >> 3, co1 = co0;          // rep 1 staging coords

    v8bf kr[2], vr[2];
    if (sp < nch) {
        int j0 = sp * 64;
        kr[0] = *(const v8bf*)(Kb + (size_t)(j0 + rr0) * 64 + co0);
        vr[0] = *(const v8bf*)(Vb + (size_t)rr0 * 1088 + j0 + co0);
        kr[1] = *(const v8bf*)(Kb + (size_t)(j0 + rr1) * 64 + co1);
        vr[1] = *(const v8bf*)(Vb + (size_t)rr1 * 1088 + j0 + co1);
    }

    for (int ch = sp; ch < nch; ch += 4) {
        const int j0 = ch * 64;
        __syncthreads();                                 // prev compute done w/ LDS
        *(v8bf*)(&Ks[rr0][co0])  = kr[0];
        *(v8bf*)(&Vts[rr0][co0]) = vr[0];
        *(v8bf*)(&Ks[rr1][co1])  = kr[1];
        *(v8bf*)(&Vts[rr1][co1]) = vr[1];
        const int more = (ch + 4 < nch);
        if (more) {                                      // prefetch next chunk
            int j0n = (ch + 4) * 64;
            kr[0] = *(const v8bf*)(Kb + (size_t)(j0n + rr0) * 64 + co0);
            vr[0] = *(const v8bf*)(Vb + (size_t)rr0 * 1088 + j0n + co0);
            kr[1] = *(const v8bf*)(Kb + (size_t)(j0n + rr1) * 64 + co1);
            vr[1] = *(const v8bf*)(Vb + (size_t)rr1 * 1088 + j0n + co1);
        }
        __syncthreads();

        // QK^T
        v4f sreg[4];
#pragma unroll
        for (int nt = 0; nt < 4; ++nt) {
            v4f z = {0.f,0.f,0.f,0.f};
            v8bf kf0 = *(const v8bf*)(&Ks[nt * 16 + col][fk]);
            v8bf kf1 = *(const v8bf*)(&Ks[nt * 16 + col][32 + fk]);
            z = __builtin_amdgcn_mfma_f32_16x16x32_bf16(qf[0], kf0, z, 0, 0, 0);
            z = __builtin_amdgcn_mfma_f32_16x16x32_bf16(qf[1], kf1, z, 0, 0, 0);
            sreg[nt] = z;
        }

        // p = exp(s + bias - 16); no max tracking, no cross-lane ops.
        if (ch < yy) {
            // fully-interior chunk: no causal/pad mask, dist always >= 1
#pragma unroll
            for (int reg = 0; reg < 4; ++reg) {
                int i = i0 + w * 16 + quad * 4 + reg;
                int dbase = i - j0 - col;
#pragma unroll
                for (int nt = 0; nt < 4; ++nt) {
                    float pp = __expf(sreg[nt][reg] + bs[dbase - nt * 16]);
                    lpart[reg] += pp;
                    Ps[w][quad * 4 + reg][nt * 16 + col] = f2bf(pp);
                }
            }
        } else {
#pragma unroll
            for (int reg = 0; reg < 4; ++reg) {
                int i = i0 + w * 16 + quad * 4 + reg;
#pragma unroll
                for (int nt = 0; nt < 4; ++nt) {
                    int j = j0 + nt * 16 + col;
                    float pp = 0.f;
                    if (j <= i + 1 && j < 1025) {
                        int dist = i - j; if (dist < 0) dist = 0;
                        pp = __expf(sreg[nt][reg] + bs[dist]);
                    }
                    lpart[reg] += pp;
                    Ps[w][quad * 4 + reg][nt * 16 + col] = f2bf(pp);
                }
            }
        }

        // PV
        v8bf pf[2];
        pf[0] = *(const v8bf*)(&Ps[w][col][fk]);
        pf[1] = *(const v8bf*)(&Ps[w][col][32 + fk]);
#pragma unroll
        for (int dt = 0; dt < 4; ++dt) {
#pragma unroll
            for (int ks = 0; ks < 2; ++ks) {
                v8bf vf = *(const v8bf*)(&Vts[dt * 16 + col][ks * 32 + fk]);
                oacc[dt] = __builtin_amdgcn_mfma_f32_16x16x32_bf16(pf[ks], vf, oacc[dt], 0, 0, 0);
            }
        }
    }

    // single deferred l reduction (16 cols per row)
#pragma unroll
    for (int reg = 0; reg < 4; ++reg) {
#pragma unroll
        for (int o = 1; o < 16; o <<= 1) lpart[reg] += __shfl_xor(lpart[reg], o, 64);
    }

    // write UNNORMALIZED partials: Op[((sp*32+bh)*1024+i)*64+d], ml[...] = l
#pragma unroll
    for (int reg = 0; reg < 4; ++reg) {
        int i = i0 + w * 16 + quad * 4 + reg;
        size_t rbase = ((size_t)(sp * 32 + bh) * 1024 + i);
#pragma unroll
        for (int dt = 0; dt < 4; ++dt)
            Op[rbase * 64 + dt * 16 + col] = f2bf(oacc[dt][reg]);
        if (col == 0) ml[rbase] = lpart[reg];
    }
}

// ---------------- combine 4 k-split partials (plain sums) --------------------
__global__ __launch_bounds__(256)
void attn_comb(const bf16* __restrict__ Op, const float* __restrict__ ml,
               bf16* __restrict__ O)
{
    int tid = blockIdx.x * 256 + threadIdx.x;   // 32*1024*64 = 2,097,152
    int d = tid & 63;
    int r = tid >> 6;                           // bh*1024 + i
    float l = ml[r] + ml[32768 + r] + ml[65536 + r] + ml[98304 + r];
    float o = bf2f(Op[(size_t)r * 64 + d])
            + bf2f(Op[((size_t)32768 + r) * 64 + d])
            + bf2f(Op[((size_t)65536 + r) * 64 + d])
            + bf2f(Op[((size_t)98304 + r) * 64 + d]);
    int bh = r >> 10, i = r & 1023, b = bh >> 3, h = bh & 7;
    O[((size_t)(b * 1024 + i)) * 512 + h * 64 + d] = f2bf(o / l);
}

// =============================================================================
extern "C" void kernel_launch(void* const* d_in, const int* in_sizes, int n_in,
                              void* d_out, int out_size, void* d_ws, size_t ws_size,
                              hipStream_t stream)
{
    const void* x_in     = d_in[0];
    const void* rpe      = d_in[1];
    const void* g_attn   = d_in[2];
    const void* null_kv  = d_in[3];
    const void* Wq       = d_in[4];
    const void* Wkv      = d_in[5];
    const void* Wo       = d_in[6];
    const void* g_attn_o = d_in[7];
    const void* g_ff     = d_in[8];
    const void* W1       = d_in[9];
    const void* W2       = d_in[10];
    const void* g_final  = d_in[11];
    const void* W_proj   = d_in[12];

    char* wp = (char*)d_ws;
    auto alloc = [&](size_t bytes) {
        char* p = wp; wp += (bytes + 255) & ~(size_t)255; return p;
    };
    float* xf    = (float*)alloc(4096ull * 512 * 4);
    bf16*  xn    = (bf16*) alloc(4096ull * 512 * 2);
    bf16*  tb    = (bf16*) alloc(4096ull * 512 * 2);
    bf16*  ub    = (bf16*) alloc(4096ull * 4096 * 2);
    bf16*  Kb    = (bf16*) alloc(4ull * 1088 * 64 * 2);
    bf16*  Vtb   = (bf16*) alloc(4ull * 64 * 1088 * 2);
    float* btab  = (float*)alloc(8ull * 1025 * 4);
    int*   dfl   = (int*)  alloc(256);
    bf16*  WqkvT = (bf16*) alloc(6ull * 640 * 512 * 2);
    bf16*  WoT   = (bf16*) alloc(6ull * 512 * 512 * 2);
    bf16*  W1T   = (bf16*) alloc(6ull * 4096 * 512 * 2);
    bf16*  W2T   = (bf16*) alloc(6ull * 512 * 2048 * 2);
    bf16*  WpT   = (bf16*) alloc(512ull * 512 * 2);
    // aliased into ub (16,777,216 elems; lifetimes end before W1 gemm writes ub)
    bf16*  qkvb  = ub;                        // 2,621,440 elems
    bf16*  Qb    = ub + 2621440;              // 2,097,152
    bf16*  ob    = ub + 4718592;              // 2,097,152
    bf16*  Opart = ub + 6815744;              // 4*32*1024*64 = 8,388,608
    float* mlprt = (float*)(ub + 15204352);   // 131,072 floats = 262,144 elems

    detect_k<<<1, 256, 0, stream>>>((const unsigned short*)x_in, dfl);
    transpose2_k<<<dim3(16, 16, 6),  dim3(32, 8), 0, stream>>>(Wq, WqkvT, 512, 512, 512ull*512, 640ull*512, dfl);
    transpose2_k<<<dim3(4, 16, 6),   dim3(32, 8), 0, stream>>>(Wkv, WqkvT + 512ull*512, 512, 128, 512ull*128, 640ull*512, dfl);
    transpose2_k<<<dim3(16, 16, 6),  dim3(32, 8), 0, stream>>>(Wo, WoT, 512, 512, 512ull*512, 512ull*512, dfl);
    transpose2_k<<<dim3(128, 16, 6), dim3(32, 8), 0, stream>>>(W1, W1T, 512, 4096, 512ull*4096, 512ull*4096, dfl);
    transpose2_k<<<dim3(16, 64, 6),  dim3(32, 8), 0, stream>>>(W2, W2T, 2048, 512, 2048ull*512, 2048ull*512, dfl);
    transpose2_k<<<dim3(16, 16, 1),  dim3(32, 8), 0, stream>>>(W_proj, WpT, 512, 512, 512ull*512, 512ull*512, dfl);
    bias_k<<<33, 256, 0, stream>>>(rpe, dfl, btab);
    xinit_ln_k<<<4096, 256, 0, stream>>>(x_in, g_attn, dfl, xf, xn);

    for (int l = 0; l < 6; ++l) {
        gemm64<<<dim3(64, 5), 256, 0, stream>>>(xn, WqkvT + (size_t)l * 640 * 512, qkvb, 4096, 640, 512, 512);
        qprep_k<<<8192, 256, 0, stream>>>(qkvb, Qb);
        kvprep_k<<<1088, 256, 0, stream>>>(qkvb, null_kv, l * 128, dfl, Kb, Vtb);
        attn_mfma<<<dim3(32, 16, 4), 256, 0, stream>>>(Qb, Kb, Vtb, btab, Opart, mlprt);
        attn_comb<<<8192, 256, 0, stream>>>(Opart, mlprt, ob);
        gemm64<<<dim3(64, 4), 256, 0, stream>>>(ob, WoT + (size_t)l * 512 * 512, tb, 4096, 512, 512, 512);
        addln_ln_k<<<4096, 256, 0, stream>>>(tb, g_attn_o, l * 512, g_ff, l * 512, dfl, xf, xn);
        gemm_bt<<<dim3(32, 32), 256, 0, stream>>>(xn, W1T + (size_t)l * 4096 * 512, ub, 4096, 4096, 512, 512);
        silu_k<<<32768, 256, 0, stream>>>(ub);
        gemm64<<<dim3(64, 4), 256, 0, stream>>>(ub, W2T + (size_t)l * 512 * 2048, tb, 4096, 512, 2048, 4096);
        if (l < 5)
            add_ln_k<<<4096, 256, 0, stream>>>(tb, g_attn, (l + 1) * 512, dfl, 0, xf, xn);
        else
            add_ln_k<<<4096, 256, 0, stream>>>(tb, g_final, 0, dfl, 1, xf, xn);
    }
    gemm64_out<<<dim3(64, 4), 256, 0, stream>>>(xn, WpT, d_out, 4096, 512, 512, 512, dfl);
}

// Round 2
// 1021.870 us; speedup vs baseline: 1.2295x; 1.0975x over previous
//
#include <hip/hip_runtime.h>
#include <hip/hip_bf16.h>
#include <cmath>

using bf16 = __hip_bfloat16;
typedef __bf16 v8bf __attribute__((ext_vector_type(8)));
typedef float  v4f  __attribute__((ext_vector_type(4)));

__device__ __forceinline__ float bf2f(bf16 x) { return __bfloat162float(x); }
__device__ __forceinline__ bf16  f2bf(float x) { return __float2bfloat16(x); }

// async global->LDS, 16B per lane (lds dest = wave-uniform base + lane*16)
__device__ __forceinline__ void gll16(const bf16* g, bf16* l) {
    __builtin_amdgcn_global_load_lds(
        (const __attribute__((address_space(1))) unsigned int*)g,
        (__attribute__((address_space(3))) unsigned int*)l, 16, 0, 0);
}

__device__ __forceinline__ float ldin(const void* p, size_t i, int isf32) {
    if (isf32) return ((const float*)p)[i];
    return bf2f(((const bf16*)p)[i]);
}

__device__ __forceinline__ float wave_sum(float v) {
#pragma unroll
    for (int o = 32; o > 0; o >>= 1) v += __shfl_xor(v, o, 64);
    return v;
}
__device__ __forceinline__ float wave_max(float v) {
#pragma unroll
    for (int o = 32; o > 0; o >>= 1) v = fmaxf(v, __shfl_xor(v, o, 64));
    return v;
}
__device__ __forceinline__ float block_sum(float v, float* sm) {
    v = wave_sum(v);
    int lane = threadIdx.x & 63, w = threadIdx.x >> 6;
    __syncthreads();
    if (lane == 0) sm[w] = v;
    __syncthreads();
    return (sm[0] + sm[1]) + (sm[2] + sm[3]);
}
__device__ __forceinline__ float block_max(float v, float* sm) {
    v = wave_max(v);
    int lane = threadIdx.x & 63, w = threadIdx.x >> 6;
    __syncthreads();
    if (lane == 0) sm[w] = v;
    __syncthreads();
    return fmaxf(fmaxf(sm[0], sm[1]), fmaxf(sm[2], sm[3]));
}

// ---------------- dtype detector -------------------------------------------
__global__ void detect_k(const unsigned short* __restrict__ x, int* __restrict__ flag)
{
    __shared__ int s;
    int t = threadIdx.x;
    if (t == 0) s = 0;
    __syncthreads();
    int bad = 0;
    for (int i = t; i < 4096; i += 256) {
        int e = (x[i] >> 7) & 0xFF;
        if (e >= 147) bad++;
    }
    atomicAdd(&s, bad);
    __syncthreads();
    if (t == 0) *flag = (s > 64) ? 1 : 0;
}

// ---------------- MFMA GEMM 128x128 + fused SiLU epilogue --------------------
// BT is the PERMUTED W1^T: row j' = group g=j'>>6, s=j'&63; s<32 -> a-col
// g*32+s, s>=32 -> gate-col 2048+g*32+(s-32). So acc[mt][nt] (nt<2) pairs with
// acc[mt][nt+2] as (a, gate) for output col g*32+nt*16+fr. U is 4096x2048.
__global__ __launch_bounds__(256)
void gemm_bt_silu(const bf16* __restrict__ A, const bf16* __restrict__ BT,
                  bf16* __restrict__ U, int K, int lda)
{
    __shared__ bf16 As[128 * 32];
    __shared__ bf16 Bs[128 * 32];
    const int t = threadIdx.x;
    const int lane = t & 63;
    const int wave = t >> 6;
    const int wm = (wave >> 1) * 64;
    const int wn = (wave & 1) * 64;
    const int bm = blockIdx.x * 128;
    const int bn = blockIdx.y * 128;
    const int fr = lane & 15;
    const int fk = (lane >> 4) * 8;

    v4f acc[4][4];
#pragma unroll
    for (int i = 0; i < 4; ++i)
#pragma unroll
        for (int j = 0; j < 4; ++j) { v4f z = {0.f, 0.f, 0.f, 0.f}; acc[i][j] = z; }

    for (int k0 = 0; k0 < K; k0 += 32) {
#pragma unroll
        for (int r = 0; r < 2; ++r) {
            int c = t + 256 * r;
            int row = c >> 2;
            int koff = (c & 3) * 8;
            gll16(A + (size_t)(bm + row) * lda + k0 + koff, &As[c * 8]);
            gll16(BT + (size_t)(bn + row) * K + k0 + koff, &Bs[c * 8]);
        }
        __syncthreads();
        v8bf af[4], bfr[4];
#pragma unroll
        for (int mt = 0; mt < 4; ++mt)
            af[mt] = *(const v8bf*)(&As[(wm + mt * 16 + fr) * 32 + fk]);
#pragma unroll
        for (int nt = 0; nt < 4; ++nt)
            bfr[nt] = *(const v8bf*)(&Bs[(wn + nt * 16 + fr) * 32 + fk]);
#pragma unroll
        for (int mt = 0; mt < 4; ++mt)
#pragma unroll
            for (int nt = 0; nt < 4; ++nt)
                acc[mt][nt] = __builtin_amdgcn_mfma_f32_16x16x32_bf16(
                    af[mt], bfr[nt], acc[mt][nt], 0, 0, 0);
        __syncthreads();
    }
    const int r0 = (lane >> 4) * 4;
    const int gbase = ((bn + wn) >> 6) * 32;
#pragma unroll
    for (int mt = 0; mt < 4; ++mt)
#pragma unroll
        for (int nt = 0; nt < 2; ++nt)
#pragma unroll
            for (int r = 0; r < 4; ++r) {
                int row = bm + wm + mt * 16 + r0 + r;
                int col = gbase + nt * 16 + fr;
                float a  = acc[mt][nt][r];
                float gg = acc[mt][nt + 2][r];
                U[(size_t)row * 2048 + col] = f2bf(a * (gg / (1.f + __expf(-gg))));
            }
}

// ---------------- MFMA GEMM 64x128 tile (async LDS staging) ------------------
__global__ __launch_bounds__(256)
void gemm64(const bf16* __restrict__ A, const bf16* __restrict__ BT,
            bf16* __restrict__ C, int M, int N, int K, int lda)
{
    __shared__ bf16 As[64 * 32];
    __shared__ bf16 Bs[128 * 32];
    const int t = threadIdx.x;
    const int lane = t & 63;
    const int wave = t >> 6;
    const int wm = (wave >> 1) * 32;
    const int wn = (wave & 1) * 64;
    const int bm = blockIdx.x * 64;
    const int bn = blockIdx.y * 128;
    const int fr = lane & 15;
    const int fk = (lane >> 4) * 8;

    v4f acc[2][4];
#pragma unroll
    for (int i = 0; i < 2; ++i)
#pragma unroll
        for (int j = 0; j < 4; ++j) { v4f z = {0.f, 0.f, 0.f, 0.f}; acc[i][j] = z; }

    for (int k0 = 0; k0 < K; k0 += 32) {
        {
            int row = t >> 2, koff = (t & 3) * 8;
            gll16(A + (size_t)(bm + row) * lda + k0 + koff, &As[t * 8]);
        }
#pragma unroll
        for (int r = 0; r < 2; ++r) {
            int c = t + 256 * r;
            int row = c >> 2, koff = (c & 3) * 8;
            gll16(BT + (size_t)(bn + row) * K + k0 + koff, &Bs[c * 8]);
        }
        __syncthreads();
        v8bf af[2], bfr[4];
#pragma unroll
        for (int mt = 0; mt < 2; ++mt)
            af[mt] = *(const v8bf*)(&As[(wm + mt * 16 + fr) * 32 + fk]);
#pragma unroll
        for (int nt = 0; nt < 4; ++nt)
            bfr[nt] = *(const v8bf*)(&Bs[(wn + nt * 16 + fr) * 32 + fk]);
#pragma unroll
        for (int mt = 0; mt < 2; ++mt)
#pragma unroll
            for (int nt = 0; nt < 4; ++nt)
                acc[mt][nt] = __builtin_amdgcn_mfma_f32_16x16x32_bf16(
                    af[mt], bfr[nt], acc[mt][nt], 0, 0, 0);
        __syncthreads();
    }
    const int r0 = (lane >> 4) * 4;
#pragma unroll
    for (int mt = 0; mt < 2; ++mt)
#pragma unroll
        for (int nt = 0; nt < 4; ++nt)
#pragma unroll
            for (int r = 0; r < 4; ++r) {
                int row = bm + wm + mt * 16 + r0 + r;
                int col = bn + wn + nt * 16 + fr;
                C[(size_t)row * N + col] = f2bf(acc[mt][nt][r]);
            }
}

// ---- gemm64 with flag-selected output dtype (final projection) --------------
__global__ __launch_bounds__(256)
void gemm64_out(const bf16* __restrict__ A, const bf16* __restrict__ BT,
                void* __restrict__ C, int M, int N, int K, int lda,
                const int* __restrict__ flag)
{
    __shared__ bf16 As[64 * 32];
    __shared__ bf16 Bs[128 * 32];
    const int f = *flag;
    const int t = threadIdx.x;
    const int lane = t & 63;
    const int wave = t >> 6;
    const int wm = (wave >> 1) * 32;
    const int wn = (wave & 1) * 64;
    const int bm = blockIdx.x * 64;
    const int bn = blockIdx.y * 128;
    const int fr = lane & 15;
    const int fk = (lane >> 4) * 8;

    v4f acc[2][4];
#pragma unroll
    for (int i = 0; i < 2; ++i)
#pragma unroll
        for (int j = 0; j < 4; ++j) { v4f z = {0.f, 0.f, 0.f, 0.f}; acc[i][j] = z; }

    for (int k0 = 0; k0 < K; k0 += 32) {
        {
            int row = t >> 2, koff = (t & 3) * 8;
            gll16(A + (size_t)(bm + row) * lda + k0 + koff, &As[t * 8]);
        }
#pragma unroll
        for (int r = 0; r < 2; ++r) {
            int c = t + 256 * r;
            int row = c >> 2, koff = (c & 3) * 8;
            gll16(BT + (size_t)(bn + row) * K + k0 + koff, &Bs[c * 8]);
        }
        __syncthreads();
        v8bf af[2], bfr[4];
#pragma unroll
        for (int mt = 0; mt < 2; ++mt)
            af[mt] = *(const v8bf*)(&As[(wm + mt * 16 + fr) * 32 + fk]);
#pragma unroll
        for (int nt = 0; nt < 4; ++nt)
            bfr[nt] = *(const v8bf*)(&Bs[(wn + nt * 16 + fr) * 32 + fk]);
#pragma unroll
        for (int mt = 0; mt < 2; ++mt)
#pragma unroll
            for (int nt = 0; nt < 4; ++nt)
                acc[mt][nt] = __builtin_amdgcn_mfma_f32_16x16x32_bf16(
                    af[mt], bfr[nt], acc[mt][nt], 0, 0, 0);
        __syncthreads();
    }
    const int r0 = (lane >> 4) * 4;
#pragma unroll
    for (int mt = 0; mt < 2; ++mt)
#pragma unroll
        for (int nt = 0; nt < 4; ++nt)
#pragma unroll
            for (int r = 0; r < 4; ++r) {
                int row = bm + wm + mt * 16 + r0 + r;
                int col = bn + wn + nt * 16 + fr;
                if (f) ((float*)C)[(size_t)row * N + col] = acc[mt][nt][r];
                else   ((bf16*)C)[(size_t)row * N + col] = f2bf(acc[mt][nt][r]);
            }
}

// ---------------- transpose w/ separate z-strides ----------------------------
__global__ __launch_bounds__(256)
void transpose2_k(const void* __restrict__ in, bf16* __restrict__ out, int R, int C,
                  size_t inZ, size_t outZ, const int* __restrict__ flag)
{
    __shared__ bf16 tile[32][33];
    int f = *flag;
    size_t ioff = (size_t)blockIdx.z * inZ;
    bf16* dst = out + (size_t)blockIdx.z * outZ;
    int c0 = blockIdx.x * 32, r0 = blockIdx.y * 32;
    int tx = threadIdx.x, ty = threadIdx.y;
#pragma unroll
    for (int i = 0; i < 32; i += 8)
        tile[ty + i][tx] = f2bf(ldin(in, ioff + (size_t)(r0 + ty + i) * C + c0 + tx, f));
    __syncthreads();
#pragma unroll
    for (int i = 0; i < 32; i += 8)
        dst[(size_t)(c0 + ty + i) * R + r0 + tx] = tile[tx][ty + i];
}

// ---------------- W1 transpose with a/gate interleave permutation ------------
// out row j' for orig col j: j<2048 (a): j' = (j>>5)*64 + (j&31);
// j>=2048 (gate): j' = ((j-2048)>>5)*64 + 32 + (j&31).
__global__ __launch_bounds__(256)
void transposeW1_k(const void* __restrict__ in, bf16* __restrict__ out,
                   const int* __restrict__ flag)
{
    __shared__ bf16 tile[32][33];
    int f = *flag;
    size_t ioff = (size_t)blockIdx.z * (512ull * 4096);
    bf16* dst = out + (size_t)blockIdx.z * (512ull * 4096);
    int c0 = blockIdx.x * 32, r0 = blockIdx.y * 32;
    int tx = threadIdx.x, ty = threadIdx.y;
#pragma unroll
    for (int i = 0; i < 32; i += 8)
        tile[ty + i][tx] = f2bf(ldin(in, ioff + (size_t)(r0 + ty + i) * 4096 + c0 + tx, f));
    __syncthreads();
#pragma unroll
    for (int i = 0; i < 32; i += 8) {
        int j = c0 + ty + i;
        int jp = (j < 2048) ? (((j >> 5) << 6) | (j & 31))
                            : ((((j - 2048) >> 5) << 6) | 32 | (j & 31));
        dst[(size_t)jp * 512 + r0 + tx] = tile[tx][ty + i];
    }
}

// ---------------- x = in; xn = LN(x)*g --------------------------------------
__global__ __launch_bounds__(256)
void xinit_ln_k(const void* __restrict__ in, const void* __restrict__ g,
                const int* __restrict__ flag, float* __restrict__ x, bf16* __restrict__ xn)
{
    __shared__ float sm[4];
    int f = *flag;
    int row = blockIdx.x, t = threadIdx.x;
    float v0 = ldin(in, (size_t)row * 512 + t, f);
    float v1 = ldin(in, (size_t)row * 512 + t + 256, f);
    x[(size_t)row * 512 + t] = v0;
    x[(size_t)row * 512 + t + 256] = v1;
    float mean = block_sum(v0 + v1, sm) * (1.f / 512.f);
    float d0 = v0 - mean, d1 = v1 - mean;
    float var = block_sum(d0 * d0 + d1 * d1, sm) * (1.f / 512.f);
    float rstd = rsqrtf(var + 1e-5f);
    xn[(size_t)row * 512 + t]       = f2bf(d0 * rstd * ldin(g, t, f));
    xn[(size_t)row * 512 + t + 256] = f2bf(d1 * rstd * ldin(g, t + 256, f));
}

// ---------------- x += LN(t)*g1 ; xn = LN(x)*g2 ------------------------------
__global__ __launch_bounds__(256)
void addln_ln_k(const bf16* __restrict__ tin, const void* __restrict__ g1, int g1off,
                const void* __restrict__ g2, int g2off, const int* __restrict__ flag,
                float* __restrict__ x, bf16* __restrict__ xn)
{
    __shared__ float sm[4];
    int f = *flag;
    int row = blockIdx.x, t = threadIdx.x;
    const bf16* tr = tin + (size_t)row * 512;
    float v0 = bf2f(tr[t]), v1 = bf2f(tr[t + 256]);
    float mean = block_sum(v0 + v1, sm) * (1.f / 512.f);
    float d0 = v0 - mean, d1 = v1 - mean;
    float var = block_sum(d0 * d0 + d1 * d1, sm) * (1.f / 512.f);
    float rstd = rsqrtf(var + 1e-5f);
    float nx0 = x[(size_t)row * 512 + t]       + d0 * rstd * ldin(g1, g1off + t, f);
    float nx1 = x[(size_t)row * 512 + t + 256] + d1 * rstd * ldin(g1, g1off + t + 256, f);
    x[(size_t)row * 512 + t]       = nx0;
    x[(size_t)row * 512 + t + 256] = nx1;
    float mean2 = block_sum(nx0 + nx1, sm) * (1.f / 512.f);
    float e0 = nx0 - mean2, e1 = nx1 - mean2;
    float var2 = block_sum(e0 * e0 + e1 * e1, sm) * (1.f / 512.f);
    float rstd2 = rsqrtf(var2 + 1e-5f);
    xn[(size_t)row * 512 + t]       = f2bf(e0 * rstd2 * ldin(g2, g2off + t, f));
    xn[(size_t)row * 512 + t + 256] = f2bf(e1 * rstd2 * ldin(g2, g2off + t + 256, f));
}

// ---------------- x += t ; xn = (stable? stableLN : LN)(x)*g -----------------
__global__ __launch_bounds__(256)
void add_ln_k(const bf16* __restrict__ tin, const void* __restrict__ g, int goff,
              const int* __restrict__ flag, int stable,
              float* __restrict__ x, bf16* __restrict__ xn)
{
    __shared__ float sm[4];
    int f = *flag;
    int row = blockIdx.x, t = threadIdx.x;
    float nx0 = x[(size_t)row * 512 + t]       + bf2f(tin[(size_t)row * 512 + t]);
    float nx1 = x[(size_t)row * 512 + t + 256] + bf2f(tin[(size_t)row * 512 + t + 256]);
    x[(size_t)row * 512 + t]       = nx0;
    x[(size_t)row * 512 + t + 256] = nx1;
    float v0 = nx0, v1 = nx1;
    if (stable) {
        float mx = block_max(fmaxf(v0, v1), sm);
        v0 /= mx; v1 /= mx;
    }
    float mean = block_sum(v0 + v1, sm) * (1.f / 512.f);
    float d0 = v0 - mean, d1 = v1 - mean;
    float var = block_sum(d0 * d0 + d1 * d1, sm) * (1.f / 512.f);
    float rstd = rsqrtf(var + 1e-5f);
    xn[(size_t)row * 512 + t]       = f2bf(d0 * rstd * ldin(g, goff + t, f));
    xn[(size_t)row * 512 + t + 256] = f2bf(d1 * rstd * ldin(g, goff + t + 256, f));
}

// ---------------- rotary cos/sin table: tab[n*16+p] = (cos, sin) -------------
__global__ __launch_bounds__(256)
void rotab_k(float2* __restrict__ tab)
{
    int idx = blockIdx.x * 256 + threadIdx.x;
    if (idx >= 16384) return;
    int n = idx >> 4, p = idx & 15;
    float ang = (float)n * expf((float)p * -0.5756462732f);
    tab[idx] = make_float2(cosf(ang), sinf(ang));
}

// ---------------- rel-pos bias table (pre-offset by -16: fixed softmax max) --
// qn,kn are l2-normalized to norm 4 => s = qn.kn <= 16 (Cauchy-Schwarz), and
// |bias| << 1, so exp(s + bias - 16) <= ~1.11. Softmax is shift-invariant, so
// folding the -16 here lets attention skip online-max tracking entirely.
__global__ __launch_bounds__(256)
void bias_k(const void* __restrict__ rpe, const int* __restrict__ flag, float* __restrict__ tab)
{
    int f = *flag;
    int idx = blockIdx.x * 256 + threadIdx.x;
    if (idx >= 8 * 1025) return;
    int h = idx / 1025, dist = idx % 1025;
    int bkt;
    if (dist < 16) bkt = dist;
    else {
        bkt = 16 + (int)(logf((float)dist / 16.f) / logf(8.f) * 16.f);
        if (bkt > 31) bkt = 31;
    }
    tab[idx] = ldin(rpe, bkt * 8 + h, f) - 16.f;
}

// ---------------- merged q + k/v prep (qkv stride 640, rotary via table) -----
// blocks [0,8192): q rows (B*H*N = 32768, 4/block).
// blocks [8192,9280): k/v rows j in [0,1088) x b (4352, 4/block).
__global__ __launch_bounds__(256)
void qkvprep_k(const bf16* __restrict__ qkv, const void* __restrict__ nkv, int nkoff,
               const int* __restrict__ flag, const float2* __restrict__ rtab,
               bf16* __restrict__ Q, bf16* __restrict__ K, bf16* __restrict__ Vt)
{
    int t = threadIdx.x, lane = t & 63;
    int bid = blockIdx.x;
    if (bid < 8192) {
        int rid = bid * 4 + (t >> 6);
        int h = rid & 7;
        int n = (rid >> 3) & 1023;
        int b = rid >> 13;
        float v = bf2f(qkv[(size_t)((b << 10) | n) * 640 + h * 64 + lane]) * 16.f;
        if (lane < 32) {
            float2 cs = rtab[n * 16 + (lane >> 1)];
            float other = __shfl_xor(v, 1, 64);
            float rot = (lane & 1) ? other : -other;
            v = v * cs.x + rot * cs.y;
        }
        float nrm = sqrtf(wave_sum(v * v));
        v = v / fmaxf(nrm, 1e-12f) * 4.f;
        Q[(((size_t)(b * 8 + h)) * 1024 + n) * 64 + lane] = f2bf(v);
    } else {
        int f = *flag;
        int rid = (bid - 8192) * 4 + (t >> 6);
        if (rid >= 4 * 1088) return;
        int j = rid % 1088;
        int b = rid / 1088;
        if (j >= 1025) {
            K[((size_t)b * 1088 + j) * 64 + lane] = f2bf(0.f);
            Vt[((size_t)b * 64 + lane) * 1088 + j] = f2bf(0.f);
            return;
        }
        float kv, vv;
        if (j == 0) {
            kv = ldin(nkv, nkoff + lane, f);
            vv = ldin(nkv, nkoff + 64 + lane, f);
        } else {
            int n = j - 1;
            const bf16* src = qkv + (size_t)(b * 1024 + n) * 640 + 512;
            kv = bf2f(src[lane]);
            vv = bf2f(src[64 + lane]);
            if (lane < 32) {
                float2 cs = rtab[n * 16 + (lane >> 1)];
                float other = __shfl_xor(kv, 1, 64);
                float rot = (lane & 1) ? other : -other;
                kv = kv * cs.x + rot * cs.y;
            }
        }
        float nrm = sqrtf(wave_sum(kv * kv));
        kv = kv / fmaxf(nrm, 1e-12f) * 4.f;
        K[((size_t)b * 1088 + j) * 64 + lane] = f2bf(kv);
        Vt[((size_t)b * 64 + lane) * 1088 + j] = f2bf(vv);
    }
}

// ---------------- MFMA flash attention, K-SPLIT (S=4), FIXED-MAX softmax -----
// grid (B*H=32, 16 qtiles, 4 splits), block 256 = 4 waves (16 q-rows each).
// Bias table is pre-offset by -16 (guaranteed score upper bound), so no online
// max / rescale / per-chunk row-sum reductions: p = exp(s + bias'), l is a
// per-lane f32 partial reduced once at the end. K/V are prefetched into
// registers one chunk ahead (latency hidden under compute). Partials are
// plain sums; combine just adds.
__global__ __launch_bounds__(256)
void attn_mfma(const bf16* __restrict__ Q, const bf16* __restrict__ Kg,
               const bf16* __restrict__ Vtg, const float* __restrict__ bias,
               bf16* __restrict__ Op, float* __restrict__ ml)
{
    __shared__ bf16 Ks[64][72];
    __shared__ bf16 Vts[64][72];
    __shared__ bf16 Ps[4][16][72];
    __shared__ float bs[1088];
    const int bh = blockIdx.x, b = bh >> 3, h = bh & 7;
    const int yy = (int)gridDim.y - 1 - (int)blockIdx.y;   // longest first
    const int sp = blockIdx.z;
    const int i0 = yy * 64;
    const int t = threadIdx.x, lane = t & 63, w = t >> 6;
    const int col = lane & 15, quad = lane >> 4, fk = quad * 8;
    const float* bt = bias + h * 1025;
    const bf16* Kb = Kg + (size_t)b * 1088 * 64;
    const bf16* Vb = Vtg + (size_t)b * 64 * 1088;

    // stage bias row into LDS: dist range needed is [0, i0+63]
    for (int idx = t; idx < i0 + 64; idx += 256) bs[idx] = bt[idx];

    v8bf qf[2];
    const bf16* qrow = Q + ((size_t)bh * 1024 + i0 + w * 16 + col) * 64;
    qf[0] = *(const v8bf*)(qrow + fk);
    qf[1] = *(const v8bf*)(qrow + 32 + fk);

    v4f oacc[4];
#pragma unroll
    for (int dt = 0; dt < 4; ++dt) { v4f z = {0.f,0.f,0.f,0.f}; oacc[dt] = z; }
    float lpart[4] = {0.f, 0.f, 0.f, 0.f};

    const int nch = yy + 2;
    const int rr0 = t >> 3, co0 = (t & 7) * 8;          // rep 0 staging coords
    const int rr1 = (t + 256) >> 3, co1 = co0;          // rep 1 staging coords

    v8bf kr[2], vr[2];
    if (sp < nch) {
        int j0 = sp * 64;
        kr[0] = *(const v8bf*)(Kb + (size_t)(j0 + rr0) * 64 + co0);
        vr[0] = *(const v8bf*)(Vb + (size_t)rr0 * 1088 + j0 + co0);
        kr[1] = *(const v8bf*)(Kb + (size_t)(j0 + rr1) * 64 + co1);
        vr[1] = *(const v8bf*)(Vb + (size_t)rr1 * 1088 + j0 + co1);
    }

    for (int ch = sp; ch < nch; ch += 4) {
        const int j0 = ch * 64;
        __syncthreads();                                 // prev compute done w/ LDS
        *(v8bf*)(&Ks[rr0][co0])  = kr[0];
        *(v8bf*)(&Vts[rr0][co0]) = vr[0];
        *(v8bf*)(&Ks[rr1][co1])  = kr[1];
        *(v8bf*)(&Vts[rr1][co1]) = vr[1];
        const int more = (ch + 4 < nch);
        if (more) {                                      // prefetch next chunk
            int j0n = (ch + 4) * 64;
            kr[0] = *(const v8bf*)(Kb + (size_t)(j0n + rr0) * 64 + co0);
            vr[0] = *(const v8bf*)(Vb + (size_t)rr0 * 1088 + j0n + co0);
            kr[1] = *(const v8bf*)(Kb + (size_t)(j0n + rr1) * 64 + co1);
            vr[1] = *(const v8bf*)(Vb + (size_t)rr1 * 1088 + j0n + co1);
        }
        __syncthreads();

        // QK^T
        v4f sreg[4];
#pragma unroll
        for (int nt = 0; nt < 4; ++nt) {
            v4f z = {0.f,0.f,0.f,0.f};
            v8bf kf0 = *(const v8bf*)(&Ks[nt * 16 + col][fk]);
            v8bf kf1 = *(const v8bf*)(&Ks[nt * 16 + col][32 + fk]);
            z = __builtin_amdgcn_mfma_f32_16x16x32_bf16(qf[0], kf0, z, 0, 0, 0);
            z = __builtin_amdgcn_mfma_f32_16x16x32_bf16(qf[1], kf1, z, 0, 0, 0);
            sreg[nt] = z;
        }

        // p = exp(s + bias - 16); no max tracking, no cross-lane ops.
        if (ch < yy) {
            // fully-interior chunk: no causal/pad mask, dist always >= 1
#pragma unroll
            for (int reg = 0; reg < 4; ++reg) {
                int i = i0 + w * 16 + quad * 4 + reg;
                int dbase = i - j0 - col;
#pragma unroll
                for (int nt = 0; nt < 4; ++nt) {
                    float pp = __expf(sreg[nt][reg] + bs[dbase - nt * 16]);
                    lpart[reg] += pp;
                    Ps[w][quad * 4 + reg][nt * 16 + col] = f2bf(pp);
                }
            }
        } else {
#pragma unroll
            for (int reg = 0; reg < 4; ++reg) {
                int i = i0 + w * 16 + quad * 4 + reg;
#pragma unroll
                for (int nt = 0; nt < 4; ++nt) {
                    int j = j0 + nt * 16 + col;
                    float pp = 0.f;
                    if (j <= i + 1 && j < 1025) {
                        int dist = i - j; if (dist < 0) dist = 0;
                        pp = __expf(sreg[nt][reg] + bs[dist]);
                    }
                    lpart[reg] += pp;
                    Ps[w][quad * 4 + reg][nt * 16 + col] = f2bf(pp);
                }
            }
        }

        // PV
        v8bf pf[2];
        pf[0] = *(const v8bf*)(&Ps[w][col][fk]);
        pf[1] = *(const v8bf*)(&Ps[w][col][32 + fk]);
#pragma unroll
        for (int dt = 0; dt < 4; ++dt) {
#pragma unroll
            for (int ks = 0; ks < 2; ++ks) {
                v8bf vf = *(const v8bf*)(&Vts[dt * 16 + col][ks * 32 + fk]);
                oacc[dt] = __builtin_amdgcn_mfma_f32_16x16x32_bf16(pf[ks], vf, oacc[dt], 0, 0, 0);
            }
        }
    }

    // single deferred l reduction (16 cols per row)
#pragma unroll
    for (int reg = 0; reg < 4; ++reg) {
#pragma unroll
        for (int o = 1; o < 16; o <<= 1) lpart[reg] += __shfl_xor(lpart[reg], o, 64);
    }

    // write UNNORMALIZED partials: Op[((sp*32+bh)*1024+i)*64+d], ml[...] = l
#pragma unroll
    for (int reg = 0; reg < 4; ++reg) {
        int i = i0 + w * 16 + quad * 4 + reg;
        size_t rbase = ((size_t)(sp * 32 + bh) * 1024 + i);
#pragma unroll
        for (int dt = 0; dt < 4; ++dt)
            Op[rbase * 64 + dt * 16 + col] = f2bf(oacc[dt][reg]);
        if (col == 0) ml[rbase] = lpart[reg];
    }
}

// ---------------- combine 4 k-split partials (plain sums) --------------------
__global__ __launch_bounds__(256)
void attn_comb(const bf16* __restrict__ Op, const float* __restrict__ ml,
               bf16* __restrict__ O)
{
    int tid = blockIdx.x * 256 + threadIdx.x;   // 32*1024*64 = 2,097,152
    int d = tid & 63;
    int r = tid >> 6;                           // bh*1024 + i
    float l = ml[r] + ml[32768 + r] + ml[65536 + r] + ml[98304 + r];
    float o = bf2f(Op[(size_t)r * 64 + d])
            + bf2f(Op[((size_t)32768 + r) * 64 + d])
            + bf2f(Op[((size_t)65536 + r) * 64 + d])
            + bf2f(Op[((size_t)98304 + r) * 64 + d]);
    int bh = r >> 10, i = r & 1023, b = bh >> 3, h = bh & 7;
    O[((size_t)(b * 1024 + i)) * 512 + h * 64 + d] = f2bf(o / l);
}

// =============================================================================
extern "C" void kernel_launch(void* const* d_in, const int* in_sizes, int n_in,
                              void* d_out, int out_size, void* d_ws, size_t ws_size,
                              hipStream_t stream)
{
    const void* x_in     = d_in[0];
    const void* rpe      = d_in[1];
    const void* g_attn   = d_in[2];
    const void* null_kv  = d_in[3];
    const void* Wq       = d_in[4];
    const void* Wkv      = d_in[5];
    const void* Wo       = d_in[6];
    const void* g_attn_o = d_in[7];
    const void* g_ff     = d_in[8];
    const void* W1       = d_in[9];
    const void* W2       = d_in[10];
    const void* g_final  = d_in[11];
    const void* W_proj   = d_in[12];

    char* wp = (char*)d_ws;
    auto alloc = [&](size_t bytes) {
        char* p = wp; wp += (bytes + 255) & ~(size_t)255; return p;
    };
    float* xf    = (float*)alloc(4096ull * 512 * 4);
    bf16*  xn    = (bf16*) alloc(4096ull * 512 * 2);
    bf16*  tb    = (bf16*) alloc(4096ull * 512 * 2);
    bf16*  ub    = (bf16*) alloc(4096ull * 4096 * 2);
    bf16*  Kb    = (bf16*) alloc(4ull * 1088 * 64 * 2);
    bf16*  Vtb   = (bf16*) alloc(4ull * 64 * 1088 * 2);
    float* btab  = (float*)alloc(8ull * 1025 * 4);
    float2* rtab = (float2*)alloc(16384ull * 8);
    int*   dfl   = (int*)  alloc(256);
    bf16*  WqkvT = (bf16*) alloc(6ull * 640 * 512 * 2);
    bf16*  WoT   = (bf16*) alloc(6ull * 512 * 512 * 2);
    bf16*  W1T   = (bf16*) alloc(6ull * 4096 * 512 * 2);
    bf16*  W2T   = (bf16*) alloc(6ull * 512 * 2048 * 2);
    bf16*  WpT   = (bf16*) alloc(512ull * 512 * 2);
    // aliased into ub (16,777,216 elems; lifetimes end before W1 gemm writes ub)
    bf16*  qkvb  = ub;                        // 2,621,440 elems
    bf16*  Qb    = ub + 2621440;              // 2,097,152
    bf16*  ob    = ub + 4718592;              // 2,097,152
    bf16*  Opart = ub + 6815744;              // 4*32*1024*64 = 8,388,608
    float* mlprt = (float*)(ub + 15204352);   // 131,072 floats = 262,144 elems

    detect_k<<<1, 256, 0, stream>>>((const unsigned short*)x_in, dfl);
    transpose2_k<<<dim3(16, 16, 6),  dim3(32, 8), 0, stream>>>(Wq, WqkvT, 512, 512, 512ull*512, 640ull*512, dfl);
    transpose2_k<<<dim3(4, 16, 6),   dim3(32, 8), 0, stream>>>(Wkv, WqkvT + 512ull*512, 512, 128, 512ull*128, 640ull*512, dfl);
    transpose2_k<<<dim3(16, 16, 6),  dim3(32, 8), 0, stream>>>(Wo, WoT, 512, 512, 512ull*512, 512ull*512, dfl);
    transposeW1_k<<<dim3(128, 16, 6), dim3(32, 8), 0, stream>>>(W1, W1T, dfl);
    transpose2_k<<<dim3(16, 64, 6),  dim3(32, 8), 0, stream>>>(W2, W2T, 2048, 512, 2048ull*512, 2048ull*512, dfl);
    transpose2_k<<<dim3(16, 16, 1),  dim3(32, 8), 0, stream>>>(W_proj, WpT, 512, 512, 512ull*512, 512ull*512, dfl);
    bias_k<<<33, 256, 0, stream>>>(rpe, dfl, btab);
    rotab_k<<<64, 256, 0, stream>>>(rtab);
    xinit_ln_k<<<4096, 256, 0, stream>>>(x_in, g_attn, dfl, xf, xn);

    for (int l = 0; l < 6; ++l) {
        gemm64<<<dim3(64, 5), 256, 0, stream>>>(xn, WqkvT + (size_t)l * 640 * 512, qkvb, 4096, 640, 512, 512);
        qkvprep_k<<<9280, 256, 0, stream>>>(qkvb, null_kv, l * 128, dfl, rtab, Qb, Kb, Vtb);
        attn_mfma<<<dim3(32, 16, 4), 256, 0, stream>>>(Qb, Kb, Vtb, btab, Opart, mlprt);
        attn_comb<<<8192, 256, 0, stream>>>(Opart, mlprt, ob);
        gemm64<<<dim3(64, 4), 256, 0, stream>>>(ob, WoT + (size_t)l * 512 * 512, tb, 4096, 512, 512, 512);
        addln_ln_k<<<4096, 256, 0, stream>>>(tb, g_attn_o, l * 512, g_ff, l * 512, dfl, xf, xn);
        gemm_bt_silu<<<dim3(32, 32), 256, 0, stream>>>(xn, W1T + (size_t)l * 4096 * 512, ub, 512, 512);
        gemm64<<<dim3(64, 4), 256, 0, stream>>>(ub, W2T + (size_t)l * 512 * 2048, tb, 4096, 512, 2048, 2048);
        if (l < 5)
            add_ln_k<<<4096, 256, 0, stream>>>(tb, g_attn, (l + 1) * 512, dfl, 0, xf, xn);
        else
            add_ln_k<<<4096, 256, 0, stream>>>(tb, g_final, 0, dfl, 1, xf, xn);
    }
    gemm64_out<<<dim3(64, 4), 256, 0, stream>>>(xn, WpT, d_out, 4096, 512, 512, 512, dfl);
}

// Round 3
// 963.366 us; speedup vs baseline: 1.3041x; 1.0607x over previous
//
#include <hip/hip_runtime.h>
#include <hip/hip_bf16.h>
#include <cmath>

using bf16 = __hip_bfloat16;
typedef __bf16 v8bf __attribute__((ext_vector_type(8)));
typedef __bf16 v4bf __attribute__((ext_vector_type(4)));
typedef float  v4f  __attribute__((ext_vector_type(4)));

__device__ __forceinline__ float bf2f(bf16 x) { return __bfloat162float(x); }
__device__ __forceinline__ bf16  f2bf(float x) { return __float2bfloat16(x); }
__device__ __forceinline__ __bf16 tobf(float x) {
    bf16 h = __float2bfloat16(x);
    return __builtin_bit_cast(__bf16, h);
}

// async global->LDS, 16B per lane (lds dest = wave-uniform base + lane*16)
__device__ __forceinline__ void gll16(const bf16* g, bf16* l) {
    __builtin_amdgcn_global_load_lds(
        (const __attribute__((address_space(1))) unsigned int*)g,
        (__attribute__((address_space(3))) unsigned int*)l, 16, 0, 0);
}

__device__ __forceinline__ float ldin(const void* p, size_t i, int isf32) {
    if (isf32) return ((const float*)p)[i];
    return bf2f(((const bf16*)p)[i]);
}

// flag-dtype vector load of 8 consecutive elements
__device__ __forceinline__ void ld8(const void* p, size_t base, int f, float v[8]) {
    if (f) {
        const float* pf = (const float*)p + base;
        float4 a = *(const float4*)pf, b = *(const float4*)(pf + 4);
        v[0]=a.x; v[1]=a.y; v[2]=a.z; v[3]=a.w;
        v[4]=b.x; v[5]=b.y; v[6]=b.z; v[7]=b.w;
    } else {
        v8bf a = *(const v8bf*)((const bf16*)p + base);
#pragma unroll
        for (int j = 0; j < 8; ++j) v[j] = (float)a[j];
    }
}

__device__ __forceinline__ float wave_sum(float v) {
#pragma unroll
    for (int o = 32; o > 0; o >>= 1) v += __shfl_xor(v, o, 64);
    return v;
}
__device__ __forceinline__ float wave_max(float v) {
#pragma unroll
    for (int o = 32; o > 0; o >>= 1) v = fmaxf(v, __shfl_xor(v, o, 64));
    return v;
}

// ---------------- dtype detector -------------------------------------------
__global__ void detect_k(const unsigned short* __restrict__ x, int* __restrict__ flag)
{
    __shared__ int s;
    int t = threadIdx.x;
    if (t == 0) s = 0;
    __syncthreads();
    int bad = 0;
    for (int i = t; i < 4096; i += 256) {
        int e = (x[i] >> 7) & 0xFF;
        if (e >= 147) bad++;
    }
    atomicAdd(&s, bad);
    __syncthreads();
    if (t == 0) *flag = (s > 64) ? 1 : 0;
}

// ---------------- MFMA GEMM 128x128 + fused SiLU epilogue --------------------
// BT is the PERMUTED W1^T: row j' = group g=j'>>6, s=j'&63; s<32 -> a-col
// g*32+s, s>=32 -> gate-col 2048+g*32+(s-32). So acc[mt][nt] (nt<2) pairs with
// acc[mt][nt+2] as (a, gate) for output col g*32+nt*16+fr. U is 4096x2048.
__global__ __launch_bounds__(256)
void gemm_bt_silu(const bf16* __restrict__ A, const bf16* __restrict__ BT,
                  bf16* __restrict__ U, int K, int lda)
{
    __shared__ bf16 As[128 * 32];
    __shared__ bf16 Bs[128 * 32];
    const int t = threadIdx.x;
    const int lane = t & 63;
    const int wave = t >> 6;
    const int wm = (wave >> 1) * 64;
    const int wn = (wave & 1) * 64;
    const int bm = blockIdx.x * 128;
    const int bn = blockIdx.y * 128;
    const int fr = lane & 15;
    const int fk = (lane >> 4) * 8;

    v4f acc[4][4];
#pragma unroll
    for (int i = 0; i < 4; ++i)
#pragma unroll
        for (int j = 0; j < 4; ++j) { v4f z = {0.f, 0.f, 0.f, 0.f}; acc[i][j] = z; }

    for (int k0 = 0; k0 < K; k0 += 32) {
#pragma unroll
        for (int r = 0; r < 2; ++r) {
            int c = t + 256 * r;
            int row = c >> 2;
            int koff = (c & 3) * 8;
            gll16(A + (size_t)(bm + row) * lda + k0 + koff, &As[c * 8]);
            gll16(BT + (size_t)(bn + row) * K + k0 + koff, &Bs[c * 8]);
        }
        __syncthreads();
        v8bf af[4], bfr[4];
#pragma unroll
        for (int mt = 0; mt < 4; ++mt)
            af[mt] = *(const v8bf*)(&As[(wm + mt * 16 + fr) * 32 + fk]);
#pragma unroll
        for (int nt = 0; nt < 4; ++nt)
            bfr[nt] = *(const v8bf*)(&Bs[(wn + nt * 16 + fr) * 32 + fk]);
#pragma unroll
        for (int mt = 0; mt < 4; ++mt)
#pragma unroll
            for (int nt = 0; nt < 4; ++nt)
                acc[mt][nt] = __builtin_amdgcn_mfma_f32_16x16x32_bf16(
                    af[mt], bfr[nt], acc[mt][nt], 0, 0, 0);
        __syncthreads();
    }
    const int r0 = (lane >> 4) * 4;
    const int gbase = ((bn + wn) >> 6) * 32;
#pragma unroll
    for (int mt = 0; mt < 4; ++mt)
#pragma unroll
        for (int nt = 0; nt < 2; ++nt)
#pragma unroll
            for (int r = 0; r < 4; ++r) {
                int row = bm + wm + mt * 16 + r0 + r;
                int col = gbase + nt * 16 + fr;
                float a  = acc[mt][nt][r];
                float gg = acc[mt][nt + 2][r];
                U[(size_t)row * 2048 + col] = f2bf(a * (gg / (1.f + __expf(-gg))));
            }
}

// ---------------- MFMA GEMM 64x128 tile (async LDS staging) ------------------
__global__ __launch_bounds__(256)
void gemm64(const bf16* __restrict__ A, const bf16* __restrict__ BT,
            bf16* __restrict__ C, int M, int N, int K, int lda)
{
    __shared__ bf16 As[64 * 32];
    __shared__ bf16 Bs[128 * 32];
    const int t = threadIdx.x;
    const int lane = t & 63;
    const int wave = t >> 6;
    const int wm = (wave >> 1) * 32;
    const int wn = (wave & 1) * 64;
    const int bm = blockIdx.x * 64;
    const int bn = blockIdx.y * 128;
    const int fr = lane & 15;
    const int fk = (lane >> 4) * 8;

    v4f acc[2][4];
#pragma unroll
    for (int i = 0; i < 2; ++i)
#pragma unroll
        for (int j = 0; j < 4; ++j) { v4f z = {0.f, 0.f, 0.f, 0.f}; acc[i][j] = z; }

    for (int k0 = 0; k0 < K; k0 += 32) {
        {
            int row = t >> 2, koff = (t & 3) * 8;
            gll16(A + (size_t)(bm + row) * lda + k0 + koff, &As[t * 8]);
        }
#pragma unroll
        for (int r = 0; r < 2; ++r) {
            int c = t + 256 * r;
            int row = c >> 2, koff = (c & 3) * 8;
            gll16(BT + (size_t)(bn + row) * K + k0 + koff, &Bs[c * 8]);
        }
        __syncthreads();
        v8bf af[2], bfr[4];
#pragma unroll
        for (int mt = 0; mt < 2; ++mt)
            af[mt] = *(const v8bf*)(&As[(wm + mt * 16 + fr) * 32 + fk]);
#pragma unroll
        for (int nt = 0; nt < 4; ++nt)
            bfr[nt] = *(const v8bf*)(&Bs[(wn + nt * 16 + fr) * 32 + fk]);
#pragma unroll
        for (int mt = 0; mt < 2; ++mt)
#pragma unroll
            for (int nt = 0; nt < 4; ++nt)
                acc[mt][nt] = __builtin_amdgcn_mfma_f32_16x16x32_bf16(
                    af[mt], bfr[nt], acc[mt][nt], 0, 0, 0);
        __syncthreads();
    }
    const int r0 = (lane >> 4) * 4;
#pragma unroll
    for (int mt = 0; mt < 2; ++mt)
#pragma unroll
        for (int nt = 0; nt < 4; ++nt)
#pragma unroll
            for (int r = 0; r < 4; ++r) {
                int row = bm + wm + mt * 16 + r0 + r;
                int col = bn + wn + nt * 16 + fr;
                C[(size_t)row * N + col] = f2bf(acc[mt][nt][r]);
            }
}

// ---- gemm64 with flag-selected output dtype (final projection) --------------
__global__ __launch_bounds__(256)
void gemm64_out(const bf16* __restrict__ A, const bf16* __restrict__ BT,
                void* __restrict__ C, int M, int N, int K, int lda,
                const int* __restrict__ flag)
{
    __shared__ bf16 As[64 * 32];
    __shared__ bf16 Bs[128 * 32];
    const int f = *flag;
    const int t = threadIdx.x;
    const int lane = t & 63;
    const int wave = t >> 6;
    const int wm = (wave >> 1) * 32;
    const int wn = (wave & 1) * 64;
    const int bm = blockIdx.x * 64;
    const int bn = blockIdx.y * 128;
    const int fr = lane & 15;
    const int fk = (lane >> 4) * 8;

    v4f acc[2][4];
#pragma unroll
    for (int i = 0; i < 2; ++i)
#pragma unroll
        for (int j = 0; j < 4; ++j) { v4f z = {0.f, 0.f, 0.f, 0.f}; acc[i][j] = z; }

    for (int k0 = 0; k0 < K; k0 += 32) {
        {
            int row = t >> 2, koff = (t & 3) * 8;
            gll16(A + (size_t)(bm + row) * lda + k0 + koff, &As[t * 8]);
        }
#pragma unroll
        for (int r = 0; r < 2; ++r) {
            int c = t + 256 * r;
            int row = c >> 2, koff = (c & 3) * 8;
            gll16(BT + (size_t)(bn + row) * K + k0 + koff, &Bs[c * 8]);
        }
        __syncthreads();
        v8bf af[2], bfr[4];
#pragma unroll
        for (int mt = 0; mt < 2; ++mt)
            af[mt] = *(const v8bf*)(&As[(wm + mt * 16 + fr) * 32 + fk]);
#pragma unroll
        for (int nt = 0; nt < 4; ++nt)
            bfr[nt] = *(const v8bf*)(&Bs[(wn + nt * 16 + fr) * 32 + fk]);
#pragma unroll
        for (int mt = 0; mt < 2; ++mt)
#pragma unroll
            for (int nt = 0; nt < 4; ++nt)
                acc[mt][nt] = __builtin_amdgcn_mfma_f32_16x16x32_bf16(
                    af[mt], bfr[nt], acc[mt][nt], 0, 0, 0);
        __syncthreads();
    }
    const int r0 = (lane >> 4) * 4;
#pragma unroll
    for (int mt = 0; mt < 2; ++mt)
#pragma unroll
        for (int nt = 0; nt < 4; ++nt)
#pragma unroll
            for (int r = 0; r < 4; ++r) {
                int row = bm + wm + mt * 16 + r0 + r;
                int col = bn + wn + nt * 16 + fr;
                if (f) ((float*)C)[(size_t)row * N + col] = acc[mt][nt][r];
                else   ((bf16*)C)[(size_t)row * N + col] = f2bf(acc[mt][nt][r]);
            }
}

// ---------------- transpose w/ separate z-strides ----------------------------
__global__ __launch_bounds__(256)
void transpose2_k(const void* __restrict__ in, bf16* __restrict__ out, int R, int C,
                  size_t inZ, size_t outZ, const int* __restrict__ flag)
{
    __shared__ bf16 tile[32][33];
    int f = *flag;
    size_t ioff = (size_t)blockIdx.z * inZ;
    bf16* dst = out + (size_t)blockIdx.z * outZ;
    int c0 = blockIdx.x * 32, r0 = blockIdx.y * 32;
    int tx = threadIdx.x, ty = threadIdx.y;
#pragma unroll
    for (int i = 0; i < 32; i += 8)
        tile[ty + i][tx] = f2bf(ldin(in, ioff + (size_t)(r0 + ty + i) * C + c0 + tx, f));
    __syncthreads();
#pragma unroll
    for (int i = 0; i < 32; i += 8)
        dst[(size_t)(c0 + ty + i) * R + r0 + tx] = tile[tx][ty + i];
}

// ---------------- W1 transpose with a/gate interleave permutation ------------
// out row j' for orig col j: j<2048 (a): j' = (j>>5)*64 + (j&31);
// j>=2048 (gate): j' = ((j-2048)>>5)*64 + 32 + (j&31).
__global__ __launch_bounds__(256)
void transposeW1_k(const void* __restrict__ in, bf16* __restrict__ out,
                   const int* __restrict__ flag)
{
    __shared__ bf16 tile[32][33];
    int f = *flag;
    size_t ioff = (size_t)blockIdx.z * (512ull * 4096);
    bf16* dst = out + (size_t)blockIdx.z * (512ull * 4096);
    int c0 = blockIdx.x * 32, r0 = blockIdx.y * 32;
    int tx = threadIdx.x, ty = threadIdx.y;
#pragma unroll
    for (int i = 0; i < 32; i += 8)
        tile[ty + i][tx] = f2bf(ldin(in, ioff + (size_t)(r0 + ty + i) * 4096 + c0 + tx, f));
    __syncthreads();
#pragma unroll
    for (int i = 0; i < 32; i += 8) {
        int j = c0 + ty + i;
        int jp = (j < 2048) ? (((j >> 5) << 6) | (j & 31))
                            : ((((j - 2048) >> 5) << 6) | 32 | (j & 31));
        dst[(size_t)jp * 512 + r0 + tx] = tile[tx][ty + i];
    }
}

// ---------------- x = in; xn = LN(x)*g  (one row per WAVE, no barriers) ------
__global__ __launch_bounds__(256)
void xinit_ln_k(const void* __restrict__ in, const void* __restrict__ g,
                const int* __restrict__ flag, float* __restrict__ x, bf16* __restrict__ xn)
{
    int f = *flag;
    int row = blockIdx.x * 4 + (threadIdx.x >> 6);
    int lane = threadIdx.x & 63;
    int c0 = lane * 8;
    float v[8];
    ld8(in, (size_t)row * 512 + c0, f, v);
    // persist x as f32
    float* xr = x + (size_t)row * 512 + c0;
    *(float4*)xr       = make_float4(v[0], v[1], v[2], v[3]);
    *(float4*)(xr + 4) = make_float4(v[4], v[5], v[6], v[7]);
    float s = 0.f;
#pragma unroll
    for (int j = 0; j < 8; ++j) s += v[j];
    float mean = wave_sum(s) * (1.f / 512.f);
    float q = 0.f;
#pragma unroll
    for (int j = 0; j < 8; ++j) { float d = v[j] - mean; q += d * d; }
    float var = wave_sum(q) * (1.f / 512.f);
    float rstd = rsqrtf(var + 1e-5f);
    float gv[8];
    ld8(g, c0, f, gv);
    v8bf o;
#pragma unroll
    for (int j = 0; j < 8; ++j) o[j] = tobf((v[j] - mean) * rstd * gv[j]);
    *(v8bf*)(xn + (size_t)row * 512 + c0) = o;
}

// ------ x += LN(t)*g1 ; xn = LN(x)*g2  (one row per WAVE, no barriers) -------
__global__ __launch_bounds__(256)
void addln_ln_k(const bf16* __restrict__ tin, const void* __restrict__ g1, int g1off,
                const void* __restrict__ g2, int g2off, const int* __restrict__ flag,
                float* __restrict__ x, bf16* __restrict__ xn)
{
    int f = *flag;
    int row = blockIdx.x * 4 + (threadIdx.x >> 6);
    int lane = threadIdx.x & 63;
    int c0 = lane * 8;
    float tv[8];
    {
        v8bf a = *(const v8bf*)(tin + (size_t)row * 512 + c0);
#pragma unroll
        for (int j = 0; j < 8; ++j) tv[j] = (float)a[j];
    }
    float s = 0.f;
#pragma unroll
    for (int j = 0; j < 8; ++j) s += tv[j];
    float mean = wave_sum(s) * (1.f / 512.f);
    float q = 0.f;
#pragma unroll
    for (int j = 0; j < 8; ++j) { float d = tv[j] - mean; q += d * d; }
    float var = wave_sum(q) * (1.f / 512.f);
    float rstd = rsqrtf(var + 1e-5f);
    float g1v[8];
    ld8(g1, (size_t)g1off + c0, f, g1v);
    float* xr = x + (size_t)row * 512 + c0;
    float4 xa = *(float4*)xr, xb = *(float4*)(xr + 4);
    float nx[8] = {xa.x, xa.y, xa.z, xa.w, xb.x, xb.y, xb.z, xb.w};
#pragma unroll
    for (int j = 0; j < 8; ++j) nx[j] += (tv[j] - mean) * rstd * g1v[j];
    *(float4*)xr       = make_float4(nx[0], nx[1], nx[2], nx[3]);
    *(float4*)(xr + 4) = make_float4(nx[4], nx[5], nx[6], nx[7]);
    float s2 = 0.f;
#pragma unroll
    for (int j = 0; j < 8; ++j) s2 += nx[j];
    float mean2 = wave_sum(s2) * (1.f / 512.f);
    float q2 = 0.f;
#pragma unroll
    for (int j = 0; j < 8; ++j) { float e = nx[j] - mean2; q2 += e * e; }
    float var2 = wave_sum(q2) * (1.f / 512.f);
    float rstd2 = rsqrtf(var2 + 1e-5f);
    float g2v[8];
    ld8(g2, (size_t)g2off + c0, f, g2v);
    v8bf o;
#pragma unroll
    for (int j = 0; j < 8; ++j) o[j] = tobf((nx[j] - mean2) * rstd2 * g2v[j]);
    *(v8bf*)(xn + (size_t)row * 512 + c0) = o;
}

// -- x += t ; xn = (stable? stableLN : LN)(x)*g  (one row per WAVE) -----------
__global__ __launch_bounds__(256)
void add_ln_k(const bf16* __restrict__ tin, const void* __restrict__ g, int goff,
              const int* __restrict__ flag, int stable,
              float* __restrict__ x, bf16* __restrict__ xn)
{
    int f = *flag;
    int row = blockIdx.x * 4 + (threadIdx.x >> 6);
    int lane = threadIdx.x & 63;
    int c0 = lane * 8;
    float nx[8];
    {
        v8bf a = *(const v8bf*)(tin + (size_t)row * 512 + c0);
        float* xr = x + (size_t)row * 512 + c0;
        float4 xa = *(float4*)xr, xb = *(float4*)(xr + 4);
        float xv[8] = {xa.x, xa.y, xa.z, xa.w, xb.x, xb.y, xb.z, xb.w};
#pragma unroll
        for (int j = 0; j < 8; ++j) nx[j] = xv[j] + (float)a[j];
        *(float4*)xr       = make_float4(nx[0], nx[1], nx[2], nx[3]);
        *(float4*)(xr + 4) = make_float4(nx[4], nx[5], nx[6], nx[7]);
    }
    float v[8];
#pragma unroll
    for (int j = 0; j < 8; ++j) v[j] = nx[j];
    if (stable) {
        float m = v[0];
#pragma unroll
        for (int j = 1; j < 8; ++j) m = fmaxf(m, v[j]);
        float mx = wave_max(m);
#pragma unroll
        for (int j = 0; j < 8; ++j) v[j] /= mx;
    }
    float s = 0.f;
#pragma unroll
    for (int j = 0; j < 8; ++j) s += v[j];
    float mean = wave_sum(s) * (1.f / 512.f);
    float q = 0.f;
#pragma unroll
    for (int j = 0; j < 8; ++j) { float d = v[j] - mean; q += d * d; }
    float var = wave_sum(q) * (1.f / 512.f);
    float rstd = rsqrtf(var + 1e-5f);
    float gv[8];
    ld8(g, (size_t)goff + c0, f, gv);
    v8bf o;
#pragma unroll
    for (int j = 0; j < 8; ++j) o[j] = tobf((v[j] - mean) * rstd * gv[j]);
    *(v8bf*)(xn + (size_t)row * 512 + c0) = o;
}

// ---------------- rotary cos/sin table: tab[n*16+p] = (cos, sin) -------------
__global__ __launch_bounds__(256)
void rotab_k(float2* __restrict__ tab)
{
    int idx = blockIdx.x * 256 + threadIdx.x;
    if (idx >= 16384) return;
    int n = idx >> 4, p = idx & 15;
    float ang = (float)n * expf((float)p * -0.5756462732f);
    tab[idx] = make_float2(cosf(ang), sinf(ang));
}

// ---------------- rel-pos bias table (pre-offset by -16: fixed softmax max) --
// qn,kn are l2-normalized to norm 4 => s = qn.kn <= 16 (Cauchy-Schwarz), and
// |bias| << 1, so exp(s + bias - 16) <= ~1.11. Softmax is shift-invariant, so
// folding the -16 here lets attention skip online-max tracking entirely.
__global__ __launch_bounds__(256)
void bias_k(const void* __restrict__ rpe, const int* __restrict__ flag, float* __restrict__ tab)
{
    int f = *flag;
    int idx = blockIdx.x * 256 + threadIdx.x;
    if (idx >= 8 * 1025) return;
    int h = idx / 1025, dist = idx % 1025;
    int bkt;
    if (dist < 16) bkt = dist;
    else {
        bkt = 16 + (int)(logf((float)dist / 16.f) / logf(8.f) * 16.f);
        if (bkt > 31) bkt = 31;
    }
    tab[idx] = ldin(rpe, bkt * 8 + h, f) - 16.f;
}

// ---------------- merged q + k/v prep (qkv stride 640, rotary via table) -----
// blocks [0,2048): q rows, 16 per block (4/wave, 16 lanes x 4 els each).
// blocks [2048,3136): k/v rows j in [0,1088) x b (4352, 4/block, 1/wave).
__global__ __launch_bounds__(256)
void qkvprep_k(const bf16* __restrict__ qkv, const void* __restrict__ nkv, int nkoff,
               const int* __restrict__ flag, const float2* __restrict__ rtab,
               bf16* __restrict__ Q, bf16* __restrict__ K, bf16* __restrict__ Vt)
{
    int t = threadIdx.x, lane = t & 63;
    int bid = blockIdx.x;
    if (bid < 2048) {
        int rid = bid * 16 + (t >> 4);            // one row per 16-lane group
        int h = rid & 7;
        int n = (rid >> 3) & 1023;
        int b = rid >> 13;
        int g16 = t & 15;
        int d0 = g16 * 4;
        v4bf a = *(const v4bf*)(qkv + (size_t)((b << 10) | n) * 640 + h * 64 + d0);
        float v[4];
#pragma unroll
        for (int j = 0; j < 4; ++j) v[j] = (float)a[j] * 16.f;
        if (d0 < 32) {                            // rotary, pairs in-lane
            float4 cs = *(const float4*)((const float*)rtab + (size_t)n * 32 + (size_t)(d0 >> 1) * 2);
            float r0 = v[0] * cs.x - v[1] * cs.y;
            float r1 = v[1] * cs.x + v[0] * cs.y;
            float r2 = v[2] * cs.z - v[3] * cs.w;
            float r3 = v[3] * cs.z + v[2] * cs.w;
            v[0] = r0; v[1] = r1; v[2] = r2; v[3] = r3;
        }
        float ss = v[0]*v[0] + v[1]*v[1] + v[2]*v[2] + v[3]*v[3];
#pragma unroll
        for (int o = 1; o < 16; o <<= 1) ss += __shfl_xor(ss, o, 64);
        float sc = 4.f / fmaxf(sqrtf(ss), 1e-12f);
        v4bf ov;
#pragma unroll
        for (int j = 0; j < 4; ++j) ov[j] = tobf(v[j] * sc);
        *(v4bf*)(Q + (((size_t)(b * 8 + h)) * 1024 + n) * 64 + d0) = ov;
    } else {
        int f = *flag;
        int rid = (bid - 2048) * 4 + (t >> 6);
        if (rid >= 4 * 1088) return;
        int j = rid % 1088;
        int b = rid / 1088;
        if (j >= 1025) {
            K[((size_t)b * 1088 + j) * 64 + lane] = f2bf(0.f);
            Vt[((size_t)b * 64 + lane) * 1088 + j] = f2bf(0.f);
            return;
        }
        float kv, vv;
        if (j == 0) {
            kv = ldin(nkv, nkoff + lane, f);
            vv = ldin(nkv, nkoff + 64 + lane, f);
        } else {
            int n = j - 1;
            const bf16* src = qkv + (size_t)(b * 1024 + n) * 640 + 512;
            kv = bf2f(src[lane]);
            vv = bf2f(src[64 + lane]);
            if (lane < 32) {
                float2 cs = rtab[n * 16 + (lane >> 1)];
                float other = __shfl_xor(kv, 1, 64);
                float rot = (lane & 1) ? other : -other;
                kv = kv * cs.x + rot * cs.y;
            }
        }
        float nrm = sqrtf(wave_sum(kv * kv));
        kv = kv / fmaxf(nrm, 1e-12f) * 4.f;
        K[((size_t)b * 1088 + j) * 64 + lane] = f2bf(kv);
        Vt[((size_t)b * 64 + lane) * 1088 + j] = f2bf(vv);
    }
}

// ---------------- MFMA flash attention, K-SPLIT (S=4), FIXED-MAX softmax -----
// grid (B*H=32, 16 qtiles, 4 splits), block 256 = 4 waves (16 q-rows each).
// Bias table is pre-offset by -16 (guaranteed score upper bound), so no online
// max / rescale / per-chunk row-sum reductions: p = exp(s + bias'), l is a
// per-lane f32 partial reduced once at the end. K/V are prefetched into
// registers one chunk ahead (latency hidden under compute). Partials are
// plain sums; combine just adds.
__global__ __launch_bounds__(256)
void attn_mfma(const bf16* __restrict__ Q, const bf16* __restrict__ Kg,
               const bf16* __restrict__ Vtg, const float* __restrict__ bias,
               bf16* __restrict__ Op, float* __restrict__ ml)
{
    __shared__ bf16 Ks[64][72];
    __shared__ bf16 Vts[64][72];
    __shared__ bf16 Ps[4][16][72];
    __shared__ float bs[1088];
    const int bh = blockIdx.x, b = bh >> 3, h = bh & 7;
    const int yy = (int)gridDim.y - 1 - (int)blockIdx.y;   // longest first
    const int sp = blockIdx.z;
    const int i0 = yy * 64;
    const int t = threadIdx.x, lane = t & 63, w = t >> 6;
    const int col = lane & 15, quad = lane >> 4, fk = quad * 8;
    const float* bt = bias + h * 1025;
    const bf16* Kb = Kg + (size_t)b * 1088 * 64;
    const bf16* Vb = Vtg + (size_t)b * 64 * 1088;

    // stage bias row into LDS: dist range needed is [0, i0+63]
    for (int idx = t; idx < i0 + 64; idx += 256) bs[idx] = bt[idx];

    v8bf qf[2];
    const bf16* qrow = Q + ((size_t)bh * 1024 + i0 + w * 16 + col) * 64;
    qf[0] = *(const v8bf*)(qrow + fk);
    qf[1] = *(const v8bf*)(qrow + 32 + fk);

    v4f oacc[4];
#pragma unroll
    for (int dt = 0; dt < 4; ++dt) { v4f z = {0.f,0.f,0.f,0.f}; oacc[dt] = z; }
    float lpart[4] = {0.f, 0.f, 0.f, 0.f};

    const int nch = yy + 2;
    const int rr0 = t >> 3, co0 = (t & 7) * 8;          // rep 0 staging coords
    const int rr1 = (t + 256) >> 3, co1 = co0;          // rep 1 staging coords

    v8bf kr[2], vr[2];
    if (sp < nch) {
        int j0 = sp * 64;
        kr[0] = *(const v8bf*)(Kb + (size_t)(j0 + rr0) * 64 + co0);
        vr[0] = *(const v8bf*)(Vb + (size_t)rr0 * 1088 + j0 + co0);
        kr[1] = *(const v8bf*)(Kb + (size_t)(j0 + rr1) * 64 + co1);
        vr[1] = *(const v8bf*)(Vb + (size_t)rr1 * 1088 + j0 + co1);
    }

    for (int ch = sp; ch < nch; ch += 4) {
        const int j0 = ch * 64;
        __syncthreads();                                 // prev compute done w/ LDS
        *(v8bf*)(&Ks[rr0][co0])  = kr[0];
        *(v8bf*)(&Vts[rr0][co0]) = vr[0];
        *(v8bf*)(&Ks[rr1][co1])  = kr[1];
        *(v8bf*)(&Vts[rr1][co1]) = vr[1];
        const int more = (ch + 4 < nch);
        if (more) {                                      // prefetch next chunk
            int j0n = (ch + 4) * 64;
            kr[0] = *(const v8bf*)(Kb + (size_t)(j0n + rr0) * 64 + co0);
            vr[0] = *(const v8bf*)(Vb + (size_t)rr0 * 1088 + j0n + co0);
            kr[1] = *(const v8bf*)(Kb + (size_t)(j0n + rr1) * 64 + co1);
            vr[1] = *(const v8bf*)(Vb + (size_t)rr1 * 1088 + j0n + co1);
        }
        __syncthreads();

        // QK^T
        v4f sreg[4];
#pragma unroll
        for (int nt = 0; nt < 4; ++nt) {
            v4f z = {0.f,0.f,0.f,0.f};
            v8bf kf0 = *(const v8bf*)(&Ks[nt * 16 + col][fk]);
            v8bf kf1 = *(const v8bf*)(&Ks[nt * 16 + col][32 + fk]);
            z = __builtin_amdgcn_mfma_f32_16x16x32_bf16(qf[0], kf0, z, 0, 0, 0);
            z = __builtin_amdgcn_mfma_f32_16x16x32_bf16(qf[1], kf1, z, 0, 0, 0);
            sreg[nt] = z;
        }

        // p = exp(s + bias - 16); no max tracking, no cross-lane ops.
        if (ch < yy) {
            // fully-interior chunk: no causal/pad mask, dist always >= 1
#pragma unroll
            for (int reg = 0; reg < 4; ++reg) {
                int i = i0 + w * 16 + quad * 4 + reg;
                int dbase = i - j0 - col;
#pragma unroll
                for (int nt = 0; nt < 4; ++nt) {
                    float pp = __expf(sreg[nt][reg] + bs[dbase - nt * 16]);
                    lpart[reg] += pp;
                    Ps[w][quad * 4 + reg][nt * 16 + col] = f2bf(pp);
                }
            }
        } else {
#pragma unroll
            for (int reg = 0; reg < 4; ++reg) {
                int i = i0 + w * 16 + quad * 4 + reg;
#pragma unroll
                for (int nt = 0; nt < 4; ++nt) {
                    int j = j0 + nt * 16 + col;
                    float pp = 0.f;
                    if (j <= i + 1 && j < 1025) {
                        int dist = i - j; if (dist < 0) dist = 0;
                        pp = __expf(sreg[nt][reg] + bs[dist]);
                    }
                    lpart[reg] += pp;
                    Ps[w][quad * 4 + reg][nt * 16 + col] = f2bf(pp);
                }
            }
        }

        // PV
        v8bf pf[2];
        pf[0] = *(const v8bf*)(&Ps[w][col][fk]);
        pf[1] = *(const v8bf*)(&Ps[w][col][32 + fk]);
#pragma unroll
        for (int dt = 0; dt < 4; ++dt) {
#pragma unroll
            for (int ks = 0; ks < 2; ++ks) {
                v8bf vf = *(const v8bf*)(&Vts[dt * 16 + col][ks * 32 + fk]);
                oacc[dt] = __builtin_amdgcn_mfma_f32_16x16x32_bf16(pf[ks], vf, oacc[dt], 0, 0, 0);
            }
        }
    }

    // single deferred l reduction (16 cols per row)
#pragma unroll
    for (int reg = 0; reg < 4; ++reg) {
#pragma unroll
        for (int o = 1; o < 16; o <<= 1) lpart[reg] += __shfl_xor(lpart[reg], o, 64);
    }

    // write UNNORMALIZED partials: Op[((sp*32+bh)*1024+i)*64+d], ml[...] = l
#pragma unroll
    for (int reg = 0; reg < 4; ++reg) {
        int i = i0 + w * 16 + quad * 4 + reg;
        size_t rbase = ((size_t)(sp * 32 + bh) * 1024 + i);
#pragma unroll
        for (int dt = 0; dt < 4; ++dt)
            Op[rbase * 64 + dt * 16 + col] = f2bf(oacc[dt][reg]);
        if (col == 0) ml[rbase] = lpart[reg];
    }
}

// -------- combine 4 k-split partials (plain sums, 8 els/thread) --------------
__global__ __launch_bounds__(256)
void attn_comb(const bf16* __restrict__ Op, const float* __restrict__ ml,
               bf16* __restrict__ O)
{
    int tid = blockIdx.x * 256 + threadIdx.x;   // 262144 threads x 8 els
    int r = tid >> 3;                           // bh*1024 + i
    int d0 = (tid & 7) * 8;
    float l = ml[r] + ml[32768 + r] + ml[65536 + r] + ml[98304 + r];
    float inv = 1.f / l;
    v8bf p0 = *(const v8bf*)(Op + (size_t)r * 64 + d0);
    v8bf p1 = *(const v8bf*)(Op + ((size_t)32768 + r) * 64 + d0);
    v8bf p2 = *(const v8bf*)(Op + ((size_t)65536 + r) * 64 + d0);
    v8bf p3 = *(const v8bf*)(Op + ((size_t)98304 + r) * 64 + d0);
    v8bf o;
#pragma unroll
    for (int j = 0; j < 8; ++j)
        o[j] = tobf(((float)p0[j] + (float)p1[j] + (float)p2[j] + (float)p3[j]) * inv);
    int bh = r >> 10, i = r & 1023, b = bh >> 3, h = bh & 7;
    *(v8bf*)(O + ((size_t)(b * 1024 + i)) * 512 + h * 64 + d0) = o;
}

// =============================================================================
extern "C" void kernel_launch(void* const* d_in, const int* in_sizes, int n_in,
                              void* d_out, int out_size, void* d_ws, size_t ws_size,
                              hipStream_t stream)
{
    const void* x_in     = d_in[0];
    const void* rpe      = d_in[1];
    const void* g_attn   = d_in[2];
    const void* null_kv  = d_in[3];
    const void* Wq       = d_in[4];
    const void* Wkv      = d_in[5];
    const void* Wo       = d_in[6];
    const void* g_attn_o = d_in[7];
    const void* g_ff     = d_in[8];
    const void* W1       = d_in[9];
    const void* W2       = d_in[10];
    const void* g_final  = d_in[11];
    const void* W_proj   = d_in[12];

    char* wp = (char*)d_ws;
    auto alloc = [&](size_t bytes) {
        char* p = wp; wp += (bytes + 255) & ~(size_t)255; return p;
    };
    float* xf    = (float*)alloc(4096ull * 512 * 4);
    bf16*  xn    = (bf16*) alloc(4096ull * 512 * 2);
    bf16*  tb    = (bf16*) alloc(4096ull * 512 * 2);
    bf16*  ub    = (bf16*) alloc(4096ull * 4096 * 2);
    bf16*  Kb    = (bf16*) alloc(4ull * 1088 * 64 * 2);
    bf16*  Vtb   = (bf16*) alloc(4ull * 64 * 1088 * 2);
    float* btab  = (float*)alloc(8ull * 1025 * 4);
    float2* rtab = (float2*)alloc(16384ull * 8);
    int*   dfl   = (int*)  alloc(256);
    bf16*  WqkvT = (bf16*) alloc(6ull * 640 * 512 * 2);
    bf16*  WoT   = (bf16*) alloc(6ull * 512 * 512 * 2);
    bf16*  W1T   = (bf16*) alloc(6ull * 4096 * 512 * 2);
    bf16*  W2T   = (bf16*) alloc(6ull * 512 * 2048 * 2);
    bf16*  WpT   = (bf16*) alloc(512ull * 512 * 2);
    // aliased into ub (16,777,216 elems; lifetimes end before W1 gemm writes ub)
    bf16*  qkvb  = ub;                        // 2,621,440 elems
    bf16*  Qb    = ub + 2621440;              // 2,097,152
    bf16*  ob    = ub + 4718592;              // 2,097,152
    bf16*  Opart = ub + 6815744;              // 4*32*1024*64 = 8,388,608
    float* mlprt = (float*)(ub + 15204352);   // 131,072 floats = 262,144 elems

    detect_k<<<1, 256, 0, stream>>>((const unsigned short*)x_in, dfl);
    transpose2_k<<<dim3(16, 16, 6),  dim3(32, 8), 0, stream>>>(Wq, WqkvT, 512, 512, 512ull*512, 640ull*512, dfl);
    transpose2_k<<<dim3(4, 16, 6),   dim3(32, 8), 0, stream>>>(Wkv, WqkvT + 512ull*512, 512, 128, 512ull*128, 640ull*512, dfl);
    transpose2_k<<<dim3(16, 16, 6),  dim3(32, 8), 0, stream>>>(Wo, WoT, 512, 512, 512ull*512, 512ull*512, dfl);
    transposeW1_k<<<dim3(128, 16, 6), dim3(32, 8), 0, stream>>>(W1, W1T, dfl);
    transpose2_k<<<dim3(16, 64, 6),  dim3(32, 8), 0, stream>>>(W2, W2T, 2048, 512, 2048ull*512, 2048ull*512, dfl);
    transpose2_k<<<dim3(16, 16, 1),  dim3(32, 8), 0, stream>>>(W_proj, WpT, 512, 512, 512ull*512, 512ull*512, dfl);
    bias_k<<<33, 256, 0, stream>>>(rpe, dfl, btab);
    rotab_k<<<64, 256, 0, stream>>>(rtab);
    xinit_ln_k<<<1024, 256, 0, stream>>>(x_in, g_attn, dfl, xf, xn);

    for (int l = 0; l < 6; ++l) {
        gemm64<<<dim3(64, 5), 256, 0, stream>>>(xn, WqkvT + (size_t)l * 640 * 512, qkvb, 4096, 640, 512, 512);
        qkvprep_k<<<3136, 256, 0, stream>>>(qkvb, null_kv, l * 128, dfl, rtab, Qb, Kb, Vtb);
        attn_mfma<<<dim3(32, 16, 4), 256, 0, stream>>>(Qb, Kb, Vtb, btab, Opart, mlprt);
        attn_comb<<<1024, 256, 0, stream>>>(Opart, mlprt, ob);
        gemm64<<<dim3(64, 4), 256, 0, stream>>>(ob, WoT + (size_t)l * 512 * 512, tb, 4096, 512, 512, 512);
        addln_ln_k<<<1024, 256, 0, stream>>>(tb, g_attn_o, l * 512, g_ff, l * 512, dfl, xf, xn);
        gemm_bt_silu<<<dim3(32, 32), 256, 0, stream>>>(xn, W1T + (size_t)l * 4096 * 512, ub, 512, 512);
        gemm64<<<dim3(64, 4), 256, 0, stream>>>(ub, W2T + (size_t)l * 512 * 2048, tb, 4096, 512, 2048, 2048);
        if (l < 5)
            add_ln_k<<<1024, 256, 0, stream>>>(tb, g_attn, (l + 1) * 512, dfl, 0, xf, xn);
        else
            add_ln_k<<<1024, 256, 0, stream>>>(tb, g_final, 0, dfl, 1, xf, xn);
    }
    gemm64_out<<<dim3(64, 4), 256, 0, stream>>>(xn, WpT, d_out, 4096, 512, 512, 512, dfl);
}

// Round 4
// 935.971 us; speedup vs baseline: 1.3423x; 1.0293x over previous
//
#include <hip/hip_runtime.h>
#include <hip/hip_bf16.h>
#include <cmath>

using bf16 = __hip_bfloat16;
typedef __bf16 v8bf __attribute__((ext_vector_type(8)));
typedef __bf16 v4bf __attribute__((ext_vector_type(4)));
typedef float  v4f  __attribute__((ext_vector_type(4)));

__device__ __forceinline__ float bf2f(bf16 x) { return __bfloat162float(x); }
__device__ __forceinline__ bf16  f2bf(float x) { return __float2bfloat16(x); }
__device__ __forceinline__ __bf16 tobf(float x) {
    bf16 h = __float2bfloat16(x);
    return __builtin_bit_cast(__bf16, h);
}

// async global->LDS, 16B per lane (lds dest = wave-uniform base + lane*16)
__device__ __forceinline__ void gll16(const bf16* g, bf16* l) {
    __builtin_amdgcn_global_load_lds(
        (const __attribute__((address_space(1))) unsigned int*)g,
        (__attribute__((address_space(3))) unsigned int*)l, 16, 0, 0);
}

__device__ __forceinline__ float ldin(const void* p, size_t i, int isf32) {
    if (isf32) return ((const float*)p)[i];
    return bf2f(((const bf16*)p)[i]);
}

// flag-dtype vector load of 8 consecutive elements
__device__ __forceinline__ void ld8(const void* p, size_t base, int f, float v[8]) {
    if (f) {
        const float* pf = (const float*)p + base;
        float4 a = *(const float4*)pf, b = *(const float4*)(pf + 4);
        v[0]=a.x; v[1]=a.y; v[2]=a.z; v[3]=a.w;
        v[4]=b.x; v[5]=b.y; v[6]=b.z; v[7]=b.w;
    } else {
        v8bf a = *(const v8bf*)((const bf16*)p + base);
#pragma unroll
        for (int j = 0; j < 8; ++j) v[j] = (float)a[j];
    }
}

__device__ __forceinline__ float wave_sum(float v) {
#pragma unroll
    for (int o = 32; o > 0; o >>= 1) v += __shfl_xor(v, o, 64);
    return v;
}
__device__ __forceinline__ float wave_max(float v) {
#pragma unroll
    for (int o = 32; o > 0; o >>= 1) v = fmaxf(v, __shfl_xor(v, o, 64));
    return v;
}

// ---------------- dtype detector -------------------------------------------
__global__ void detect_k(const unsigned short* __restrict__ x, int* __restrict__ flag)
{
    __shared__ int s;
    int t = threadIdx.x;
    if (t == 0) s = 0;
    __syncthreads();
    int bad = 0;
    for (int i = t; i < 4096; i += 256) {
        int e = (x[i] >> 7) & 0xFF;
        if (e >= 147) bad++;
    }
    atomicAdd(&s, bad);
    __syncthreads();
    if (t == 0) *flag = (s > 64) ? 1 : 0;
}

// LDS bank-swizzle note (all GEMM kernels): rows are 32 bf16 (64B) so plain
// chunk order puts the 16 fr-lanes of a ds_read_b128 on 2 bank-groups (8-way).
// We XOR the 16B-chunk index with ((row>>1)&3): LDS dest of gload_lds stays
// LINEAR (rule: wave-uniform base + lane*16); the SOURCE k-chunk is picked
// pre-swizzled, and the fragment read applies the same involution.
//   stage:  koff = ((c&3) ^ ((row>>1)&3)) * 8
//   read:   fk   = (quad ^ ((fr>>1)&3)) * 8
// 16 lanes now cover all 8 bank-groups (2-way aliasing = free).

// ---------------- MFMA GEMM 128x128 + fused SiLU epilogue --------------------
// BT is the PERMUTED W1^T: row j' = group g=j'>>6, s=j'&63; s<32 -> a-col
// g*32+s, s>=32 -> gate-col 2048+g*32+(s-32). So acc[mt][nt] (nt<2) pairs with
// acc[mt][nt+2] as (a, gate) for output col g*32+nt*16+fr. U is 4096x2048.
__global__ __launch_bounds__(256)
void gemm_bt_silu(const bf16* __restrict__ A, const bf16* __restrict__ BT,
                  bf16* __restrict__ U, int K, int lda)
{
    __shared__ bf16 As[128 * 32];
    __shared__ bf16 Bs[128 * 32];
    const int t = threadIdx.x;
    const int lane = t & 63;
    const int wave = t >> 6;
    const int wm = (wave >> 1) * 64;
    const int wn = (wave & 1) * 64;
    const int bm = blockIdx.x * 128;
    const int bn = blockIdx.y * 128;
    const int fr = lane & 15;
    const int fk = (((lane >> 4) ^ ((fr >> 1) & 3))) * 8;

    v4f acc[4][4];
#pragma unroll
    for (int i = 0; i < 4; ++i)
#pragma unroll
        for (int j = 0; j < 4; ++j) { v4f z = {0.f, 0.f, 0.f, 0.f}; acc[i][j] = z; }

    for (int k0 = 0; k0 < K; k0 += 32) {
#pragma unroll
        for (int r = 0; r < 2; ++r) {
            int c = t + 256 * r;
            int row = c >> 2;
            int koff = ((c & 3) ^ ((row >> 1) & 3)) * 8;
            gll16(A + (size_t)(bm + row) * lda + k0 + koff, &As[c * 8]);
            gll16(BT + (size_t)(bn + row) * K + k0 + koff, &Bs[c * 8]);
        }
        __syncthreads();
        v8bf af[4], bfr[4];
#pragma unroll
        for (int mt = 0; mt < 4; ++mt)
            af[mt] = *(const v8bf*)(&As[(wm + mt * 16 + fr) * 32 + fk]);
#pragma unroll
        for (int nt = 0; nt < 4; ++nt)
            bfr[nt] = *(const v8bf*)(&Bs[(wn + nt * 16 + fr) * 32 + fk]);
#pragma unroll
        for (int mt = 0; mt < 4; ++mt)
#pragma unroll
            for (int nt = 0; nt < 4; ++nt)
                acc[mt][nt] = __builtin_amdgcn_mfma_f32_16x16x32_bf16(
                    af[mt], bfr[nt], acc[mt][nt], 0, 0, 0);
        __syncthreads();
    }
    const int r0 = (lane >> 4) * 4;
    const int gbase = ((bn + wn) >> 6) * 32;
#pragma unroll
    for (int mt = 0; mt < 4; ++mt)
#pragma unroll
        for (int nt = 0; nt < 2; ++nt)
#pragma unroll
            for (int r = 0; r < 4; ++r) {
                int row = bm + wm + mt * 16 + r0 + r;
                int col = gbase + nt * 16 + fr;
                float a  = acc[mt][nt][r];
                float gg = acc[mt][nt + 2][r];
                U[(size_t)row * 2048 + col] = f2bf(a * (gg / (1.f + __expf(-gg))));
            }
}

// ---------------- MFMA GEMM 64x128 tile (async LDS staging) ------------------
__global__ __launch_bounds__(256)
void gemm64(const bf16* __restrict__ A, const bf16* __restrict__ BT,
            bf16* __restrict__ C, int M, int N, int K, int lda)
{
    __shared__ bf16 As[64 * 32];
    __shared__ bf16 Bs[128 * 32];
    const int t = threadIdx.x;
    const int lane = t & 63;
    const int wave = t >> 6;
    const int wm = (wave >> 1) * 32;
    const int wn = (wave & 1) * 64;
    const int bm = blockIdx.x * 64;
    const int bn = blockIdx.y * 128;
    const int fr = lane & 15;
    const int fk = (((lane >> 4) ^ ((fr >> 1) & 3))) * 8;

    v4f acc[2][4];
#pragma unroll
    for (int i = 0; i < 2; ++i)
#pragma unroll
        for (int j = 0; j < 4; ++j) { v4f z = {0.f, 0.f, 0.f, 0.f}; acc[i][j] = z; }

    for (int k0 = 0; k0 < K; k0 += 32) {
        {
            int row = t >> 2;
            int koff = ((t & 3) ^ ((row >> 1) & 3)) * 8;
            gll16(A + (size_t)(bm + row) * lda + k0 + koff, &As[t * 8]);
        }
#pragma unroll
        for (int r = 0; r < 2; ++r) {
            int c = t + 256 * r;
            int row = c >> 2;
            int koff = ((c & 3) ^ ((row >> 1) & 3)) * 8;
            gll16(BT + (size_t)(bn + row) * K + k0 + koff, &Bs[c * 8]);
        }
        __syncthreads();
        v8bf af[2], bfr[4];
#pragma unroll
        for (int mt = 0; mt < 2; ++mt)
            af[mt] = *(const v8bf*)(&As[(wm + mt * 16 + fr) * 32 + fk]);
#pragma unroll
        for (int nt = 0; nt < 4; ++nt)
            bfr[nt] = *(const v8bf*)(&Bs[(wn + nt * 16 + fr) * 32 + fk]);
#pragma unroll
        for (int mt = 0; mt < 2; ++mt)
#pragma unroll
            for (int nt = 0; nt < 4; ++nt)
                acc[mt][nt] = __builtin_amdgcn_mfma_f32_16x16x32_bf16(
                    af[mt], bfr[nt], acc[mt][nt], 0, 0, 0);
        __syncthreads();
    }
    const int r0 = (lane >> 4) * 4;
#pragma unroll
    for (int mt = 0; mt < 2; ++mt)
#pragma unroll
        for (int nt = 0; nt < 4; ++nt)
#pragma unroll
            for (int r = 0; r < 4; ++r) {
                int row = bm + wm + mt * 16 + r0 + r;
                int col = bn + wn + nt * 16 + fr;
                C[(size_t)row * N + col] = f2bf(acc[mt][nt][r]);
            }
}

// ---- gemm64 with flag-selected output dtype (final projection) --------------
__global__ __launch_bounds__(256)
void gemm64_out(const bf16* __restrict__ A, const bf16* __restrict__ BT,
                void* __restrict__ C, int M, int N, int K, int lda,
                const int* __restrict__ flag)
{
    __shared__ bf16 As[64 * 32];
    __shared__ bf16 Bs[128 * 32];
    const int f = *flag;
    const int t = threadIdx.x;
    const int lane = t & 63;
    const int wave = t >> 6;
    const int wm = (wave >> 1) * 32;
    const int wn = (wave & 1) * 64;
    const int bm = blockIdx.x * 64;
    const int bn = blockIdx.y * 128;
    const int fr = lane & 15;
    const int fk = (((lane >> 4) ^ ((fr >> 1) & 3))) * 8;

    v4f acc[2][4];
#pragma unroll
    for (int i = 0; i < 2; ++i)
#pragma unroll
        for (int j = 0; j < 4; ++j) { v4f z = {0.f, 0.f, 0.f, 0.f}; acc[i][j] = z; }

    for (int k0 = 0; k0 < K; k0 += 32) {
        {
            int row = t >> 2;
            int koff = ((t & 3) ^ ((row >> 1) & 3)) * 8;
            gll16(A + (size_t)(bm + row) * lda + k0 + koff, &As[t * 8]);
        }
#pragma unroll
        for (int r = 0; r < 2; ++r) {
            int c = t + 256 * r;
            int row = c >> 2;
            int koff = ((c & 3) ^ ((row >> 1) & 3)) * 8;
            gll16(BT + (size_t)(bn + row) * K + k0 + koff, &Bs[c * 8]);
        }
        __syncthreads();
        v8bf af[2], bfr[4];
#pragma unroll
        for (int mt = 0; mt < 2; ++mt)
            af[mt] = *(const v8bf*)(&As[(wm + mt * 16 + fr) * 32 + fk]);
#pragma unroll
        for (int nt = 0; nt < 4; ++nt)
            bfr[nt] = *(const v8bf*)(&Bs[(wn + nt * 16 + fr) * 32 + fk]);
#pragma unroll
        for (int mt = 0; mt < 2; ++mt)
#pragma unroll
            for (int nt = 0; nt < 4; ++nt)
                acc[mt][nt] = __builtin_amdgcn_mfma_f32_16x16x32_bf16(
                    af[mt], bfr[nt], acc[mt][nt], 0, 0, 0);
        __syncthreads();
    }
    const int r0 = (lane >> 4) * 4;
#pragma unroll
    for (int mt = 0; mt < 2; ++mt)
#pragma unroll
        for (int nt = 0; nt < 4; ++nt)
#pragma unroll
            for (int r = 0; r < 4; ++r) {
                int row = bm + wm + mt * 16 + r0 + r;
                int col = bn + wn + nt * 16 + fr;
                if (f) ((float*)C)[(size_t)row * N + col] = acc[mt][nt][r];
                else   ((bf16*)C)[(size_t)row * N + col] = f2bf(acc[mt][nt][r]);
            }
}

// ---------------- transpose w/ separate z-strides ----------------------------
__global__ __launch_bounds__(256)
void transpose2_k(const void* __restrict__ in, bf16* __restrict__ out, int R, int C,
                  size_t inZ, size_t outZ, const int* __restrict__ flag)
{
    __shared__ bf16 tile[32][33];
    int f = *flag;
    size_t ioff = (size_t)blockIdx.z * inZ;
    bf16* dst = out + (size_t)blockIdx.z * outZ;
    int c0 = blockIdx.x * 32, r0 = blockIdx.y * 32;
    int tx = threadIdx.x, ty = threadIdx.y;
#pragma unroll
    for (int i = 0; i < 32; i += 8)
        tile[ty + i][tx] = f2bf(ldin(in, ioff + (size_t)(r0 + ty + i) * C + c0 + tx, f));
    __syncthreads();
#pragma unroll
    for (int i = 0; i < 32; i += 8)
        dst[(size_t)(c0 + ty + i) * R + r0 + tx] = tile[tx][ty + i];
}

// ---------------- W1 transpose with a/gate interleave permutation ------------
// out row j' for orig col j: j<2048 (a): j' = (j>>5)*64 + (j&31);
// j>=2048 (gate): j' = ((j-2048)>>5)*64 + 32 + (j&31).
__global__ __launch_bounds__(256)
void transposeW1_k(const void* __restrict__ in, bf16* __restrict__ out,
                   const int* __restrict__ flag)
{
    __shared__ bf16 tile[32][33];
    int f = *flag;
    size_t ioff = (size_t)blockIdx.z * (512ull * 4096);
    bf16* dst = out + (size_t)blockIdx.z * (512ull * 4096);
    int c0 = blockIdx.x * 32, r0 = blockIdx.y * 32;
    int tx = threadIdx.x, ty = threadIdx.y;
#pragma unroll
    for (int i = 0; i < 32; i += 8)
        tile[ty + i][tx] = f2bf(ldin(in, ioff + (size_t)(r0 + ty + i) * 4096 + c0 + tx, f));
    __syncthreads();
#pragma unroll
    for (int i = 0; i < 32; i += 8) {
        int j = c0 + ty + i;
        int jp = (j < 2048) ? (((j >> 5) << 6) | (j & 31))
                            : ((((j - 2048) >> 5) << 6) | 32 | (j & 31));
        dst[(size_t)jp * 512 + r0 + tx] = tile[tx][ty + i];
    }
}

// ---------------- x = in; xn = LN(x)*g  (one row per WAVE, no barriers) ------
__global__ __launch_bounds__(256)
void xinit_ln_k(const void* __restrict__ in, const void* __restrict__ g,
                const int* __restrict__ flag, float* __restrict__ x, bf16* __restrict__ xn)
{
    int f = *flag;
    int row = blockIdx.x * 4 + (threadIdx.x >> 6);
    int lane = threadIdx.x & 63;
    int c0 = lane * 8;
    float v[8];
    ld8(in, (size_t)row * 512 + c0, f, v);
    // persist x as f32
    float* xr = x + (size_t)row * 512 + c0;
    *(float4*)xr       = make_float4(v[0], v[1], v[2], v[3]);
    *(float4*)(xr + 4) = make_float4(v[4], v[5], v[6], v[7]);
    float s = 0.f;
#pragma unroll
    for (int j = 0; j < 8; ++j) s += v[j];
    float mean = wave_sum(s) * (1.f / 512.f);
    float q = 0.f;
#pragma unroll
    for (int j = 0; j < 8; ++j) { float d = v[j] - mean; q += d * d; }
    float var = wave_sum(q) * (1.f / 512.f);
    float rstd = rsqrtf(var + 1e-5f);
    float gv[8];
    ld8(g, c0, f, gv);
    v8bf o;
#pragma unroll
    for (int j = 0; j < 8; ++j) o[j] = tobf((v[j] - mean) * rstd * gv[j]);
    *(v8bf*)(xn + (size_t)row * 512 + c0) = o;
}

// ------ x += LN(t)*g1 ; xn = LN(x)*g2  (one row per WAVE, no barriers) -------
__global__ __launch_bounds__(256)
void addln_ln_k(const bf16* __restrict__ tin, const void* __restrict__ g1, int g1off,
                const void* __restrict__ g2, int g2off, const int* __restrict__ flag,
                float* __restrict__ x, bf16* __restrict__ xn)
{
    int f = *flag;
    int row = blockIdx.x * 4 + (threadIdx.x >> 6);
    int lane = threadIdx.x & 63;
    int c0 = lane * 8;
    float tv[8];
    {
        v8bf a = *(const v8bf*)(tin + (size_t)row * 512 + c0);
#pragma unroll
        for (int j = 0; j < 8; ++j) tv[j] = (float)a[j];
    }
    float s = 0.f;
#pragma unroll
    for (int j = 0; j < 8; ++j) s += tv[j];
    float mean = wave_sum(s) * (1.f / 512.f);
    float q = 0.f;
#pragma unroll
    for (int j = 0; j < 8; ++j) { float d = tv[j] - mean; q += d * d; }
    float var = wave_sum(q) * (1.f / 512.f);
    float rstd = rsqrtf(var + 1e-5f);
    float g1v[8];
    ld8(g1, (size_t)g1off + c0, f, g1v);
    float* xr = x + (size_t)row * 512 + c0;
    float4 xa = *(float4*)xr, xb = *(float4*)(xr + 4);
    float nx[8] = {xa.x, xa.y, xa.z, xa.w, xb.x, xb.y, xb.z, xb.w};
#pragma unroll
    for (int j = 0; j < 8; ++j) nx[j] += (tv[j] - mean) * rstd * g1v[j];
    *(float4*)xr       = make_float4(nx[0], nx[1], nx[2], nx[3]);
    *(float4*)(xr + 4) = make_float4(nx[4], nx[5], nx[6], nx[7]);
    float s2 = 0.f;
#pragma unroll
    for (int j = 0; j < 8; ++j) s2 += nx[j];
    float mean2 = wave_sum(s2) * (1.f / 512.f);
    float q2 = 0.f;
#pragma unroll
    for (int j = 0; j < 8; ++j) { float e = nx[j] - mean2; q2 += e * e; }
    float var2 = wave_sum(q2) * (1.f / 512.f);
    float rstd2 = rsqrtf(var2 + 1e-5f);
    float g2v[8];
    ld8(g2, (size_t)g2off + c0, f, g2v);
    v8bf o;
#pragma unroll
    for (int j = 0; j < 8; ++j) o[j] = tobf((nx[j] - mean2) * rstd2 * g2v[j]);
    *(v8bf*)(xn + (size_t)row * 512 + c0) = o;
}

// -- x += t ; xn = (stable? stableLN : LN)(x)*g  (one row per WAVE) -----------
__global__ __launch_bounds__(256)
void add_ln_k(const bf16* __restrict__ tin, const void* __restrict__ g, int goff,
              const int* __restrict__ flag, int stable,
              float* __restrict__ x, bf16* __restrict__ xn)
{
    int f = *flag;
    int row = blockIdx.x * 4 + (threadIdx.x >> 6);
    int lane = threadIdx.x & 63;
    int c0 = lane * 8;
    float nx[8];
    {
        v8bf a = *(const v8bf*)(tin + (size_t)row * 512 + c0);
        float* xr = x + (size_t)row * 512 + c0;
        float4 xa = *(float4*)xr, xb = *(float4*)(xr + 4);
        float xv[8] = {xa.x, xa.y, xa.z, xa.w, xb.x, xb.y, xb.z, xb.w};
#pragma unroll
        for (int j = 0; j < 8; ++j) nx[j] = xv[j] + (float)a[j];
        *(float4*)xr       = make_float4(nx[0], nx[1], nx[2], nx[3]);
        *(float4*)(xr + 4) = make_float4(nx[4], nx[5], nx[6], nx[7]);
    }
    float v[8];
#pragma unroll
    for (int j = 0; j < 8; ++j) v[j] = nx[j];
    if (stable) {
        float m = v[0];
#pragma unroll
        for (int j = 1; j < 8; ++j) m = fmaxf(m, v[j]);
        float mx = wave_max(m);
#pragma unroll
        for (int j = 0; j < 8; ++j) v[j] /= mx;
    }
    float s = 0.f;
#pragma unroll
    for (int j = 0; j < 8; ++j) s += v[j];
    float mean = wave_sum(s) * (1.f / 512.f);
    float q = 0.f;
#pragma unroll
    for (int j = 0; j < 8; ++j) { float d = v[j] - mean; q += d * d; }
    float var = wave_sum(q) * (1.f / 512.f);
    float rstd = rsqrtf(var + 1e-5f);
    float gv[8];
    ld8(g, (size_t)goff + c0, f, gv);
    v8bf o;
#pragma unroll
    for (int j = 0; j < 8; ++j) o[j] = tobf((v[j] - mean) * rstd * gv[j]);
    *(v8bf*)(xn + (size_t)row * 512 + c0) = o;
}

// ---------------- rotary cos/sin table: tab[n*16+p] = (cos, sin) -------------
__global__ __launch_bounds__(256)
void rotab_k(float2* __restrict__ tab)
{
    int idx = blockIdx.x * 256 + threadIdx.x;
    if (idx >= 16384) return;
    int n = idx >> 4, p = idx & 15;
    float ang = (float)n * expf((float)p * -0.5756462732f);
    tab[idx] = make_float2(cosf(ang), sinf(ang));
}

// ---------------- rel-pos bias table (pre-offset by -16: fixed softmax max) --
// qn,kn are l2-normalized to norm 4 => s = qn.kn <= 16 (Cauchy-Schwarz), and
// |bias| << 1, so exp(s + bias - 16) <= ~1.11. Softmax is shift-invariant, so
// folding the -16 here lets attention skip online-max tracking entirely.
__global__ __launch_bounds__(256)
void bias_k(const void* __restrict__ rpe, const int* __restrict__ flag, float* __restrict__ tab)
{
    int f = *flag;
    int idx = blockIdx.x * 256 + threadIdx.x;
    if (idx >= 8 * 1025) return;
    int h = idx / 1025, dist = idx % 1025;
    int bkt;
    if (dist < 16) bkt = dist;
    else {
        bkt = 16 + (int)(logf((float)dist / 16.f) / logf(8.f) * 16.f);
        if (bkt > 31) bkt = 31;
    }
    tab[idx] = ldin(rpe, bkt * 8 + h, f) - 16.f;
}

// ---------------- merged q + k/v prep (qkv stride 640, rotary via table) -----
// blocks [0,2048): q rows, 16 per block (4/wave, 16 lanes x 4 els each).
// blocks [2048,3136): k/v rows j in [0,1088) x b (4352, 4/block, 1/wave).
__global__ __launch_bounds__(256)
void qkvprep_k(const bf16* __restrict__ qkv, const void* __restrict__ nkv, int nkoff,
               const int* __restrict__ flag, const float2* __restrict__ rtab,
               bf16* __restrict__ Q, bf16* __restrict__ K, bf16* __restrict__ Vt)
{
    int t = threadIdx.x, lane = t & 63;
    int bid = blockIdx.x;
    if (bid < 2048) {
        int rid = bid * 16 + (t >> 4);            // one row per 16-lane group
        int h = rid & 7;
        int n = (rid >> 3) & 1023;
        int b = rid >> 13;
        int g16 = t & 15;
        int d0 = g16 * 4;
        v4bf a = *(const v4bf*)(qkv + (size_t)((b << 10) | n) * 640 + h * 64 + d0);
        float v[4];
#pragma unroll
        for (int j = 0; j < 4; ++j) v[j] = (float)a[j] * 16.f;
        if (d0 < 32) {                            // rotary, pairs in-lane
            float4 cs = *(const float4*)((const float*)rtab + (size_t)n * 32 + (size_t)(d0 >> 1) * 2);
            float r0 = v[0] * cs.x - v[1] * cs.y;
            float r1 = v[1] * cs.x + v[0] * cs.y;
            float r2 = v[2] * cs.z - v[3] * cs.w;
            float r3 = v[3] * cs.z + v[2] * cs.w;
            v[0] = r0; v[1] = r1; v[2] = r2; v[3] = r3;
        }
        float ss = v[0]*v[0] + v[1]*v[1] + v[2]*v[2] + v[3]*v[3];
#pragma unroll
        for (int o = 1; o < 16; o <<= 1) ss += __shfl_xor(ss, o, 64);
        float sc = 4.f / fmaxf(sqrtf(ss), 1e-12f);
        v4bf ov;
#pragma unroll
        for (int j = 0; j < 4; ++j) ov[j] = tobf(v[j] * sc);
        *(v4bf*)(Q + (((size_t)(b * 8 + h)) * 1024 + n) * 64 + d0) = ov;
    } else {
        int f = *flag;
        int rid = (bid - 2048) * 4 + (t >> 6);
        if (rid >= 4 * 1088) return;
        int j = rid % 1088;
        int b = rid / 1088;
        if (j >= 1025) {
            K[((size_t)b * 1088 + j) * 64 + lane] = f2bf(0.f);
            Vt[((size_t)b * 64 + lane) * 1088 + j] = f2bf(0.f);
            return;
        }
        float kv, vv;
        if (j == 0) {
            kv = ldin(nkv, nkoff + lane, f);
            vv = ldin(nkv, nkoff + 64 + lane, f);
        } else {
            int n = j - 1;
            const bf16* src = qkv + (size_t)(b * 1024 + n) * 640 + 512;
            kv = bf2f(src[lane]);
            vv = bf2f(src[64 + lane]);
            if (lane < 32) {
                float2 cs = rtab[n * 16 + (lane >> 1)];
                float other = __shfl_xor(kv, 1, 64);
                float rot = (lane & 1) ? other : -other;
                kv = kv * cs.x + rot * cs.y;
            }
        }
        float nrm = sqrtf(wave_sum(kv * kv));
        kv = kv / fmaxf(nrm, 1e-12f) * 4.f;
        K[((size_t)b * 1088 + j) * 64 + lane] = f2bf(kv);
        Vt[((size_t)b * 64 + lane) * 1088 + j] = f2bf(vv);
    }
}

// ---------------- MFMA flash attention, NO SPLIT, FIXED-MAX softmax ----------
// grid (B*H=32, 16 qtiles), block 256 = 4 waves (16 q-rows each). Each block
// walks all its K/V chunks (longest tiles dispatched first). Bias table is
// pre-offset by -16 so no online max / rescale: p = exp(s + bias'), l is a
// per-lane f32 partial reduced once at the end; output normalized in-register
// (f32 throughout) and written directly -- no partials, no combine pass.
__global__ __launch_bounds__(256)
void attn_mfma(const bf16* __restrict__ Q, const bf16* __restrict__ Kg,
               const bf16* __restrict__ Vtg, const float* __restrict__ bias,
               bf16* __restrict__ O)
{
    __shared__ bf16 Ks[64][72];
    __shared__ bf16 Vts[64][72];
    __shared__ bf16 Ps[4][16][72];
    __shared__ float bs[1088];
    const int bh = blockIdx.x, b = bh >> 3, h = bh & 7;
    const int yy = (int)gridDim.y - 1 - (int)blockIdx.y;   // longest first
    const int i0 = yy * 64;
    const int t = threadIdx.x, lane = t & 63, w = t >> 6;
    const int col = lane & 15, quad = lane >> 4, fk = quad * 8;
    const float* bt = bias + h * 1025;
    const bf16* Kb = Kg + (size_t)b * 1088 * 64;
    const bf16* Vb = Vtg + (size_t)b * 64 * 1088;

    // stage bias row into LDS: dist range needed is [0, i0+63]
    for (int idx = t; idx < i0 + 64; idx += 256) bs[idx] = bt[idx];

    v8bf qf[2];
    const bf16* qrow = Q + ((size_t)bh * 1024 + i0 + w * 16 + col) * 64;
    qf[0] = *(const v8bf*)(qrow + fk);
    qf[1] = *(const v8bf*)(qrow + 32 + fk);

    v4f oacc[4];
#pragma unroll
    for (int dt = 0; dt < 4; ++dt) { v4f z = {0.f,0.f,0.f,0.f}; oacc[dt] = z; }
    float lpart[4] = {0.f, 0.f, 0.f, 0.f};

    const int nch = yy + 2;
    const int rr0 = t >> 3, co0 = (t & 7) * 8;          // rep 0 staging coords
    const int rr1 = (t + 256) >> 3, co1 = co0;          // rep 1 staging coords

    v8bf kr[2], vr[2];
    {
        kr[0] = *(const v8bf*)(Kb + (size_t)rr0 * 64 + co0);
        vr[0] = *(const v8bf*)(Vb + (size_t)rr0 * 1088 + co0);
        kr[1] = *(const v8bf*)(Kb + (size_t)rr1 * 64 + co1);
        vr[1] = *(const v8bf*)(Vb + (size_t)rr1 * 1088 + co1);
    }

    for (int ch = 0; ch < nch; ++ch) {
        const int j0 = ch * 64;
        __syncthreads();                                 // prev compute done w/ LDS
        *(v8bf*)(&Ks[rr0][co0])  = kr[0];
        *(v8bf*)(&Vts[rr0][co0]) = vr[0];
        *(v8bf*)(&Ks[rr1][co1])  = kr[1];
        *(v8bf*)(&Vts[rr1][co1]) = vr[1];
        if (ch + 1 < nch) {                              // prefetch next chunk
            int j0n = (ch + 1) * 64;
            kr[0] = *(const v8bf*)(Kb + (size_t)(j0n + rr0) * 64 + co0);
            vr[0] = *(const v8bf*)(Vb + (size_t)rr0 * 1088 + j0n + co0);
            kr[1] = *(const v8bf*)(Kb + (size_t)(j0n + rr1) * 64 + co1);
            vr[1] = *(const v8bf*)(Vb + (size_t)rr1 * 1088 + j0n + co1);
        }
        __syncthreads();

        // QK^T
        v4f sreg[4];
#pragma unroll
        for (int nt = 0; nt < 4; ++nt) {
            v4f z = {0.f,0.f,0.f,0.f};
            v8bf kf0 = *(const v8bf*)(&Ks[nt * 16 + col][fk]);
            v8bf kf1 = *(const v8bf*)(&Ks[nt * 16 + col][32 + fk]);
            z = __builtin_amdgcn_mfma_f32_16x16x32_bf16(qf[0], kf0, z, 0, 0, 0);
            z = __builtin_amdgcn_mfma_f32_16x16x32_bf16(qf[1], kf1, z, 0, 0, 0);
            sreg[nt] = z;
        }

        // p = exp(s + bias - 16); no max tracking, no cross-lane ops.
        if (ch < yy) {
            // fully-interior chunk: no causal/pad mask, dist always >= 1
#pragma unroll
            for (int reg = 0; reg < 4; ++reg) {
                int i = i0 + w * 16 + quad * 4 + reg;
                int dbase = i - j0 - col;
#pragma unroll
                for (int nt = 0; nt < 4; ++nt) {
                    float pp = __expf(sreg[nt][reg] + bs[dbase - nt * 16]);
                    lpart[reg] += pp;
                    Ps[w][quad * 4 + reg][nt * 16 + col] = f2bf(pp);
                }
            }
        } else {
#pragma unroll
            for (int reg = 0; reg < 4; ++reg) {
                int i = i0 + w * 16 + quad * 4 + reg;
#pragma unroll
                for (int nt = 0; nt < 4; ++nt) {
                    int j = j0 + nt * 16 + col;
                    float pp = 0.f;
                    if (j <= i + 1 && j < 1025) {
                        int dist = i - j; if (dist < 0) dist = 0;
                        pp = __expf(sreg[nt][reg] + bs[dist]);
                    }
                    lpart[reg] += pp;
                    Ps[w][quad * 4 + reg][nt * 16 + col] = f2bf(pp);
                }
            }
        }

        // PV
        v8bf pf[2];
        pf[0] = *(const v8bf*)(&Ps[w][col][fk]);
        pf[1] = *(const v8bf*)(&Ps[w][col][32 + fk]);
#pragma unroll
        for (int dt = 0; dt < 4; ++dt) {
#pragma unroll
            for (int ks = 0; ks < 2; ++ks) {
                v8bf vf = *(const v8bf*)(&Vts[dt * 16 + col][ks * 32 + fk]);
                oacc[dt] = __builtin_amdgcn_mfma_f32_16x16x32_bf16(pf[ks], vf, oacc[dt], 0, 0, 0);
            }
        }
    }

    // single deferred l reduction (16 cols per row) + normalized direct write
#pragma unroll
    for (int reg = 0; reg < 4; ++reg) {
#pragma unroll
        for (int o = 1; o < 16; o <<= 1) lpart[reg] += __shfl_xor(lpart[reg], o, 64);
        float inv = 1.f / lpart[reg];
        int i = i0 + w * 16 + quad * 4 + reg;
        bf16* orow = O + ((size_t)(b * 1024 + i)) * 512 + h * 64;
#pragma unroll
        for (int dt = 0; dt < 4; ++dt)
            orow[dt * 16 + col] = f2bf(oacc[dt][reg] * inv);
    }
}

// =============================================================================
extern "C" void kernel_launch(void* const* d_in, const int* in_sizes, int n_in,
                              void* d_out, int out_size, void* d_ws, size_t ws_size,
                              hipStream_t stream)
{
    const void* x_in     = d_in[0];
    const void* rpe      = d_in[1];
    const void* g_attn   = d_in[2];
    const void* null_kv  = d_in[3];
    const void* Wq       = d_in[4];
    const void* Wkv      = d_in[5];
    const void* Wo       = d_in[6];
    const void* g_attn_o = d_in[7];
    const void* g_ff     = d_in[8];
    const void* W1       = d_in[9];
    const void* W2       = d_in[10];
    const void* g_final  = d_in[11];
    const void* W_proj   = d_in[12];

    char* wp = (char*)d_ws;
    auto alloc = [&](size_t bytes) {
        char* p = wp; wp += (bytes + 255) & ~(size_t)255; return p;
    };
    float* xf    = (float*)alloc(4096ull * 512 * 4);
    bf16*  xn    = (bf16*) alloc(4096ull * 512 * 2);
    bf16*  tb    = (bf16*) alloc(4096ull * 512 * 2);
    bf16*  ub    = (bf16*) alloc(4096ull * 4096 * 2);
    bf16*  Kb    = (bf16*) alloc(4ull * 1088 * 64 * 2);
    bf16*  Vtb   = (bf16*) alloc(4ull * 64 * 1088 * 2);
    float* btab  = (float*)alloc(8ull * 1025 * 4);
    float2* rtab = (float2*)alloc(16384ull * 8);
    int*   dfl   = (int*)  alloc(256);
    bf16*  WqkvT = (bf16*) alloc(6ull * 640 * 512 * 2);
    bf16*  WoT   = (bf16*) alloc(6ull * 512 * 512 * 2);
    bf16*  W1T   = (bf16*) alloc(6ull * 4096 * 512 * 2);
    bf16*  W2T   = (bf16*) alloc(6ull * 512 * 2048 * 2);
    bf16*  WpT   = (bf16*) alloc(512ull * 512 * 2);
    // aliased into ub (16,777,216 elems; all dead before gemm_bt_silu writes ub)
    bf16*  qkvb  = ub;                        // 2,621,440 elems
    bf16*  Qb    = ub + 2621440;              // 2,097,152
    bf16*  ob    = ub + 4718592;              // 2,097,152

    detect_k<<<1, 256, 0, stream>>>((const unsigned short*)x_in, dfl);
    transpose2_k<<<dim3(16, 16, 6),  dim3(32, 8), 0, stream>>>(Wq, WqkvT, 512, 512, 512ull*512, 640ull*512, dfl);
    transpose2_k<<<dim3(4, 16, 6),   dim3(32, 8), 0, stream>>>(Wkv, WqkvT + 512ull*512, 512, 128, 512ull*128, 640ull*512, dfl);
    transpose2_k<<<dim3(16, 16, 6),  dim3(32, 8), 0, stream>>>(Wo, WoT, 512, 512, 512ull*512, 512ull*512, dfl);
    transposeW1_k<<<dim3(128, 16, 6), dim3(32, 8), 0, stream>>>(W1, W1T, dfl);
    transpose2_k<<<dim3(16, 64, 6),  dim3(32, 8), 0, stream>>>(W2, W2T, 2048, 512, 2048ull*512, 2048ull*512, dfl);
    transpose2_k<<<dim3(16, 16, 1),  dim3(32, 8), 0, stream>>>(W_proj, WpT, 512, 512, 512ull*512, 512ull*512, dfl);
    bias_k<<<33, 256, 0, stream>>>(rpe, dfl, btab);
    rotab_k<<<64, 256, 0, stream>>>(rtab);
    xinit_ln_k<<<1024, 256, 0, stream>>>(x_in, g_attn, dfl, xf, xn);

    for (int l = 0; l < 6; ++l) {
        gemm64<<<dim3(64, 5), 256, 0, stream>>>(xn, WqkvT + (size_t)l * 640 * 512, qkvb, 4096, 640, 512, 512);
        qkvprep_k<<<3136, 256, 0, stream>>>(qkvb, null_kv, l * 128, dfl, rtab, Qb, Kb, Vtb);
        attn_mfma<<<dim3(32, 16), 256, 0, stream>>>(Qb, Kb, Vtb, btab, ob);
        gemm64<<<dim3(64, 4), 256, 0, stream>>>(ob, WoT + (size_t)l * 512 * 512, tb, 4096, 512, 512, 512);
        addln_ln_k<<<1024, 256, 0, stream>>>(tb, g_attn_o, l * 512, g_ff, l * 512, dfl, xf, xn);
        gemm_bt_silu<<<dim3(32, 32), 256, 0, stream>>>(xn, W1T + (size_t)l * 4096 * 512, ub, 512, 512);
        gemm64<<<dim3(64, 4), 256, 0, stream>>>(ub, W2T + (size_t)l * 512 * 2048, tb, 4096, 512, 2048, 2048);
        if (l < 5)
            add_ln_k<<<1024, 256, 0, stream>>>(tb, g_attn, (l + 1) * 512, dfl, 0, xf, xn);
        else
            add_ln_k<<<1024, 256, 0, stream>>>(tb, g_final, 0, dfl, 1, xf, xn);
    }
    gemm64_out<<<dim3(64, 4), 256, 0, stream>>>(xn, WpT, d_out, 4096, 512, 512, 512, dfl);
}

// Round 5
// 895.994 us; speedup vs baseline: 1.4022x; 1.0446x over previous
//
#include <hip/hip_runtime.h>
#include <hip/hip_bf16.h>
#include <cmath>

using bf16 = __hip_bfloat16;
typedef __bf16 v8bf __attribute__((ext_vector_type(8)));
typedef __bf16 v4bf __attribute__((ext_vector_type(4)));
typedef float  v4f  __attribute__((ext_vector_type(4)));

__device__ __forceinline__ float bf2f(bf16 x) { return __bfloat162float(x); }
__device__ __forceinline__ bf16  f2bf(float x) { return __float2bfloat16(x); }
__device__ __forceinline__ __bf16 tobf(float x) {
    bf16 h = __float2bfloat16(x);
    return __builtin_bit_cast(__bf16, h);
}

// async global->LDS, 16B per lane (lds dest = wave-uniform base + lane*16)
__device__ __forceinline__ void gll16(const bf16* g, bf16* l) {
    __builtin_amdgcn_global_load_lds(
        (const __attribute__((address_space(1))) unsigned int*)g,
        (__attribute__((address_space(3))) unsigned int*)l, 16, 0, 0);
}

__device__ __forceinline__ float ldin(const void* p, size_t i, int isf32) {
    if (isf32) return ((const float*)p)[i];
    return bf2f(((const bf16*)p)[i]);
}

// flag-dtype vector load of 8 consecutive elements
__device__ __forceinline__ void ld8(const void* p, size_t base, int f, float v[8]) {
    if (f) {
        const float* pf = (const float*)p + base;
        float4 a = *(const float4*)pf, b = *(const float4*)(pf + 4);
        v[0]=a.x; v[1]=a.y; v[2]=a.z; v[3]=a.w;
        v[4]=b.x; v[5]=b.y; v[6]=b.z; v[7]=b.w;
    } else {
        v8bf a = *(const v8bf*)((const bf16*)p + base);
#pragma unroll
        for (int j = 0; j < 8; ++j) v[j] = (float)a[j];
    }
}

__device__ __forceinline__ float wave_sum(float v) {
#pragma unroll
    for (int o = 32; o > 0; o >>= 1) v += __shfl_xor(v, o, 64);
    return v;
}
__device__ __forceinline__ float wave_max(float v) {
#pragma unroll
    for (int o = 32; o > 0; o >>= 1) v = fmaxf(v, __shfl_xor(v, o, 64));
    return v;
}

// ---------------- dtype detector -------------------------------------------
__global__ void detect_k(const unsigned short* __restrict__ x, int* __restrict__ flag)
{
    __shared__ int s;
    int t = threadIdx.x;
    if (t == 0) s = 0;
    __syncthreads();
    int bad = 0;
    for (int i = t; i < 4096; i += 256) {
        int e = (x[i] >> 7) & 0xFF;
        if (e >= 147) bad++;
    }
    atomicAdd(&s, bad);
    __syncthreads();
    if (t == 0) *flag = (s > 64) ? 1 : 0;
}

// ============ 256x256 / BK=64 / 8-wave double-buffered GEMM + SiLU ===========
// 2-phase pipeline (m230-V0 class): stage K-tile t+1 into buf^1 (async
// global_load_lds) BEFORE computing K-tile t from buf; the single
// __syncthreads() per tile drains vmcnt (stage complete) and lgkmcnt (reads
// complete) -- the ~640cy MFMA phase hides the prefetch latency that the old
// 128x128/BK=32 kernel exposed at every barrier.
// Swizzle (both-sides, rule #21): 16B-granule g within a 128B row is stored at
// linear LDS slot but sourced from global granule g^(row&7); ds_read applies
// the same XOR -> the 16 fr-lanes of a fragment read cover all 8 granule slots
// (2-way bank aliasing = free) instead of a 16-way conflict.
// BT is the PERMUTED W1^T (a/gate interleave, groups of 64 rows = 32 a + 32
// gate): each wave's 64-col span is exactly one group; acc[mt][nt] (nt<2)
// pairs with acc[mt][nt+2] as (a, gate). U is 4096x2048.
__global__ __launch_bounds__(512, 2)
void gemm256_silu(const bf16* __restrict__ A, const bf16* __restrict__ BT,
                  bf16* __restrict__ U, int K, int lda)
{
    __shared__ bf16 As[2][256 * 64];
    __shared__ bf16 Bs[2][256 * 64];
    const int t = threadIdx.x;            // 0..511
    const int lane = t & 63;
    const int wave = t >> 6;              // 0..7  (2 M x 4 N)
    const int wm = (wave >> 2) * 128;
    const int wn = (wave & 3) * 64;
    const int bm = blockIdx.x * 256;
    const int bn = blockIdx.y * 256;
    const int fr = lane & 15;
    const int quad = lane >> 4;

    v4f acc[8][4];
#pragma unroll
    for (int i = 0; i < 8; ++i)
#pragma unroll
        for (int j = 0; j < 4; ++j) { v4f z = {0.f, 0.f, 0.f, 0.f}; acc[i][j] = z; }

    // stage one K-tile (256 rows x 64 k for A and B) into buffer `buf`
    // linear granule c = t + 512*r  (2048 granules = 256 rows x 8)
    // LDS dest linear (gll16 requirement); SOURCE granule pre-swizzled.
    auto stage = [&](int buf, int k0) {
#pragma unroll
        for (int r = 0; r < 4; ++r) {
            int c = t + 512 * r;
            int row = c >> 3;
            int g = (c & 7) ^ (row & 7);
            gll16(A + (size_t)(bm + row) * lda + k0 + g * 8, &As[buf][c * 8]);
            gll16(BT + (size_t)(bn + row) * K + k0 + g * 8, &Bs[buf][c * 8]);
        }
    };

    stage(0, 0);
    __syncthreads();
    const int nb = K >> 6;                 // K/64 tiles
    for (int kt = 0; kt < nb; ++kt) {
        const int buf = kt & 1;
        if (kt + 1 < nb) stage(buf ^ 1, (kt + 1) * 64);
#pragma unroll
        for (int ks = 0; ks < 2; ++ks) {
            v8bf af[8], bfr[4];
            const int gk = ((ks * 4 + quad) ^ (fr & 7)) * 8;
#pragma unroll
            for (int mt = 0; mt < 8; ++mt)
                af[mt] = *(const v8bf*)(&As[buf][(wm + mt * 16 + fr) * 64 + gk]);
#pragma unroll
            for (int nt = 0; nt < 4; ++nt)
                bfr[nt] = *(const v8bf*)(&Bs[buf][(wn + nt * 16 + fr) * 64 + gk]);
#pragma unroll
            for (int mt = 0; mt < 8; ++mt)
#pragma unroll
                for (int nt = 0; nt < 4; ++nt)
                    acc[mt][nt] = __builtin_amdgcn_mfma_f32_16x16x32_bf16(
                        af[mt], bfr[nt], acc[mt][nt], 0, 0, 0);
        }
        __syncthreads();                   // drains stage (vmcnt) + reads done
    }

    const int r0 = quad * 4;
    const int gbase = ((bn + wn) >> 6) * 32;
#pragma unroll
    for (int mt = 0; mt < 8; ++mt)
#pragma unroll
        for (int nt = 0; nt < 2; ++nt)
#pragma unroll
            for (int r = 0; r < 4; ++r) {
                int row = bm + wm + mt * 16 + r0 + r;
                int col = gbase + nt * 16 + fr;
                float a  = acc[mt][nt][r];
                float gg = acc[mt][nt + 2][r];
                U[(size_t)row * 2048 + col] = f2bf(a * (gg / (1.f + __expf(-gg))));
            }
}

// LDS bank-swizzle note (64x128-tile GEMMs): rows are 32 bf16 (64B) so plain
// chunk order puts the 16 fr-lanes of a ds_read_b128 on 2 bank-groups (8-way).
// We XOR the 16B-chunk index with ((row>>1)&3): LDS dest of gload_lds stays
// LINEAR; the SOURCE k-chunk is picked pre-swizzled, and the fragment read
// applies the same involution.

// ---------------- MFMA GEMM 64x128 tile (async LDS staging) ------------------
__global__ __launch_bounds__(256)
void gemm64(const bf16* __restrict__ A, const bf16* __restrict__ BT,
            bf16* __restrict__ C, int M, int N, int K, int lda)
{
    __shared__ bf16 As[64 * 32];
    __shared__ bf16 Bs[128 * 32];
    const int t = threadIdx.x;
    const int lane = t & 63;
    const int wave = t >> 6;
    const int wm = (wave >> 1) * 32;
    const int wn = (wave & 1) * 64;
    const int bm = blockIdx.x * 64;
    const int bn = blockIdx.y * 128;
    const int fr = lane & 15;
    const int fk = (((lane >> 4) ^ ((fr >> 1) & 3))) * 8;

    v4f acc[2][4];
#pragma unroll
    for (int i = 0; i < 2; ++i)
#pragma unroll
        for (int j = 0; j < 4; ++j) { v4f z = {0.f, 0.f, 0.f, 0.f}; acc[i][j] = z; }

    for (int k0 = 0; k0 < K; k0 += 32) {
        {
            int row = t >> 2;
            int koff = ((t & 3) ^ ((row >> 1) & 3)) * 8;
            gll16(A + (size_t)(bm + row) * lda + k0 + koff, &As[t * 8]);
        }
#pragma unroll
        for (int r = 0; r < 2; ++r) {
            int c = t + 256 * r;
            int row = c >> 2;
            int koff = ((c & 3) ^ ((row >> 1) & 3)) * 8;
            gll16(BT + (size_t)(bn + row) * K + k0 + koff, &Bs[c * 8]);
        }
        __syncthreads();
        v8bf af[2], bfr[4];
#pragma unroll
        for (int mt = 0; mt < 2; ++mt)
            af[mt] = *(const v8bf*)(&As[(wm + mt * 16 + fr) * 32 + fk]);
#pragma unroll
        for (int nt = 0; nt < 4; ++nt)
            bfr[nt] = *(const v8bf*)(&Bs[(wn + nt * 16 + fr) * 32 + fk]);
#pragma unroll
        for (int mt = 0; mt < 2; ++mt)
#pragma unroll
            for (int nt = 0; nt < 4; ++nt)
                acc[mt][nt] = __builtin_amdgcn_mfma_f32_16x16x32_bf16(
                    af[mt], bfr[nt], acc[mt][nt], 0, 0, 0);
        __syncthreads();
    }
    const int r0 = (lane >> 4) * 4;
#pragma unroll
    for (int mt = 0; mt < 2; ++mt)
#pragma unroll
        for (int nt = 0; nt < 4; ++nt)
#pragma unroll
            for (int r = 0; r < 4; ++r) {
                int row = bm + wm + mt * 16 + r0 + r;
                int col = bn + wn + nt * 16 + fr;
                C[(size_t)row * N + col] = f2bf(acc[mt][nt][r]);
            }
}

// ---- gemm64 with flag-selected output dtype (final projection) --------------
__global__ __launch_bounds__(256)
void gemm64_out(const bf16* __restrict__ A, const bf16* __restrict__ BT,
                void* __restrict__ C, int M, int N, int K, int lda,
                const int* __restrict__ flag)
{
    __shared__ bf16 As[64 * 32];
    __shared__ bf16 Bs[128 * 32];
    const int f = *flag;
    const int t = threadIdx.x;
    const int lane = t & 63;
    const int wave = t >> 6;
    const int wm = (wave >> 1) * 32;
    const int wn = (wave & 1) * 64;
    const int bm = blockIdx.x * 64;
    const int bn = blockIdx.y * 128;
    const int fr = lane & 15;
    const int fk = (((lane >> 4) ^ ((fr >> 1) & 3))) * 8;

    v4f acc[2][4];
#pragma unroll
    for (int i = 0; i < 2; ++i)
#pragma unroll
        for (int j = 0; j < 4; ++j) { v4f z = {0.f, 0.f, 0.f, 0.f}; acc[i][j] = z; }

    for (int k0 = 0; k0 < K; k0 += 32) {
        {
            int row = t >> 2;
            int koff = ((t & 3) ^ ((row >> 1) & 3)) * 8;
            gll16(A + (size_t)(bm + row) * lda + k0 + koff, &As[t * 8]);
        }
#pragma unroll
        for (int r = 0; r < 2; ++r) {
            int c = t + 256 * r;
            int row = c >> 2;
            int koff = ((c & 3) ^ ((row >> 1) & 3)) * 8;
            gll16(BT + (size_t)(bn + row) * K + k0 + koff, &Bs[c * 8]);
        }
        __syncthreads();
        v8bf af[2], bfr[4];
#pragma unroll
        for (int mt = 0; mt < 2; ++mt)
            af[mt] = *(const v8bf*)(&As[(wm + mt * 16 + fr) * 32 + fk]);
#pragma unroll
        for (int nt = 0; nt < 4; ++nt)
            bfr[nt] = *(const v8bf*)(&Bs[(wn + nt * 16 + fr) * 32 + fk]);
#pragma unroll
        for (int mt = 0; mt < 2; ++mt)
#pragma unroll
            for (int nt = 0; nt < 4; ++nt)
                acc[mt][nt] = __builtin_amdgcn_mfma_f32_16x16x32_bf16(
                    af[mt], bfr[nt], acc[mt][nt], 0, 0, 0);
        __syncthreads();
    }
    const int r0 = (lane >> 4) * 4;
#pragma unroll
    for (int mt = 0; mt < 2; ++mt)
#pragma unroll
        for (int nt = 0; nt < 4; ++nt)
#pragma unroll
            for (int r = 0; r < 4; ++r) {
                int row = bm + wm + mt * 16 + r0 + r;
                int col = bn + wn + nt * 16 + fr;
                if (f) ((float*)C)[(size_t)row * N + col] = acc[mt][nt][r];
                else   ((bf16*)C)[(size_t)row * N + col] = f2bf(acc[mt][nt][r]);
            }
}

// ---------------- transpose w/ separate z-strides ----------------------------
__global__ __launch_bounds__(256)
void transpose2_k(const void* __restrict__ in, bf16* __restrict__ out, int R, int C,
                  size_t inZ, size_t outZ, const int* __restrict__ flag)
{
    __shared__ bf16 tile[32][33];
    int f = *flag;
    size_t ioff = (size_t)blockIdx.z * inZ;
    bf16* dst = out + (size_t)blockIdx.z * outZ;
    int c0 = blockIdx.x * 32, r0 = blockIdx.y * 32;
    int tx = threadIdx.x, ty = threadIdx.y;
#pragma unroll
    for (int i = 0; i < 32; i += 8)
        tile[ty + i][tx] = f2bf(ldin(in, ioff + (size_t)(r0 + ty + i) * C + c0 + tx, f));
    __syncthreads();
#pragma unroll
    for (int i = 0; i < 32; i += 8)
        dst[(size_t)(c0 + ty + i) * R + r0 + tx] = tile[tx][ty + i];
}

// ---------------- W1 transpose with a/gate interleave permutation ------------
// out row j' for orig col j: j<2048 (a): j' = (j>>5)*64 + (j&31);
// j>=2048 (gate): j' = ((j-2048)>>5)*64 + 32 + (j&31).
__global__ __launch_bounds__(256)
void transposeW1_k(const void* __restrict__ in, bf16* __restrict__ out,
                   const int* __restrict__ flag)
{
    __shared__ bf16 tile[32][33];
    int f = *flag;
    size_t ioff = (size_t)blockIdx.z * (512ull * 4096);
    bf16* dst = out + (size_t)blockIdx.z * (512ull * 4096);
    int c0 = blockIdx.x * 32, r0 = blockIdx.y * 32;
    int tx = threadIdx.x, ty = threadIdx.y;
#pragma unroll
    for (int i = 0; i < 32; i += 8)
        tile[ty + i][tx] = f2bf(ldin(in, ioff + (size_t)(r0 + ty + i) * 4096 + c0 + tx, f));
    __syncthreads();
#pragma unroll
    for (int i = 0; i < 32; i += 8) {
        int j = c0 + ty + i;
        int jp = (j < 2048) ? (((j >> 5) << 6) | (j & 31))
                            : ((((j - 2048) >> 5) << 6) | 32 | (j & 31));
        dst[(size_t)jp * 512 + r0 + tx] = tile[tx][ty + i];
    }
}

// ---------------- x = in; xn = LN(x)*g  (one row per WAVE, no barriers) ------
__global__ __launch_bounds__(256)
void xinit_ln_k(const void* __restrict__ in, const void* __restrict__ g,
                const int* __restrict__ flag, float* __restrict__ x, bf16* __restrict__ xn)
{
    int f = *flag;
    int row = blockIdx.x * 4 + (threadIdx.x >> 6);
    int lane = threadIdx.x & 63;
    int c0 = lane * 8;
    float v[8];
    ld8(in, (size_t)row * 512 + c0, f, v);
    // persist x as f32
    float* xr = x + (size_t)row * 512 + c0;
    *(float4*)xr       = make_float4(v[0], v[1], v[2], v[3]);
    *(float4*)(xr + 4) = make_float4(v[4], v[5], v[6], v[7]);
    float s = 0.f;
#pragma unroll
    for (int j = 0; j < 8; ++j) s += v[j];
    float mean = wave_sum(s) * (1.f / 512.f);
    float q = 0.f;
#pragma unroll
    for (int j = 0; j < 8; ++j) { float d = v[j] - mean; q += d * d; }
    float var = wave_sum(q) * (1.f / 512.f);
    float rstd = rsqrtf(var + 1e-5f);
    float gv[8];
    ld8(g, c0, f, gv);
    v8bf o;
#pragma unroll
    for (int j = 0; j < 8; ++j) o[j] = tobf((v[j] - mean) * rstd * gv[j]);
    *(v8bf*)(xn + (size_t)row * 512 + c0) = o;
}

// ------ x += LN(t)*g1 ; xn = LN(x)*g2  (one row per WAVE, no barriers) -------
__global__ __launch_bounds__(256)
void addln_ln_k(const bf16* __restrict__ tin, const void* __restrict__ g1, int g1off,
                const void* __restrict__ g2, int g2off, const int* __restrict__ flag,
                float* __restrict__ x, bf16* __restrict__ xn)
{
    int f = *flag;
    int row = blockIdx.x * 4 + (threadIdx.x >> 6);
    int lane = threadIdx.x & 63;
    int c0 = lane * 8;
    float tv[8];
    {
        v8bf a = *(const v8bf*)(tin + (size_t)row * 512 + c0);
#pragma unroll
        for (int j = 0; j < 8; ++j) tv[j] = (float)a[j];
    }
    float s = 0.f;
#pragma unroll
    for (int j = 0; j < 8; ++j) s += tv[j];
    float mean = wave_sum(s) * (1.f / 512.f);
    float q = 0.f;
#pragma unroll
    for (int j = 0; j < 8; ++j) { float d = tv[j] - mean; q += d * d; }
    float var = wave_sum(q) * (1.f / 512.f);
    float rstd = rsqrtf(var + 1e-5f);
    float g1v[8];
    ld8(g1, (size_t)g1off + c0, f, g1v);
    float* xr = x + (size_t)row * 512 + c0;
    float4 xa = *(float4*)xr, xb = *(float4*)(xr + 4);
    float nx[8] = {xa.x, xa.y, xa.z, xa.w, xb.x, xb.y, xb.z, xb.w};
#pragma unroll
    for (int j = 0; j < 8; ++j) nx[j] += (tv[j] - mean) * rstd * g1v[j];
    *(float4*)xr       = make_float4(nx[0], nx[1], nx[2], nx[3]);
    *(float4*)(xr + 4) = make_float4(nx[4], nx[5], nx[6], nx[7]);
    float s2 = 0.f;
#pragma unroll
    for (int j = 0; j < 8; ++j) s2 += nx[j];
    float mean2 = wave_sum(s2) * (1.f / 512.f);
    float q2 = 0.f;
#pragma unroll
    for (int j = 0; j < 8; ++j) { float e = nx[j] - mean2; q2 += e * e; }
    float var2 = wave_sum(q2) * (1.f / 512.f);
    float rstd2 = rsqrtf(var2 + 1e-5f);
    float g2v[8];
    ld8(g2, (size_t)g2off + c0, f, g2v);
    v8bf o;
#pragma unroll
    for (int j = 0; j < 8; ++j) o[j] = tobf((nx[j] - mean2) * rstd2 * g2v[j]);
    *(v8bf*)(xn + (size_t)row * 512 + c0) = o;
}

// -- x += t ; xn = (stable? stableLN : LN)(x)*g  (one row per WAVE) -----------
__global__ __launch_bounds__(256)
void add_ln_k(const bf16* __restrict__ tin, const void* __restrict__ g, int goff,
              const int* __restrict__ flag, int stable,
              float* __restrict__ x, bf16* __restrict__ xn)
{
    int f = *flag;
    int row = blockIdx.x * 4 + (threadIdx.x >> 6);
    int lane = threadIdx.x & 63;
    int c0 = lane * 8;
    float nx[8];
    {
        v8bf a = *(const v8bf*)(tin + (size_t)row * 512 + c0);
        float* xr = x + (size_t)row * 512 + c0;
        float4 xa = *(float4*)xr, xb = *(float4*)(xr + 4);
        float xv[8] = {xa.x, xa.y, xa.z, xa.w, xb.x, xb.y, xb.z, xb.w};
#pragma unroll
        for (int j = 0; j < 8; ++j) nx[j] = xv[j] + (float)a[j];
        *(float4*)xr       = make_float4(nx[0], nx[1], nx[2], nx[3]);
        *(float4*)(xr + 4) = make_float4(nx[4], nx[5], nx[6], nx[7]);
    }
    float v[8];
#pragma unroll
    for (int j = 0; j < 8; ++j) v[j] = nx[j];
    if (stable) {
        float m = v[0];
#pragma unroll
        for (int j = 1; j < 8; ++j) m = fmaxf(m, v[j]);
        float mx = wave_max(m);
#pragma unroll
        for (int j = 0; j < 8; ++j) v[j] /= mx;
    }
    float s = 0.f;
#pragma unroll
    for (int j = 0; j < 8; ++j) s += v[j];
    float mean = wave_sum(s) * (1.f / 512.f);
    float q = 0.f;
#pragma unroll
    for (int j = 0; j < 8; ++j) { float d = v[j] - mean; q += d * d; }
    float var = wave_sum(q) * (1.f / 512.f);
    float rstd = rsqrtf(var + 1e-5f);
    float gv[8];
    ld8(g, (size_t)goff + c0, f, gv);
    v8bf o;
#pragma unroll
    for (int j = 0; j < 8; ++j) o[j] = tobf((v[j] - mean) * rstd * gv[j]);
    *(v8bf*)(xn + (size_t)row * 512 + c0) = o;
}

// ---------------- rotary cos/sin table: tab[n*16+p] = (cos, sin) -------------
__global__ __launch_bounds__(256)
void rotab_k(float2* __restrict__ tab)
{
    int idx = blockIdx.x * 256 + threadIdx.x;
    if (idx >= 16384) return;
    int n = idx >> 4, p = idx & 15;
    float ang = (float)n * expf((float)p * -0.5756462732f);
    tab[idx] = make_float2(cosf(ang), sinf(ang));
}

// ---------------- rel-pos bias table (pre-offset by -16: fixed softmax max) --
// qn,kn are l2-normalized to norm 4 => s = qn.kn <= 16 (Cauchy-Schwarz), and
// |bias| << 1, so exp(s + bias - 16) <= ~1.11. Softmax is shift-invariant, so
// folding the -16 here lets attention skip online-max tracking entirely.
__global__ __launch_bounds__(256)
void bias_k(const void* __restrict__ rpe, const int* __restrict__ flag, float* __restrict__ tab)
{
    int f = *flag;
    int idx = blockIdx.x * 256 + threadIdx.x;
    if (idx >= 8 * 1025) return;
    int h = idx / 1025, dist = idx % 1025;
    int bkt;
    if (dist < 16) bkt = dist;
    else {
        bkt = 16 + (int)(logf((float)dist / 16.f) / logf(8.f) * 16.f);
        if (bkt > 31) bkt = 31;
    }
    tab[idx] = ldin(rpe, bkt * 8 + h, f) - 16.f;
}

// ---------------- merged q + k/v prep (qkv stride 640, rotary via table) -----
// blocks [0,2048): q rows, 16 per block (4/wave, 16 lanes x 4 els each).
// blocks [2048,3136): k/v rows j in [0,1088) x b (4352, 4/block, 1/wave).
__global__ __launch_bounds__(256)
void qkvprep_k(const bf16* __restrict__ qkv, const void* __restrict__ nkv, int nkoff,
               const int* __restrict__ flag, const float2* __restrict__ rtab,
               bf16* __restrict__ Q, bf16* __restrict__ K, bf16* __restrict__ Vt)
{
    int t = threadIdx.x, lane = t & 63;
    int bid = blockIdx.x;
    if (bid < 2048) {
        int rid = bid * 16 + (t >> 4);            // one row per 16-lane group
        int h = rid & 7;
        int n = (rid >> 3) & 1023;
        int b = rid >> 13;
        int g16 = t & 15;
        int d0 = g16 * 4;
        v4bf a = *(const v4bf*)(qkv + (size_t)((b << 10) | n) * 640 + h * 64 + d0);
        float v[4];
#pragma unroll
        for (int j = 0; j < 4; ++j) v[j] = (float)a[j] * 16.f;
        if (d0 < 32) {                            // rotary, pairs in-lane
            float4 cs = *(const float4*)((const float*)rtab + (size_t)n * 32 + (size_t)(d0 >> 1) * 2);
            float r0 = v[0] * cs.x - v[1] * cs.y;
            float r1 = v[1] * cs.x + v[0] * cs.y;
            float r2 = v[2] * cs.z - v[3] * cs.w;
            float r3 = v[3] * cs.z + v[2] * cs.w;
            v[0] = r0; v[1] = r1; v[2] = r2; v[3] = r3;
        }
        float ss = v[0]*v[0] + v[1]*v[1] + v[2]*v[2] + v[3]*v[3];
#pragma unroll
        for (int o = 1; o < 16; o <<= 1) ss += __shfl_xor(ss, o, 64);
        float sc = 4.f / fmaxf(sqrtf(ss), 1e-12f);
        v4bf ov;
#pragma unroll
        for (int j = 0; j < 4; ++j) ov[j] = tobf(v[j] * sc);
        *(v4bf*)(Q + (((size_t)(b * 8 + h)) * 1024 + n) * 64 + d0) = ov;
    } else {
        int f = *flag;
        int rid = (bid - 2048) * 4 + (t >> 6);
        if (rid >= 4 * 1088) return;
        int j = rid % 1088;
        int b = rid / 1088;
        if (j >= 1025) {
            K[((size_t)b * 1088 + j) * 64 + lane] = f2bf(0.f);
            Vt[((size_t)b * 64 + lane) * 1088 + j] = f2bf(0.f);
            return;
        }
        float kv, vv;
        if (j == 0) {
            kv = ldin(nkv, nkoff + lane, f);
            vv = ldin(nkv, nkoff + 64 + lane, f);
        } else {
            int n = j - 1;
            const bf16* src = qkv + (size_t)(b * 1024 + n) * 640 + 512;
            kv = bf2f(src[lane]);
            vv = bf2f(src[64 + lane]);
            if (lane < 32) {
                float2 cs = rtab[n * 16 + (lane >> 1)];
                float other = __shfl_xor(kv, 1, 64);
                float rot = (lane & 1) ? other : -other;
                kv = kv * cs.x + rot * cs.y;
            }
        }
        float nrm = sqrtf(wave_sum(kv * kv));
        kv = kv / fmaxf(nrm, 1e-12f) * 4.f;
        K[((size_t)b * 1088 + j) * 64 + lane] = f2bf(kv);
        Vt[((size_t)b * 64 + lane) * 1088 + j] = f2bf(vv);
    }
}

// ---------------- MFMA flash attention, NO SPLIT, FIXED-MAX softmax ----------
// grid (B*H=32, 16 qtiles), block 256 = 4 waves (16 q-rows each). Each block
// walks all its K/V chunks (longest tiles dispatched first). Bias table is
// pre-offset by -16 so no online max / rescale: p = exp(s + bias'), l is a
// per-lane f32 partial reduced once at the end; output normalized in-register
// (f32 throughout) and written directly -- no partials, no combine pass.
__global__ __launch_bounds__(256)
void attn_mfma(const bf16* __restrict__ Q, const bf16* __restrict__ Kg,
               const bf16* __restrict__ Vtg, const float* __restrict__ bias,
               bf16* __restrict__ O)
{
    __shared__ bf16 Ks[64][72];
    __shared__ bf16 Vts[64][72];
    __shared__ bf16 Ps[4][16][72];
    __shared__ float bs[1088];
    const int bh = blockIdx.x, b = bh >> 3, h = bh & 7;
    const int yy = (int)gridDim.y - 1 - (int)blockIdx.y;   // longest first
    const int i0 = yy * 64;
    const int t = threadIdx.x, lane = t & 63, w = t >> 6;
    const int col = lane & 15, quad = lane >> 4, fk = quad * 8;
    const float* bt = bias + h * 1025;
    const bf16* Kb = Kg + (size_t)b * 1088 * 64;
    const bf16* Vb = Vtg + (size_t)b * 64 * 1088;

    // stage bias row into LDS: dist range needed is [0, i0+63]
    for (int idx = t; idx < i0 + 64; idx += 256) bs[idx] = bt[idx];

    v8bf qf[2];
    const bf16* qrow = Q + ((size_t)bh * 1024 + i0 + w * 16 + col) * 64;
    qf[0] = *(const v8bf*)(qrow + fk);
    qf[1] = *(const v8bf*)(qrow + 32 + fk);

    v4f oacc[4];
#pragma unroll
    for (int dt = 0; dt < 4; ++dt) { v4f z = {0.f,0.f,0.f,0.f}; oacc[dt] = z; }
    float lpart[4] = {0.f, 0.f, 0.f, 0.f};

    const int nch = yy + 2;
    const int rr0 = t >> 3, co0 = (t & 7) * 8;          // rep 0 staging coords
    const int rr1 = (t + 256) >> 3, co1 = co0;          // rep 1 staging coords

    v8bf kr[2], vr[2];
    {
        kr[0] = *(const v8bf*)(Kb + (size_t)rr0 * 64 + co0);
        vr[0] = *(const v8bf*)(Vb + (size_t)rr0 * 1088 + co0);
        kr[1] = *(const v8bf*)(Kb + (size_t)rr1 * 64 + co1);
        vr[1] = *(const v8bf*)(Vb + (size_t)rr1 * 1088 + co1);
    }

    for (int ch = 0; ch < nch; ++ch) {
        const int j0 = ch * 64;
        __syncthreads();                                 // prev compute done w/ LDS
        *(v8bf*)(&Ks[rr0][co0])  = kr[0];
        *(v8bf*)(&Vts[rr0][co0]) = vr[0];
        *(v8bf*)(&Ks[rr1][co1])  = kr[1];
        *(v8bf*)(&Vts[rr1][co1]) = vr[1];
        if (ch + 1 < nch) {                              // prefetch next chunk
            int j0n = (ch + 1) * 64;
            kr[0] = *(const v8bf*)(Kb + (size_t)(j0n + rr0) * 64 + co0);
            vr[0] = *(const v8bf*)(Vb + (size_t)rr0 * 1088 + j0n + co0);
            kr[1] = *(const v8bf*)(Kb + (size_t)(j0n + rr1) * 64 + co1);
            vr[1] = *(const v8bf*)(Vb + (size_t)rr1 * 1088 + j0n + co1);
        }
        __syncthreads();

        // QK^T
        v4f sreg[4];
#pragma unroll
        for (int nt = 0; nt < 4; ++nt) {
            v4f z = {0.f,0.f,0.f,0.f};
            v8bf kf0 = *(const v8bf*)(&Ks[nt * 16 + col][fk]);
            v8bf kf1 = *(const v8bf*)(&Ks[nt * 16 + col][32 + fk]);
            z = __builtin_amdgcn_mfma_f32_16x16x32_bf16(qf[0], kf0, z, 0, 0, 0);
            z = __builtin_amdgcn_mfma_f32_16x16x32_bf16(qf[1], kf1, z, 0, 0, 0);
            sreg[nt] = z;
        }

        // p = exp(s + bias - 16); no max tracking, no cross-lane ops.
        if (ch < yy) {
            // fully-interior chunk: no causal/pad mask, dist always >= 1
#pragma unroll
            for (int reg = 0; reg < 4; ++reg) {
                int i = i0 + w * 16 + quad * 4 + reg;
                int dbase = i - j0 - col;
#pragma unroll
                for (int nt = 0; nt < 4; ++nt) {
                    float pp = __expf(sreg[nt][reg] + bs[dbase - nt * 16]);
                    lpart[reg] += pp;
                    Ps[w][quad * 4 + reg][nt * 16 + col] = f2bf(pp);
                }
            }
        } else {
#pragma unroll
            for (int reg = 0; reg < 4; ++reg) {
                int i = i0 + w * 16 + quad * 4 + reg;
#pragma unroll
                for (int nt = 0; nt < 4; ++nt) {
                    int j = j0 + nt * 16 + col;
                    float pp = 0.f;
                    if (j <= i + 1 && j < 1025) {
                        int dist = i - j; if (dist < 0) dist = 0;
                        pp = __expf(sreg[nt][reg] + bs[dist]);
                    }
                    lpart[reg] += pp;
                    Ps[w][quad * 4 + reg][nt * 16 + col] = f2bf(pp);
                }
            }
        }

        // PV
        v8bf pf[2];
        pf[0] = *(const v8bf*)(&Ps[w][col][fk]);
        pf[1] = *(const v8bf*)(&Ps[w][col][32 + fk]);
#pragma unroll
        for (int dt = 0; dt < 4; ++dt) {
#pragma unroll
            for (int ks = 0; ks < 2; ++ks) {
                v8bf vf = *(const v8bf*)(&Vts[dt * 16 + col][ks * 32 + fk]);
                oacc[dt] = __builtin_amdgcn_mfma_f32_16x16x32_bf16(pf[ks], vf, oacc[dt], 0, 0, 0);
            }
        }
    }

    // single deferred l reduction (16 cols per row) + normalized direct write
#pragma unroll
    for (int reg = 0; reg < 4; ++reg) {
#pragma unroll
        for (int o = 1; o < 16; o <<= 1) lpart[reg] += __shfl_xor(lpart[reg], o, 64);
        float inv = 1.f / lpart[reg];
        int i = i0 + w * 16 + quad * 4 + reg;
        bf16* orow = O + ((size_t)(b * 1024 + i)) * 512 + h * 64;
#pragma unroll
        for (int dt = 0; dt < 4; ++dt)
            orow[dt * 16 + col] = f2bf(oacc[dt][reg] * inv);
    }
}

// =============================================================================
extern "C" void kernel_launch(void* const* d_in, const int* in_sizes, int n_in,
                              void* d_out, int out_size, void* d_ws, size_t ws_size,
                              hipStream_t stream)
{
    const void* x_in     = d_in[0];
    const void* rpe      = d_in[1];
    const void* g_attn   = d_in[2];
    const void* null_kv  = d_in[3];
    const void* Wq       = d_in[4];
    const void* Wkv      = d_in[5];
    const void* Wo       = d_in[6];
    const void* g_attn_o = d_in[7];
    const void* g_ff     = d_in[8];
    const void* W1       = d_in[9];
    const void* W2       = d_in[10];
    const void* g_final  = d_in[11];
    const void* W_proj   = d_in[12];

    char* wp = (char*)d_ws;
    auto alloc = [&](size_t bytes) {
        char* p = wp; wp += (bytes + 255) & ~(size_t)255; return p;
    };
    float* xf    = (float*)alloc(4096ull * 512 * 4);
    bf16*  xn    = (bf16*) alloc(4096ull * 512 * 2);
    bf16*  tb    = (bf16*) alloc(4096ull * 512 * 2);
    bf16*  ub    = (bf16*) alloc(4096ull * 4096 * 2);
    bf16*  Kb    = (bf16*) alloc(4ull * 1088 * 64 * 2);
    bf16*  Vtb   = (bf16*) alloc(4ull * 64 * 1088 * 2);
    float* btab  = (float*)alloc(8ull * 1025 * 4);
    float2* rtab = (float2*)alloc(16384ull * 8);
    int*   dfl   = (int*)  alloc(256);
    bf16*  WqkvT = (bf16*) alloc(6ull * 640 * 512 * 2);
    bf16*  WoT   = (bf16*) alloc(6ull * 512 * 512 * 2);
    bf16*  W1T   = (bf16*) alloc(6ull * 4096 * 512 * 2);
    bf16*  W2T   = (bf16*) alloc(6ull * 512 * 2048 * 2);
    bf16*  WpT   = (bf16*) alloc(512ull * 512 * 2);
    // aliased into ub (16,777,216 elems; all dead before gemm256_silu writes ub)
    bf16*  qkvb  = ub;                        // 2,621,440 elems
    bf16*  Qb    = ub + 2621440;              // 2,097,152
    bf16*  ob    = ub + 4718592;              // 2,097,152

    detect_k<<<1, 256, 0, stream>>>((const unsigned short*)x_in, dfl);
    transpose2_k<<<dim3(16, 16, 6),  dim3(32, 8), 0, stream>>>(Wq, WqkvT, 512, 512, 512ull*512, 640ull*512, dfl);
    transpose2_k<<<dim3(4, 16, 6),   dim3(32, 8), 0, stream>>>(Wkv, WqkvT + 512ull*512, 512, 128, 512ull*128, 640ull*512, dfl);
    transpose2_k<<<dim3(16, 16, 6),  dim3(32, 8), 0, stream>>>(Wo, WoT, 512, 512, 512ull*512, 512ull*512, dfl);
    transposeW1_k<<<dim3(128, 16, 6), dim3(32, 8), 0, stream>>>(W1, W1T, dfl);
    transpose2_k<<<dim3(16, 64, 6),  dim3(32, 8), 0, stream>>>(W2, W2T, 2048, 512, 2048ull*512, 2048ull*512, dfl);
    transpose2_k<<<dim3(16, 16, 1),  dim3(32, 8), 0, stream>>>(W_proj, WpT, 512, 512, 512ull*512, 512ull*512, dfl);
    bias_k<<<33, 256, 0, stream>>>(rpe, dfl, btab);
    rotab_k<<<64, 256, 0, stream>>>(rtab);
    xinit_ln_k<<<1024, 256, 0, stream>>>(x_in, g_attn, dfl, xf, xn);

    for (int l = 0; l < 6; ++l) {
        gemm64<<<dim3(64, 5), 256, 0, stream>>>(xn, WqkvT + (size_t)l * 640 * 512, qkvb, 4096, 640, 512, 512);
        qkvprep_k<<<3136, 256, 0, stream>>>(qkvb, null_kv, l * 128, dfl, rtab, Qb, Kb, Vtb);
        attn_mfma<<<dim3(32, 16), 256, 0, stream>>>(Qb, Kb, Vtb, btab, ob);
        gemm64<<<dim3(64, 4), 256, 0, stream>>>(ob, WoT + (size_t)l * 512 * 512, tb, 4096, 512, 512, 512);
        addln_ln_k<<<1024, 256, 0, stream>>>(tb, g_attn_o, l * 512, g_ff, l * 512, dfl, xf, xn);
        gemm256_silu<<<dim3(16, 16), 512, 0, stream>>>(xn, W1T + (size_t)l * 4096 * 512, ub, 512, 512);
        gemm64<<<dim3(64, 4), 256, 0, stream>>>(ub, W2T + (size_t)l * 512 * 2048, tb, 4096, 512, 2048, 2048);
        if (l < 5)
            add_ln_k<<<1024, 256, 0, stream>>>(tb, g_attn, (l + 1) * 512, dfl, 0, xf, xn);
        else
            add_ln_k<<<1024, 256, 0, stream>>>(tb, g_final, 0, dfl, 1, xf, xn);
    }
    gemm64_out<<<dim3(64, 4), 256, 0, stream>>>(xn, WpT, d_out, 4096, 512, 512, 512, dfl);
}

// Round 6
// 852.167 us; speedup vs baseline: 1.4743x; 1.0514x over previous
//
#include <hip/hip_runtime.h>
#include <hip/hip_bf16.h>
#include <cmath>

using bf16 = __hip_bfloat16;
typedef __bf16 v8bf __attribute__((ext_vector_type(8)));
typedef __bf16 v4bf __attribute__((ext_vector_type(4)));
typedef float  v4f  __attribute__((ext_vector_type(4)));

__device__ __forceinline__ float bf2f(bf16 x) { return __bfloat162float(x); }
__device__ __forceinline__ bf16  f2bf(float x) { return __float2bfloat16(x); }
__device__ __forceinline__ __bf16 tobf(float x) {
    bf16 h = __float2bfloat16(x);
    return __builtin_bit_cast(__bf16, h);
}

// async global->LDS, 16B per lane (lds dest = wave-uniform base + lane*16)
__device__ __forceinline__ void gll16(const bf16* g, bf16* l) {
    __builtin_amdgcn_global_load_lds(
        (const __attribute__((address_space(1))) unsigned int*)g,
        (__attribute__((address_space(3))) unsigned int*)l, 16, 0, 0);
}

__device__ __forceinline__ float ldin(const void* p, size_t i, int isf32) {
    if (isf32) return ((const float*)p)[i];
    return bf2f(((const bf16*)p)[i]);
}

// flag-dtype vector load of 8 consecutive elements
__device__ __forceinline__ void ld8(const void* p, size_t base, int f, float v[8]) {
    if (f) {
        const float* pf = (const float*)p + base;
        float4 a = *(const float4*)pf, b = *(const float4*)(pf + 4);
        v[0]=a.x; v[1]=a.y; v[2]=a.z; v[3]=a.w;
        v[4]=b.x; v[5]=b.y; v[6]=b.z; v[7]=b.w;
    } else {
        v8bf a = *(const v8bf*)((const bf16*)p + base);
#pragma unroll
        for (int j = 0; j < 8; ++j) v[j] = (float)a[j];
    }
}

__device__ __forceinline__ float wave_sum(float v) {
#pragma unroll
    for (int o = 32; o > 0; o >>= 1) v += __shfl_xor(v, o, 64);
    return v;
}
__device__ __forceinline__ float wave_max(float v) {
#pragma unroll
    for (int o = 32; o > 0; o >>= 1) v = fmaxf(v, __shfl_xor(v, o, 64));
    return v;
}

// ---------------- dtype detector -------------------------------------------
__global__ void detect_k(const unsigned short* __restrict__ x, int* __restrict__ flag)
{
    __shared__ int s;
    int t = threadIdx.x;
    if (t == 0) s = 0;
    __syncthreads();
    int bad = 0;
    for (int i = t; i < 4096; i += 256) {
        int e = (x[i] >> 7) & 0xFF;
        if (e >= 147) bad++;
    }
    atomicAdd(&s, bad);
    __syncthreads();
    if (t == 0) *flag = (s > 64) ? 1 : 0;
}

// ============ 256x256 / BK=64 / 8-wave double-buffered GEMM + SiLU ===========
// 2-phase pipeline: stage K-tile t+1 into buf^1 (async global_load_lds) BEFORE
// computing K-tile t from buf; the single __syncthreads() per tile drains
// vmcnt (stage complete) + lgkmcnt (reads complete).
// Swizzle (both-sides, rule #21): 16B-granule g within a 128B row is stored at
// linear LDS slot but sourced from global granule g^(row&7); ds_read applies
// the same XOR.
// BT is the PERMUTED W1^T (a/gate interleave, groups of 64 rows = 32 a + 32
// gate): each wave's 64-col span is exactly one group; acc[mt][nt] (nt<2)
// pairs with acc[mt][nt+2] as (a, gate). U is 4096x2048.
__global__ __launch_bounds__(512, 2)
void gemm256_silu(const bf16* __restrict__ A, const bf16* __restrict__ BT,
                  bf16* __restrict__ U, int K, int lda)
{
    __shared__ bf16 As[2][256 * 64];
    __shared__ bf16 Bs[2][256 * 64];
    const int t = threadIdx.x;            // 0..511
    const int lane = t & 63;
    const int wave = t >> 6;              // 0..7  (2 M x 4 N)
    const int wm = (wave >> 2) * 128;
    const int wn = (wave & 3) * 64;
    const int bm = blockIdx.x * 256;
    const int bn = blockIdx.y * 256;
    const int fr = lane & 15;
    const int quad = lane >> 4;

    v4f acc[8][4];
#pragma unroll
    for (int i = 0; i < 8; ++i)
#pragma unroll
        for (int j = 0; j < 4; ++j) { v4f z = {0.f, 0.f, 0.f, 0.f}; acc[i][j] = z; }

    auto stage = [&](int buf, int k0) {
#pragma unroll
        for (int r = 0; r < 4; ++r) {
            int c = t + 512 * r;
            int row = c >> 3;
            int g = (c & 7) ^ (row & 7);
            gll16(A + (size_t)(bm + row) * lda + k0 + g * 8, &As[buf][c * 8]);
            gll16(BT + (size_t)(bn + row) * K + k0 + g * 8, &Bs[buf][c * 8]);
        }
    };

    stage(0, 0);
    __syncthreads();
    const int nb = K >> 6;                 // K/64 tiles
    for (int kt = 0; kt < nb; ++kt) {
        const int buf = kt & 1;
        if (kt + 1 < nb) stage(buf ^ 1, (kt + 1) * 64);
#pragma unroll
        for (int ks = 0; ks < 2; ++ks) {
            v8bf af[8], bfr[4];
            const int gk = ((ks * 4 + quad) ^ (fr & 7)) * 8;
#pragma unroll
            for (int mt = 0; mt < 8; ++mt)
                af[mt] = *(const v8bf*)(&As[buf][(wm + mt * 16 + fr) * 64 + gk]);
#pragma unroll
            for (int nt = 0; nt < 4; ++nt)
                bfr[nt] = *(const v8bf*)(&Bs[buf][(wn + nt * 16 + fr) * 64 + gk]);
#pragma unroll
            for (int mt = 0; mt < 8; ++mt)
#pragma unroll
                for (int nt = 0; nt < 4; ++nt)
                    acc[mt][nt] = __builtin_amdgcn_mfma_f32_16x16x32_bf16(
                        af[mt], bfr[nt], acc[mt][nt], 0, 0, 0);
        }
        __syncthreads();                   // drains stage (vmcnt) + reads done
    }

    const int r0 = quad * 4;
    const int gbase = ((bn + wn) >> 6) * 32;
#pragma unroll
    for (int mt = 0; mt < 8; ++mt)
#pragma unroll
        for (int nt = 0; nt < 2; ++nt)
#pragma unroll
            for (int r = 0; r < 4; ++r) {
                int row = bm + wm + mt * 16 + r0 + r;
                int col = gbase + nt * 16 + fr;
                float a  = acc[mt][nt][r];
                float gg = acc[mt][nt + 2][r];
                U[(size_t)row * 2048 + col] = f2bf(a * (gg / (1.f + __expf(-gg))));
            }
}

// ======== MFMA GEMM 64x128 / BK=64 double-buffered (async LDS staging) =======
// Regime: grid = 1 block/CU (1 wave/SIMD) -> no cross-block overlap, so the
// old single-buffer BK=32 loop exposed full load latency every barrier.
// Depth-1 prefetch (stage kt+1 before computing kt) + BK=64 (half the
// barriers) brings the per-interval cost to ~max(load, compute).
// Swizzle identical to gemm256_silu (granule g ^ (row&7), both sides).
__global__ __launch_bounds__(256)
void gemm64(const bf16* __restrict__ A, const bf16* __restrict__ BT,
            bf16* __restrict__ C, int M, int N, int K, int lda)
{
    __shared__ bf16 As[2][64 * 64];
    __shared__ bf16 Bs[2][128 * 64];
    const int t = threadIdx.x;
    const int lane = t & 63;
    const int wave = t >> 6;
    const int wm = (wave >> 1) * 32;
    const int wn = (wave & 1) * 64;
    const int bm = blockIdx.x * 64;
    const int bn = blockIdx.y * 128;
    const int fr = lane & 15;
    const int quad = lane >> 4;

    v4f acc[2][4];
#pragma unroll
    for (int i = 0; i < 2; ++i)
#pragma unroll
        for (int j = 0; j < 4; ++j) { v4f z = {0.f, 0.f, 0.f, 0.f}; acc[i][j] = z; }

    auto stage = [&](int buf, int k0) {
#pragma unroll
        for (int r = 0; r < 2; ++r) {            // A: 64x64 = 512 granules
            int c = t + 256 * r;
            int row = c >> 3;
            int g = (c & 7) ^ (row & 7);
            gll16(A + (size_t)(bm + row) * lda + k0 + g * 8, &As[buf][c * 8]);
        }
#pragma unroll
        for (int r = 0; r < 4; ++r) {            // B: 128x64 = 1024 granules
            int c = t + 256 * r;
            int row = c >> 3;
            int g = (c & 7) ^ (row & 7);
            gll16(BT + (size_t)(bn + row) * K + k0 + g * 8, &Bs[buf][c * 8]);
        }
    };

    stage(0, 0);
    __syncthreads();
    const int nb = K >> 6;
    for (int kt = 0; kt < nb; ++kt) {
        const int buf = kt & 1;
        if (kt + 1 < nb) stage(buf ^ 1, (kt + 1) * 64);
#pragma unroll
        for (int ks = 0; ks < 2; ++ks) {
            v8bf af[2], bfr[4];
            const int gk = ((ks * 4 + quad) ^ (fr & 7)) * 8;
#pragma unroll
            for (int mt = 0; mt < 2; ++mt)
                af[mt] = *(const v8bf*)(&As[buf][(wm + mt * 16 + fr) * 64 + gk]);
#pragma unroll
            for (int nt = 0; nt < 4; ++nt)
                bfr[nt] = *(const v8bf*)(&Bs[buf][(wn + nt * 16 + fr) * 64 + gk]);
#pragma unroll
            for (int mt = 0; mt < 2; ++mt)
#pragma unroll
                for (int nt = 0; nt < 4; ++nt)
                    acc[mt][nt] = __builtin_amdgcn_mfma_f32_16x16x32_bf16(
                        af[mt], bfr[nt], acc[mt][nt], 0, 0, 0);
        }
        __syncthreads();
    }
    const int r0 = quad * 4;
#pragma unroll
    for (int mt = 0; mt < 2; ++mt)
#pragma unroll
        for (int nt = 0; nt < 4; ++nt)
#pragma unroll
            for (int r = 0; r < 4; ++r) {
                int row = bm + wm + mt * 16 + r0 + r;
                int col = bn + wn + nt * 16 + fr;
                C[(size_t)row * N + col] = f2bf(acc[mt][nt][r]);
            }
}

// ---- gemm64 (BK=64 dbuf) with flag-selected output dtype (final proj) -------
__global__ __launch_bounds__(256)
void gemm64_out(const bf16* __restrict__ A, const bf16* __restrict__ BT,
                void* __restrict__ C, int M, int N, int K, int lda,
                const int* __restrict__ flag)
{
    __shared__ bf16 As[2][64 * 64];
    __shared__ bf16 Bs[2][128 * 64];
    const int f = *flag;
    const int t = threadIdx.x;
    const int lane = t & 63;
    const int wave = t >> 6;
    const int wm = (wave >> 1) * 32;
    const int wn = (wave & 1) * 64;
    const int bm = blockIdx.x * 64;
    const int bn = blockIdx.y * 128;
    const int fr = lane & 15;
    const int quad = lane >> 4;

    v4f acc[2][4];
#pragma unroll
    for (int i = 0; i < 2; ++i)
#pragma unroll
        for (int j = 0; j < 4; ++j) { v4f z = {0.f, 0.f, 0.f, 0.f}; acc[i][j] = z; }

    auto stage = [&](int buf, int k0) {
#pragma unroll
        for (int r = 0; r < 2; ++r) {
            int c = t + 256 * r;
            int row = c >> 3;
            int g = (c & 7) ^ (row & 7);
            gll16(A + (size_t)(bm + row) * lda + k0 + g * 8, &As[buf][c * 8]);
        }
#pragma unroll
        for (int r = 0; r < 4; ++r) {
            int c = t + 256 * r;
            int row = c >> 3;
            int g = (c & 7) ^ (row & 7);
            gll16(BT + (size_t)(bn + row) * K + k0 + g * 8, &Bs[buf][c * 8]);
        }
    };

    stage(0, 0);
    __syncthreads();
    const int nb = K >> 6;
    for (int kt = 0; kt < nb; ++kt) {
        const int buf = kt & 1;
        if (kt + 1 < nb) stage(buf ^ 1, (kt + 1) * 64);
#pragma unroll
        for (int ks = 0; ks < 2; ++ks) {
            v8bf af[2], bfr[4];
            const int gk = ((ks * 4 + quad) ^ (fr & 7)) * 8;
#pragma unroll
            for (int mt = 0; mt < 2; ++mt)
                af[mt] = *(const v8bf*)(&As[buf][(wm + mt * 16 + fr) * 64 + gk]);
#pragma unroll
            for (int nt = 0; nt < 4; ++nt)
                bfr[nt] = *(const v8bf*)(&Bs[buf][(wn + nt * 16 + fr) * 64 + gk]);
#pragma unroll
            for (int mt = 0; mt < 2; ++mt)
#pragma unroll
                for (int nt = 0; nt < 4; ++nt)
                    acc[mt][nt] = __builtin_amdgcn_mfma_f32_16x16x32_bf16(
                        af[mt], bfr[nt], acc[mt][nt], 0, 0, 0);
        }
        __syncthreads();
    }
    const int r0 = quad * 4;
#pragma unroll
    for (int mt = 0; mt < 2; ++mt)
#pragma unroll
        for (int nt = 0; nt < 4; ++nt)
#pragma unroll
            for (int r = 0; r < 4; ++r) {
                int row = bm + wm + mt * 16 + r0 + r;
                int col = bn + wn + nt * 16 + fr;
                if (f) ((float*)C)[(size_t)row * N + col] = acc[mt][nt][r];
                else   ((bf16*)C)[(size_t)row * N + col] = f2bf(acc[mt][nt][r]);
            }
}

// ---------------- transpose w/ separate z-strides ----------------------------
__global__ __launch_bounds__(256)
void transpose2_k(const void* __restrict__ in, bf16* __restrict__ out, int R, int C,
                  size_t inZ, size_t outZ, const int* __restrict__ flag)
{
    __shared__ bf16 tile[32][33];
    int f = *flag;
    size_t ioff = (size_t)blockIdx.z * inZ;
    bf16* dst = out + (size_t)blockIdx.z * outZ;
    int c0 = blockIdx.x * 32, r0 = blockIdx.y * 32;
    int tx = threadIdx.x, ty = threadIdx.y;
#pragma unroll
    for (int i = 0; i < 32; i += 8)
        tile[ty + i][tx] = f2bf(ldin(in, ioff + (size_t)(r0 + ty + i) * C + c0 + tx, f));
    __syncthreads();
#pragma unroll
    for (int i = 0; i < 32; i += 8)
        dst[(size_t)(c0 + ty + i) * R + r0 + tx] = tile[tx][ty + i];
}

// ---------------- W1 transpose with a/gate interleave permutation ------------
// out row j' for orig col j: j<2048 (a): j' = (j>>5)*64 + (j&31);
// j>=2048 (gate): j' = ((j-2048)>>5)*64 + 32 + (j&31).
__global__ __launch_bounds__(256)
void transposeW1_k(const void* __restrict__ in, bf16* __restrict__ out,
                   const int* __restrict__ flag)
{
    __shared__ bf16 tile[32][33];
    int f = *flag;
    size_t ioff = (size_t)blockIdx.z * (512ull * 4096);
    bf16* dst = out + (size_t)blockIdx.z * (512ull * 4096);
    int c0 = blockIdx.x * 32, r0 = blockIdx.y * 32;
    int tx = threadIdx.x, ty = threadIdx.y;
#pragma unroll
    for (int i = 0; i < 32; i += 8)
        tile[ty + i][tx] = f2bf(ldin(in, ioff + (size_t)(r0 + ty + i) * 4096 + c0 + tx, f));
    __syncthreads();
#pragma unroll
    for (int i = 0; i < 32; i += 8) {
        int j = c0 + ty + i;
        int jp = (j < 2048) ? (((j >> 5) << 6) | (j & 31))
                            : ((((j - 2048) >> 5) << 6) | 32 | (j & 31));
        dst[(size_t)jp * 512 + r0 + tx] = tile[tx][ty + i];
    }
}

// ---------------- x = in; xn = LN(x)*g  (one row per WAVE, no barriers) ------
__global__ __launch_bounds__(256)
void xinit_ln_k(const void* __restrict__ in, const void* __restrict__ g,
                const int* __restrict__ flag, float* __restrict__ x, bf16* __restrict__ xn)
{
    int f = *flag;
    int row = blockIdx.x * 4 + (threadIdx.x >> 6);
    int lane = threadIdx.x & 63;
    int c0 = lane * 8;
    float v[8];
    ld8(in, (size_t)row * 512 + c0, f, v);
    // persist x as f32
    float* xr = x + (size_t)row * 512 + c0;
    *(float4*)xr       = make_float4(v[0], v[1], v[2], v[3]);
    *(float4*)(xr + 4) = make_float4(v[4], v[5], v[6], v[7]);
    float s = 0.f;
#pragma unroll
    for (int j = 0; j < 8; ++j) s += v[j];
    float mean = wave_sum(s) * (1.f / 512.f);
    float q = 0.f;
#pragma unroll
    for (int j = 0; j < 8; ++j) { float d = v[j] - mean; q += d * d; }
    float var = wave_sum(q) * (1.f / 512.f);
    float rstd = rsqrtf(var + 1e-5f);
    float gv[8];
    ld8(g, c0, f, gv);
    v8bf o;
#pragma unroll
    for (int j = 0; j < 8; ++j) o[j] = tobf((v[j] - mean) * rstd * gv[j]);
    *(v8bf*)(xn + (size_t)row * 512 + c0) = o;
}

// ------ x += LN(t)*g1 ; xn = LN(x)*g2  (one row per WAVE, no barriers) -------
__global__ __launch_bounds__(256)
void addln_ln_k(const bf16* __restrict__ tin, const void* __restrict__ g1, int g1off,
                const void* __restrict__ g2, int g2off, const int* __restrict__ flag,
                float* __restrict__ x, bf16* __restrict__ xn)
{
    int f = *flag;
    int row = blockIdx.x * 4 + (threadIdx.x >> 6);
    int lane = threadIdx.x & 63;
    int c0 = lane * 8;
    float tv[8];
    {
        v8bf a = *(const v8bf*)(tin + (size_t)row * 512 + c0);
#pragma unroll
        for (int j = 0; j < 8; ++j) tv[j] = (float)a[j];
    }
    float s = 0.f;
#pragma unroll
    for (int j = 0; j < 8; ++j) s += tv[j];
    float mean = wave_sum(s) * (1.f / 512.f);
    float q = 0.f;
#pragma unroll
    for (int j = 0; j < 8; ++j) { float d = tv[j] - mean; q += d * d; }
    float var = wave_sum(q) * (1.f / 512.f);
    float rstd = rsqrtf(var + 1e-5f);
    float g1v[8];
    ld8(g1, (size_t)g1off + c0, f, g1v);
    float* xr = x + (size_t)row * 512 + c0;
    float4 xa = *(float4*)xr, xb = *(float4*)(xr + 4);
    float nx[8] = {xa.x, xa.y, xa.z, xa.w, xb.x, xb.y, xb.z, xb.w};
#pragma unroll
    for (int j = 0; j < 8; ++j) nx[j] += (tv[j] - mean) * rstd * g1v[j];
    *(float4*)xr       = make_float4(nx[0], nx[1], nx[2], nx[3]);
    *(float4*)(xr + 4) = make_float4(nx[4], nx[5], nx[6], nx[7]);
    float s2 = 0.f;
#pragma unroll
    for (int j = 0; j < 8; ++j) s2 += nx[j];
    float mean2 = wave_sum(s2) * (1.f / 512.f);
    float q2 = 0.f;
#pragma unroll
    for (int j = 0; j < 8; ++j) { float e = nx[j] - mean2; q2 += e * e; }
    float var2 = wave_sum(q2) * (1.f / 512.f);
    float rstd2 = rsqrtf(var2 + 1e-5f);
    float g2v[8];
    ld8(g2, (size_t)g2off + c0, f, g2v);
    v8bf o;
#pragma unroll
    for (int j = 0; j < 8; ++j) o[j] = tobf((nx[j] - mean2) * rstd2 * g2v[j]);
    *(v8bf*)(xn + (size_t)row * 512 + c0) = o;
}

// -- x += t ; xn = (stable? stableLN : LN)(x)*g  (one row per WAVE) -----------
__global__ __launch_bounds__(256)
void add_ln_k(const bf16* __restrict__ tin, const void* __restrict__ g, int goff,
              const int* __restrict__ flag, int stable,
              float* __restrict__ x, bf16* __restrict__ xn)
{
    int f = *flag;
    int row = blockIdx.x * 4 + (threadIdx.x >> 6);
    int lane = threadIdx.x & 63;
    int c0 = lane * 8;
    float nx[8];
    {
        v8bf a = *(const v8bf*)(tin + (size_t)row * 512 + c0);
        float* xr = x + (size_t)row * 512 + c0;
        float4 xa = *(float4*)xr, xb = *(float4*)(xr + 4);
        float xv[8] = {xa.x, xa.y, xa.z, xa.w, xb.x, xb.y, xb.z, xb.w};
#pragma unroll
        for (int j = 0; j < 8; ++j) nx[j] = xv[j] + (float)a[j];
        *(float4*)xr       = make_float4(nx[0], nx[1], nx[2], nx[3]);
        *(float4*)(xr + 4) = make_float4(nx[4], nx[5], nx[6], nx[7]);
    }
    float v[8];
#pragma unroll
    for (int j = 0; j < 8; ++j) v[j] = nx[j];
    if (stable) {
        float m = v[0];
#pragma unroll
        for (int j = 1; j < 8; ++j) m = fmaxf(m, v[j]);
        float mx = wave_max(m);
#pragma unroll
        for (int j = 0; j < 8; ++j) v[j] /= mx;
    }
    float s = 0.f;
#pragma unroll
    for (int j = 0; j < 8; ++j) s += v[j];
    float mean = wave_sum(s) * (1.f / 512.f);
    float q = 0.f;
#pragma unroll
    for (int j = 0; j < 8; ++j) { float d = v[j] - mean; q += d * d; }
    float var = wave_sum(q) * (1.f / 512.f);
    float rstd = rsqrtf(var + 1e-5f);
    float gv[8];
    ld8(g, (size_t)goff + c0, f, gv);
    v8bf o;
#pragma unroll
    for (int j = 0; j < 8; ++j) o[j] = tobf((v[j] - mean) * rstd * gv[j]);
    *(v8bf*)(xn + (size_t)row * 512 + c0) = o;
}

// ---------------- rotary cos/sin table: tab[n*16+p] = (cos, sin) -------------
__global__ __launch_bounds__(256)
void rotab_k(float2* __restrict__ tab)
{
    int idx = blockIdx.x * 256 + threadIdx.x;
    if (idx >= 16384) return;
    int n = idx >> 4, p = idx & 15;
    float ang = (float)n * expf((float)p * -0.5756462732f);
    tab[idx] = make_float2(cosf(ang), sinf(ang));
}

// ---------------- rel-pos bias table (pre-offset by -16: fixed softmax max) --
// qn,kn are l2-normalized to norm 4 => s = qn.kn <= 16 (Cauchy-Schwarz), and
// |bias| << 1, so exp(s + bias - 16) <= ~1.11. Softmax is shift-invariant, so
// folding the -16 here lets attention skip online-max tracking entirely.
__global__ __launch_bounds__(256)
void bias_k(const void* __restrict__ rpe, const int* __restrict__ flag, float* __restrict__ tab)
{
    int f = *flag;
    int idx = blockIdx.x * 256 + threadIdx.x;
    if (idx >= 8 * 1025) return;
    int h = idx / 1025, dist = idx % 1025;
    int bkt;
    if (dist < 16) bkt = dist;
    else {
        bkt = 16 + (int)(logf((float)dist / 16.f) / logf(8.f) * 16.f);
        if (bkt > 31) bkt = 31;
    }
    tab[idx] = ldin(rpe, bkt * 8 + h, f) - 16.f;
}

// ---------------- merged q + k/v prep (qkv stride 640, rotary via table) -----
// blocks [0,2048): q rows, 16 per block (4/wave, 16 lanes x 4 els each).
// blocks [2048,3136): k/v rows j in [0,1088) x b (4352, 4/block, 1/wave).
__global__ __launch_bounds__(256)
void qkvprep_k(const bf16* __restrict__ qkv, const void* __restrict__ nkv, int nkoff,
               const int* __restrict__ flag, const float2* __restrict__ rtab,
               bf16* __restrict__ Q, bf16* __restrict__ K, bf16* __restrict__ Vt)
{
    int t = threadIdx.x, lane = t & 63;
    int bid = blockIdx.x;
    if (bid < 2048) {
        int rid = bid * 16 + (t >> 4);            // one row per 16-lane group
        int h = rid & 7;
        int n = (rid >> 3) & 1023;
        int b = rid >> 13;
        int g16 = t & 15;
        int d0 = g16 * 4;
        v4bf a = *(const v4bf*)(qkv + (size_t)((b << 10) | n) * 640 + h * 64 + d0);
        float v[4];
#pragma unroll
        for (int j = 0; j < 4; ++j) v[j] = (float)a[j] * 16.f;
        if (d0 < 32) {                            // rotary, pairs in-lane
            float4 cs = *(const float4*)((const float*)rtab + (size_t)n * 32 + (size_t)(d0 >> 1) * 2);
            float r0 = v[0] * cs.x - v[1] * cs.y;
            float r1 = v[1] * cs.x + v[0] * cs.y;
            float r2 = v[2] * cs.z - v[3] * cs.w;
            float r3 = v[3] * cs.z + v[2] * cs.w;
            v[0] = r0; v[1] = r1; v[2] = r2; v[3] = r3;
        }
        float ss = v[0]*v[0] + v[1]*v[1] + v[2]*v[2] + v[3]*v[3];
#pragma unroll
        for (int o = 1; o < 16; o <<= 1) ss += __shfl_xor(ss, o, 64);
        float sc = 4.f / fmaxf(sqrtf(ss), 1e-12f);
        v4bf ov;
#pragma unroll
        for (int j = 0; j < 4; ++j) ov[j] = tobf(v[j] * sc);
        *(v4bf*)(Q + (((size_t)(b * 8 + h)) * 1024 + n) * 64 + d0) = ov;
    } else {
        int f = *flag;
        int rid = (bid - 2048) * 4 + (t >> 6);
        if (rid >= 4 * 1088) return;
        int j = rid % 1088;
        int b = rid / 1088;
        if (j >= 1025) {
            K[((size_t)b * 1088 + j) * 64 + lane] = f2bf(0.f);
            Vt[((size_t)b * 64 + lane) * 1088 + j] = f2bf(0.f);
            return;
        }
        float kv, vv;
        if (j == 0) {
            kv = ldin(nkv, nkoff + lane, f);
            vv = ldin(nkv, nkoff + 64 + lane, f);
        } else {
            int n = j - 1;
            const bf16* src = qkv + (size_t)(b * 1024 + n) * 640 + 512;
            kv = bf2f(src[lane]);
            vv = bf2f(src[64 + lane]);
            if (lane < 32) {
                float2 cs = rtab[n * 16 + (lane >> 1)];
                float other = __shfl_xor(kv, 1, 64);
                float rot = (lane & 1) ? other : -other;
                kv = kv * cs.x + rot * cs.y;
            }
        }
        float nrm = sqrtf(wave_sum(kv * kv));
        kv = kv / fmaxf(nrm, 1e-12f) * 4.f;
        K[((size_t)b * 1088 + j) * 64 + lane] = f2bf(kv);
        Vt[((size_t)b * 64 + lane) * 1088 + j] = f2bf(vv);
    }
}

// ---------------- MFMA flash attention, NO SPLIT, FIXED-MAX softmax ----------
// grid (B*H=32, 16 qtiles), block 256 = 4 waves (16 q-rows each). Each block
// walks all its K/V chunks (longest tiles dispatched first). Bias table is
// pre-offset by -16 so no online max / rescale: p = exp(s + bias'), l is a
// per-lane f32 partial reduced once at the end; output normalized in-register
// (f32 throughout) and written directly -- no partials, no combine pass.
__global__ __launch_bounds__(256)
void attn_mfma(const bf16* __restrict__ Q, const bf16* __restrict__ Kg,
               const bf16* __restrict__ Vtg, const float* __restrict__ bias,
               bf16* __restrict__ O)
{
    __shared__ bf16 Ks[64][72];
    __shared__ bf16 Vts[64][72];
    __shared__ bf16 Ps[4][16][72];
    __shared__ float bs[1088];
    const int bh = blockIdx.x, b = bh >> 3, h = bh & 7;
    const int yy = (int)gridDim.y - 1 - (int)blockIdx.y;   // longest first
    const int i0 = yy * 64;
    const int t = threadIdx.x, lane = t & 63, w = t >> 6;
    const int col = lane & 15, quad = lane >> 4, fk = quad * 8;
    const float* bt = bias + h * 1025;
    const bf16* Kb = Kg + (size_t)b * 1088 * 64;
    const bf16* Vb = Vtg + (size_t)b * 64 * 1088;

    // stage bias row into LDS: dist range needed is [0, i0+63]
    for (int idx = t; idx < i0 + 64; idx += 256) bs[idx] = bt[idx];

    v8bf qf[2];
    const bf16* qrow = Q + ((size_t)bh * 1024 + i0 + w * 16 + col) * 64;
    qf[0] = *(const v8bf*)(qrow + fk);
    qf[1] = *(const v8bf*)(qrow + 32 + fk);

    v4f oacc[4];
#pragma unroll
    for (int dt = 0; dt < 4; ++dt) { v4f z = {0.f,0.f,0.f,0.f}; oacc[dt] = z; }
    float lpart[4] = {0.f, 0.f, 0.f, 0.f};

    const int nch = yy + 2;
    const int rr0 = t >> 3, co0 = (t & 7) * 8;          // rep 0 staging coords
    const int rr1 = (t + 256) >> 3, co1 = co0;          // rep 1 staging coords

    v8bf kr[2], vr[2];
    {
        kr[0] = *(const v8bf*)(Kb + (size_t)rr0 * 64 + co0);
        vr[0] = *(const v8bf*)(Vb + (size_t)rr0 * 1088 + co0);
        kr[1] = *(const v8bf*)(Kb + (size_t)rr1 * 64 + co1);
        vr[1] = *(const v8bf*)(Vb + (size_t)rr1 * 1088 + co1);
    }

    for (int ch = 0; ch < nch; ++ch) {
        const int j0 = ch * 64;
        __syncthreads();                                 // prev compute done w/ LDS
        *(v8bf*)(&Ks[rr0][co0])  = kr[0];
        *(v8bf*)(&Vts[rr0][co0]) = vr[0];
        *(v8bf*)(&Ks[rr1][co1])  = kr[1];
        *(v8bf*)(&Vts[rr1][co1]) = vr[1];
        if (ch + 1 < nch) {                              // prefetch next chunk
            int j0n = (ch + 1) * 64;
            kr[0] = *(const v8bf*)(Kb + (size_t)(j0n + rr0) * 64 + co0);
            vr[0] = *(const v8bf*)(Vb + (size_t)rr0 * 1088 + j0n + co0);
            kr[1] = *(const v8bf*)(Kb + (size_t)(j0n + rr1) * 64 + co1);
            vr[1] = *(const v8bf*)(Vb + (size_t)rr1 * 1088 + j0n + co1);
        }
        __syncthreads();

        // QK^T
        v4f sreg[4];
#pragma unroll
        for (int nt = 0; nt < 4; ++nt) {
            v4f z = {0.f,0.f,0.f,0.f};
            v8bf kf0 = *(const v8bf*)(&Ks[nt * 16 + col][fk]);
            v8bf kf1 = *(const v8bf*)(&Ks[nt * 16 + col][32 + fk]);
            z = __builtin_amdgcn_mfma_f32_16x16x32_bf16(qf[0], kf0, z, 0, 0, 0);
            z = __builtin_amdgcn_mfma_f32_16x16x32_bf16(qf[1], kf1, z, 0, 0, 0);
            sreg[nt] = z;
        }

        // p = exp(s + bias - 16); no max tracking, no cross-lane ops.
        if (ch < yy) {
            // fully-interior chunk: no causal/pad mask, dist always >= 1
#pragma unroll
            for (int reg = 0; reg < 4; ++reg) {
                int i = i0 + w * 16 + quad * 4 + reg;
                int dbase = i - j0 - col;
#pragma unroll
                for (int nt = 0; nt < 4; ++nt) {
                    float pp = __expf(sreg[nt][reg] + bs[dbase - nt * 16]);
                    lpart[reg] += pp;
                    Ps[w][quad * 4 + reg][nt * 16 + col] = f2bf(pp);
                }
            }
        } else {
#pragma unroll
            for (int reg = 0; reg < 4; ++reg) {
                int i = i0 + w * 16 + quad * 4 + reg;
#pragma unroll
                for (int nt = 0; nt < 4; ++nt) {
                    int j = j0 + nt * 16 + col;
                    float pp = 0.f;
                    if (j <= i + 1 && j < 1025) {
                        int dist = i - j; if (dist < 0) dist = 0;
                        pp = __expf(sreg[nt][reg] + bs[dist]);
                    }
                    lpart[reg] += pp;
                    Ps[w][quad * 4 + reg][nt * 16 + col] = f2bf(pp);
                }
            }
        }

        // PV
        v8bf pf[2];
        pf[0] = *(const v8bf*)(&Ps[w][col][fk]);
        pf[1] = *(const v8bf*)(&Ps[w][col][32 + fk]);
#pragma unroll
        for (int dt = 0; dt < 4; ++dt) {
#pragma unroll
            for (int ks = 0; ks < 2; ++ks) {
                v8bf vf = *(const v8bf*)(&Vts[dt * 16 + col][ks * 32 + fk]);
                oacc[dt] = __builtin_amdgcn_mfma_f32_16x16x32_bf16(pf[ks], vf, oacc[dt], 0, 0, 0);
            }
        }
    }

    // single deferred l reduction (16 cols per row) + normalized direct write
#pragma unroll
    for (int reg = 0; reg < 4; ++reg) {
#pragma unroll
        for (int o = 1; o < 16; o <<= 1) lpart[reg] += __shfl_xor(lpart[reg], o, 64);
        float inv = 1.f / lpart[reg];
        int i = i0 + w * 16 + quad * 4 + reg;
        bf16* orow = O + ((size_t)(b * 1024 + i)) * 512 + h * 64;
#pragma unroll
        for (int dt = 0; dt < 4; ++dt)
            orow[dt * 16 + col] = f2bf(oacc[dt][reg] * inv);
    }
}

// =============================================================================
extern "C" void kernel_launch(void* const* d_in, const int* in_sizes, int n_in,
                              void* d_out, int out_size, void* d_ws, size_t ws_size,
                              hipStream_t stream)
{
    const void* x_in     = d_in[0];
    const void* rpe      = d_in[1];
    const void* g_attn   = d_in[2];
    const void* null_kv  = d_in[3];
    const void* Wq       = d_in[4];
    const void* Wkv      = d_in[5];
    const void* Wo       = d_in[6];
    const void* g_attn_o = d_in[7];
    const void* g_ff     = d_in[8];
    const void* W1       = d_in[9];
    const void* W2       = d_in[10];
    const void* g_final  = d_in[11];
    const void* W_proj   = d_in[12];

    char* wp = (char*)d_ws;
    auto alloc = [&](size_t bytes) {
        char* p = wp; wp += (bytes + 255) & ~(size_t)255; return p;
    };
    float* xf    = (float*)alloc(4096ull * 512 * 4);
    bf16*  xn    = (bf16*) alloc(4096ull * 512 * 2);
    bf16*  tb    = (bf16*) alloc(4096ull * 512 * 2);
    bf16*  ub    = (bf16*) alloc(4096ull * 4096 * 2);
    bf16*  Kb    = (bf16*) alloc(4ull * 1088 * 64 * 2);
    bf16*  Vtb   = (bf16*) alloc(4ull * 64 * 1088 * 2);
    float* btab  = (float*)alloc(8ull * 1025 * 4);
    float2* rtab = (float2*)alloc(16384ull * 8);
    int*   dfl   = (int*)  alloc(256);
    bf16*  WqkvT = (bf16*) alloc(6ull * 640 * 512 * 2);
    bf16*  WoT   = (bf16*) alloc(6ull * 512 * 512 * 2);
    bf16*  W1T   = (bf16*) alloc(6ull * 4096 * 512 * 2);
    bf16*  W2T   = (bf16*) alloc(6ull * 512 * 2048 * 2);
    bf16*  WpT   = (bf16*) alloc(512ull * 512 * 2);
    // aliased into ub (16,777,216 elems; all dead before gemm256_silu writes ub)
    bf16*  qkvb  = ub;                        // 2,621,440 elems
    bf16*  Qb    = ub + 2621440;              // 2,097,152
    bf16*  ob    = ub + 4718592;              // 2,097,152

    detect_k<<<1, 256, 0, stream>>>((const unsigned short*)x_in, dfl);
    transpose2_k<<<dim3(16, 16, 6),  dim3(32, 8), 0, stream>>>(Wq, WqkvT, 512, 512, 512ull*512, 640ull*512, dfl);
    transpose2_k<<<dim3(4, 16, 6),   dim3(32, 8), 0, stream>>>(Wkv, WqkvT + 512ull*512, 512, 128, 512ull*128, 640ull*512, dfl);
    transpose2_k<<<dim3(16, 16, 6),  dim3(32, 8), 0, stream>>>(Wo, WoT, 512, 512, 512ull*512, 512ull*512, dfl);
    transposeW1_k<<<dim3(128, 16, 6), dim3(32, 8), 0, stream>>>(W1, W1T, dfl);
    transpose2_k<<<dim3(16, 64, 6),  dim3(32, 8), 0, stream>>>(W2, W2T, 2048, 512, 2048ull*512, 2048ull*512, dfl);
    transpose2_k<<<dim3(16, 16, 1),  dim3(32, 8), 0, stream>>>(W_proj, WpT, 512, 512, 512ull*512, 512ull*512, dfl);
    bias_k<<<33, 256, 0, stream>>>(rpe, dfl, btab);
    rotab_k<<<64, 256, 0, stream>>>(rtab);
    xinit_ln_k<<<1024, 256, 0, stream>>>(x_in, g_attn, dfl, xf, xn);

    for (int l = 0; l < 6; ++l) {
        gemm64<<<dim3(64, 5), 256, 0, stream>>>(xn, WqkvT + (size_t)l * 640 * 512, qkvb, 4096, 640, 512, 512);
        qkvprep_k<<<3136, 256, 0, stream>>>(qkvb, null_kv, l * 128, dfl, rtab, Qb, Kb, Vtb);
        attn_mfma<<<dim3(32, 16), 256, 0, stream>>>(Qb, Kb, Vtb, btab, ob);
        gemm64<<<dim3(64, 4), 256, 0, stream>>>(ob, WoT + (size_t)l * 512 * 512, tb, 4096, 512, 512, 512);
        addln_ln_k<<<1024, 256, 0, stream>>>(tb, g_attn_o, l * 512, g_ff, l * 512, dfl, xf, xn);
        gemm256_silu<<<dim3(16, 16), 512, 0, stream>>>(xn, W1T + (size_t)l * 4096 * 512, ub, 512, 512);
        gemm64<<<dim3(64, 4), 256, 0, stream>>>(ub, W2T + (size_t)l * 512 * 2048, tb, 4096, 512, 2048, 2048);
        if (l < 5)
            add_ln_k<<<1024, 256, 0, stream>>>(tb, g_attn, (l + 1) * 512, dfl, 0, xf, xn);
        else
            add_ln_k<<<1024, 256, 0, stream>>>(tb, g_final, 0, dfl, 1, xf, xn);
    }
    gemm64_out<<<dim3(64, 4), 256, 0, stream>>>(xn, WpT, d_out, 4096, 512, 512, 512, dfl);
}

// Round 7
// 808.563 us; speedup vs baseline: 1.5538x; 1.0539x over previous
//
#include <hip/hip_runtime.h>
#include <hip/hip_bf16.h>
#include <cmath>

using bf16 = __hip_bfloat16;
typedef __bf16 v8bf __attribute__((ext_vector_type(8)));
typedef __bf16 v4bf __attribute__((ext_vector_type(4)));
typedef float  v4f  __attribute__((ext_vector_type(4)));

__device__ __forceinline__ float bf2f(bf16 x) { return __bfloat162float(x); }
__device__ __forceinline__ bf16  f2bf(float x) { return __float2bfloat16(x); }
__device__ __forceinline__ __bf16 tobf(float x) {
    bf16 h = __float2bfloat16(x);
    return __builtin_bit_cast(__bf16, h);
}

// async global->LDS, 16B per lane (lds dest = wave-uniform base + lane*16)
__device__ __forceinline__ void gll16(const bf16* g, bf16* l) {
    __builtin_amdgcn_global_load_lds(
        (const __attribute__((address_space(1))) unsigned int*)g,
        (__attribute__((address_space(3))) unsigned int*)l, 16, 0, 0);
}

__device__ __forceinline__ float ldin(const void* p, size_t i, int isf32) {
    if (isf32) return ((const float*)p)[i];
    return bf2f(((const bf16*)p)[i]);
}

// flag-dtype vector load of 8 consecutive elements
__device__ __forceinline__ void ld8(const void* p, size_t base, int f, float v[8]) {
    if (f) {
        const float* pf = (const float*)p + base;
        float4 a = *(const float4*)pf, b = *(const float4*)(pf + 4);
        v[0]=a.x; v[1]=a.y; v[2]=a.z; v[3]=a.w;
        v[4]=b.x; v[5]=b.y; v[6]=b.z; v[7]=b.w;
    } else {
        v8bf a = *(const v8bf*)((const bf16*)p + base);
#pragma unroll
        for (int j = 0; j < 8; ++j) v[j] = (float)a[j];
    }
}

__device__ __forceinline__ float wave_sum(float v) {
#pragma unroll
    for (int o = 32; o > 0; o >>= 1) v += __shfl_xor(v, o, 64);
    return v;
}
__device__ __forceinline__ float wave_max(float v) {
#pragma unroll
    for (int o = 32; o > 0; o >>= 1) v = fmaxf(v, __shfl_xor(v, o, 64));
    return v;
}

// ---------------- dtype detector -------------------------------------------
__global__ void detect_k(const unsigned short* __restrict__ x, int* __restrict__ flag)
{
    __shared__ int s;
    int t = threadIdx.x;
    if (t == 0) s = 0;
    __syncthreads();
    int bad = 0;
    for (int i = t; i < 4096; i += 256) {
        int e = (x[i] >> 7) & 0xFF;
        if (e >= 147) bad++;
    }
    atomicAdd(&s, bad);
    __syncthreads();
    if (t == 0) *flag = (s > 64) ? 1 : 0;
}

// ============ 256x256 / BK=64 / 8-wave double-buffered GEMM + SiLU ===========
// 2-phase pipeline: stage K-tile t+1 into buf^1 (async global_load_lds) BEFORE
// computing K-tile t from buf; the single __syncthreads() per tile drains
// vmcnt (stage complete) + lgkmcnt (reads complete).
// Swizzle (both-sides, rule #21): 16B-granule g within a 128B row is stored at
// linear LDS slot but sourced from global granule g^(row&7); ds_read applies
// the same XOR.
// BT is the PERMUTED W1^T (a/gate interleave, groups of 64 rows = 32 a + 32
// gate): each wave's 64-col span is exactly one group; acc[mt][nt] (nt<2)
// pairs with acc[mt][nt+2] as (a, gate). U is 4096x2048.
__global__ __launch_bounds__(512, 2)
void gemm256_silu(const bf16* __restrict__ A, const bf16* __restrict__ BT,
                  bf16* __restrict__ U, int K, int lda)
{
    __shared__ bf16 As[2][256 * 64];
    __shared__ bf16 Bs[2][256 * 64];
    const int t = threadIdx.x;            // 0..511
    const int lane = t & 63;
    const int wave = t >> 6;              // 0..7  (2 M x 4 N)
    const int wm = (wave >> 2) * 128;
    const int wn = (wave & 3) * 64;
    const int bm = blockIdx.x * 256;
    const int bn = blockIdx.y * 256;
    const int fr = lane & 15;
    const int quad = lane >> 4;

    v4f acc[8][4];
#pragma unroll
    for (int i = 0; i < 8; ++i)
#pragma unroll
        for (int j = 0; j < 4; ++j) { v4f z = {0.f, 0.f, 0.f, 0.f}; acc[i][j] = z; }

    auto stage = [&](int buf, int k0) {
#pragma unroll
        for (int r = 0; r < 4; ++r) {
            int c = t + 512 * r;
            int row = c >> 3;
            int g = (c & 7) ^ (row & 7);
            gll16(A + (size_t)(bm + row) * lda + k0 + g * 8, &As[buf][c * 8]);
            gll16(BT + (size_t)(bn + row) * K + k0 + g * 8, &Bs[buf][c * 8]);
        }
    };

    stage(0, 0);
    __syncthreads();
    const int nb = K >> 6;                 // K/64 tiles
    for (int kt = 0; kt < nb; ++kt) {
        const int buf = kt & 1;
        if (kt + 1 < nb) stage(buf ^ 1, (kt + 1) * 64);
#pragma unroll
        for (int ks = 0; ks < 2; ++ks) {
            v8bf af[8], bfr[4];
            const int gk = ((ks * 4 + quad) ^ (fr & 7)) * 8;
#pragma unroll
            for (int mt = 0; mt < 8; ++mt)
                af[mt] = *(const v8bf*)(&As[buf][(wm + mt * 16 + fr) * 64 + gk]);
#pragma unroll
            for (int nt = 0; nt < 4; ++nt)
                bfr[nt] = *(const v8bf*)(&Bs[buf][(wn + nt * 16 + fr) * 64 + gk]);
#pragma unroll
            for (int mt = 0; mt < 8; ++mt)
#pragma unroll
                for (int nt = 0; nt < 4; ++nt)
                    acc[mt][nt] = __builtin_amdgcn_mfma_f32_16x16x32_bf16(
                        af[mt], bfr[nt], acc[mt][nt], 0, 0, 0);
        }
        __syncthreads();                   // drains stage (vmcnt) + reads done
    }

    const int r0 = quad * 4;
    const int gbase = ((bn + wn) >> 6) * 32;
#pragma unroll
    for (int mt = 0; mt < 8; ++mt)
#pragma unroll
        for (int nt = 0; nt < 2; ++nt)
#pragma unroll
            for (int r = 0; r < 4; ++r) {
                int row = bm + wm + mt * 16 + r0 + r;
                int col = gbase + nt * 16 + fr;
                float a  = acc[mt][nt][r];
                float gg = acc[mt][nt + 2][r];
                U[(size_t)row * 2048 + col] = f2bf(a * (gg / (1.f + __expf(-gg))));
            }
}

// ========= MFMA GEMM 64x64 / BK=64 double-buffered (async LDS staging) =======
// Tile shrunk 64x128 -> 64x64 so the grid doubles (512-640 blocks = 2-2.5
// blocks/CU): cross-block wave overlap (m114) hides the per-tile barrier
// drain that in-block depth-1 prefetch cannot (syncthreads drains all vmcnt).
// Swizzle identical to gemm256_silu (granule g ^ (row&7), both sides).
__global__ __launch_bounds__(256)
void gemm64(const bf16* __restrict__ A, const bf16* __restrict__ BT,
            bf16* __restrict__ C, int M, int N, int K, int lda)
{
    __shared__ bf16 As[2][64 * 64];
    __shared__ bf16 Bs[2][64 * 64];
    const int t = threadIdx.x;
    const int lane = t & 63;
    const int wave = t >> 6;
    const int wm = (wave >> 1) * 32;
    const int wn = (wave & 1) * 32;
    const int bm = blockIdx.x * 64;
    const int bn = blockIdx.y * 64;
    const int fr = lane & 15;
    const int quad = lane >> 4;

    v4f acc[2][2];
#pragma unroll
    for (int i = 0; i < 2; ++i)
#pragma unroll
        for (int j = 0; j < 2; ++j) { v4f z = {0.f, 0.f, 0.f, 0.f}; acc[i][j] = z; }

    auto stage = [&](int buf, int k0) {
#pragma unroll
        for (int r = 0; r < 2; ++r) {            // A,B: 64x64 = 512 granules each
            int c = t + 256 * r;
            int row = c >> 3;
            int g = (c & 7) ^ (row & 7);
            gll16(A + (size_t)(bm + row) * lda + k0 + g * 8, &As[buf][c * 8]);
            gll16(BT + (size_t)(bn + row) * K + k0 + g * 8, &Bs[buf][c * 8]);
        }
    };

    stage(0, 0);
    __syncthreads();
    const int nb = K >> 6;
    for (int kt = 0; kt < nb; ++kt) {
        const int buf = kt & 1;
        if (kt + 1 < nb) stage(buf ^ 1, (kt + 1) * 64);
#pragma unroll
        for (int ks = 0; ks < 2; ++ks) {
            v8bf af[2], bfr[2];
            const int gk = ((ks * 4 + quad) ^ (fr & 7)) * 8;
#pragma unroll
            for (int mt = 0; mt < 2; ++mt)
                af[mt] = *(const v8bf*)(&As[buf][(wm + mt * 16 + fr) * 64 + gk]);
#pragma unroll
            for (int nt = 0; nt < 2; ++nt)
                bfr[nt] = *(const v8bf*)(&Bs[buf][(wn + nt * 16 + fr) * 64 + gk]);
#pragma unroll
            for (int mt = 0; mt < 2; ++mt)
#pragma unroll
                for (int nt = 0; nt < 2; ++nt)
                    acc[mt][nt] = __builtin_amdgcn_mfma_f32_16x16x32_bf16(
                        af[mt], bfr[nt], acc[mt][nt], 0, 0, 0);
        }
        __syncthreads();
    }
    const int r0 = quad * 4;
#pragma unroll
    for (int mt = 0; mt < 2; ++mt)
#pragma unroll
        for (int nt = 0; nt < 2; ++nt)
#pragma unroll
            for (int r = 0; r < 4; ++r) {
                int row = bm + wm + mt * 16 + r0 + r;
                int col = bn + wn + nt * 16 + fr;
                C[(size_t)row * N + col] = f2bf(acc[mt][nt][r]);
            }
}

// ---- gemm64 (64x64, BK=64 dbuf) with flag-selected output dtype -------------
__global__ __launch_bounds__(256)
void gemm64_out(const bf16* __restrict__ A, const bf16* __restrict__ BT,
                void* __restrict__ C, int M, int N, int K, int lda,
                const int* __restrict__ flag)
{
    __shared__ bf16 As[2][64 * 64];
    __shared__ bf16 Bs[2][64 * 64];
    const int f = *flag;
    const int t = threadIdx.x;
    const int lane = t & 63;
    const int wave = t >> 6;
    const int wm = (wave >> 1) * 32;
    const int wn = (wave & 1) * 32;
    const int bm = blockIdx.x * 64;
    const int bn = blockIdx.y * 64;
    const int fr = lane & 15;
    const int quad = lane >> 4;

    v4f acc[2][2];
#pragma unroll
    for (int i = 0; i < 2; ++i)
#pragma unroll
        for (int j = 0; j < 2; ++j) { v4f z = {0.f, 0.f, 0.f, 0.f}; acc[i][j] = z; }

    auto stage = [&](int buf, int k0) {
#pragma unroll
        for (int r = 0; r < 2; ++r) {
            int c = t + 256 * r;
            int row = c >> 3;
            int g = (c & 7) ^ (row & 7);
            gll16(A + (size_t)(bm + row) * lda + k0 + g * 8, &As[buf][c * 8]);
            gll16(BT + (size_t)(bn + row) * K + k0 + g * 8, &Bs[buf][c * 8]);
        }
    };

    stage(0, 0);
    __syncthreads();
    const int nb = K >> 6;
    for (int kt = 0; kt < nb; ++kt) {
        const int buf = kt & 1;
        if (kt + 1 < nb) stage(buf ^ 1, (kt + 1) * 64);
#pragma unroll
        for (int ks = 0; ks < 2; ++ks) {
            v8bf af[2], bfr[2];
            const int gk = ((ks * 4 + quad) ^ (fr & 7)) * 8;
#pragma unroll
            for (int mt = 0; mt < 2; ++mt)
                af[mt] = *(const v8bf*)(&As[buf][(wm + mt * 16 + fr) * 64 + gk]);
#pragma unroll
            for (int nt = 0; nt < 2; ++nt)
                bfr[nt] = *(const v8bf*)(&Bs[buf][(wn + nt * 16 + fr) * 64 + gk]);
#pragma unroll
            for (int mt = 0; mt < 2; ++mt)
#pragma unroll
                for (int nt = 0; nt < 2; ++nt)
                    acc[mt][nt] = __builtin_amdgcn_mfma_f32_16x16x32_bf16(
                        af[mt], bfr[nt], acc[mt][nt], 0, 0, 0);
        }
        __syncthreads();
    }
    const int r0 = quad * 4;
#pragma unroll
    for (int mt = 0; mt < 2; ++mt)
#pragma unroll
        for (int nt = 0; nt < 2; ++nt)
#pragma unroll
            for (int r = 0; r < 4; ++r) {
                int row = bm + wm + mt * 16 + r0 + r;
                int col = bn + wn + nt * 16 + fr;
                if (f) ((float*)C)[(size_t)row * N + col] = acc[mt][nt][r];
                else   ((bf16*)C)[(size_t)row * N + col] = f2bf(acc[mt][nt][r]);
            }
}

// ---------------- transpose w/ separate z-strides ----------------------------
__global__ __launch_bounds__(256)
void transpose2_k(const void* __restrict__ in, bf16* __restrict__ out, int R, int C,
                  size_t inZ, size_t outZ, const int* __restrict__ flag)
{
    __shared__ bf16 tile[32][33];
    int f = *flag;
    size_t ioff = (size_t)blockIdx.z * inZ;
    bf16* dst = out + (size_t)blockIdx.z * outZ;
    int c0 = blockIdx.x * 32, r0 = blockIdx.y * 32;
    int tx = threadIdx.x, ty = threadIdx.y;
#pragma unroll
    for (int i = 0; i < 32; i += 8)
        tile[ty + i][tx] = f2bf(ldin(in, ioff + (size_t)(r0 + ty + i) * C + c0 + tx, f));
    __syncthreads();
#pragma unroll
    for (int i = 0; i < 32; i += 8)
        dst[(size_t)(c0 + ty + i) * R + r0 + tx] = tile[tx][ty + i];
}

// ---------------- W1 transpose with a/gate interleave permutation ------------
// out row j' for orig col j: j<2048 (a): j' = (j>>5)*64 + (j&31);
// j>=2048 (gate): j' = ((j-2048)>>5)*64 + 32 + (j&31).
__global__ __launch_bounds__(256)
void transposeW1_k(const void* __restrict__ in, bf16* __restrict__ out,
                   const int* __restrict__ flag)
{
    __shared__ bf16 tile[32][33];
    int f = *flag;
    size_t ioff = (size_t)blockIdx.z * (512ull * 4096);
    bf16* dst = out + (size_t)blockIdx.z * (512ull * 4096);
    int c0 = blockIdx.x * 32, r0 = blockIdx.y * 32;
    int tx = threadIdx.x, ty = threadIdx.y;
#pragma unroll
    for (int i = 0; i < 32; i += 8)
        tile[ty + i][tx] = f2bf(ldin(in, ioff + (size_t)(r0 + ty + i) * 4096 + c0 + tx, f));
    __syncthreads();
#pragma unroll
    for (int i = 0; i < 32; i += 8) {
        int j = c0 + ty + i;
        int jp = (j < 2048) ? (((j >> 5) << 6) | (j & 31))
                            : ((((j - 2048) >> 5) << 6) | 32 | (j & 31));
        dst[(size_t)jp * 512 + r0 + tx] = tile[tx][ty + i];
    }
}

// ---------------- x = in; xn = LN(x)*g  (one row per WAVE, no barriers) ------
__global__ __launch_bounds__(256)
void xinit_ln_k(const void* __restrict__ in, const void* __restrict__ g,
                const int* __restrict__ flag, float* __restrict__ x, bf16* __restrict__ xn)
{
    int f = *flag;
    int row = blockIdx.x * 4 + (threadIdx.x >> 6);
    int lane = threadIdx.x & 63;
    int c0 = lane * 8;
    float v[8];
    ld8(in, (size_t)row * 512 + c0, f, v);
    // persist x as f32
    float* xr = x + (size_t)row * 512 + c0;
    *(float4*)xr       = make_float4(v[0], v[1], v[2], v[3]);
    *(float4*)(xr + 4) = make_float4(v[4], v[5], v[6], v[7]);
    float s = 0.f;
#pragma unroll
    for (int j = 0; j < 8; ++j) s += v[j];
    float mean = wave_sum(s) * (1.f / 512.f);
    float q = 0.f;
#pragma unroll
    for (int j = 0; j < 8; ++j) { float d = v[j] - mean; q += d * d; }
    float var = wave_sum(q) * (1.f / 512.f);
    float rstd = rsqrtf(var + 1e-5f);
    float gv[8];
    ld8(g, c0, f, gv);
    v8bf o;
#pragma unroll
    for (int j = 0; j < 8; ++j) o[j] = tobf((v[j] - mean) * rstd * gv[j]);
    *(v8bf*)(xn + (size_t)row * 512 + c0) = o;
}

// ------ x += LN(t)*g1 ; xn = LN(x)*g2  (one row per WAVE, no barriers) -------
__global__ __launch_bounds__(256)
void addln_ln_k(const bf16* __restrict__ tin, const void* __restrict__ g1, int g1off,
                const void* __restrict__ g2, int g2off, const int* __restrict__ flag,
                float* __restrict__ x, bf16* __restrict__ xn)
{
    int f = *flag;
    int row = blockIdx.x * 4 + (threadIdx.x >> 6);
    int lane = threadIdx.x & 63;
    int c0 = lane * 8;
    float tv[8];
    {
        v8bf a = *(const v8bf*)(tin + (size_t)row * 512 + c0);
#pragma unroll
        for (int j = 0; j < 8; ++j) tv[j] = (float)a[j];
    }
    float s = 0.f;
#pragma unroll
    for (int j = 0; j < 8; ++j) s += tv[j];
    float mean = wave_sum(s) * (1.f / 512.f);
    float q = 0.f;
#pragma unroll
    for (int j = 0; j < 8; ++j) { float d = tv[j] - mean; q += d * d; }
    float var = wave_sum(q) * (1.f / 512.f);
    float rstd = rsqrtf(var + 1e-5f);
    float g1v[8];
    ld8(g1, (size_t)g1off + c0, f, g1v);
    float* xr = x + (size_t)row * 512 + c0;
    float4 xa = *(float4*)xr, xb = *(float4*)(xr + 4);
    float nx[8] = {xa.x, xa.y, xa.z, xa.w, xb.x, xb.y, xb.z, xb.w};
#pragma unroll
    for (int j = 0; j < 8; ++j) nx[j] += (tv[j] - mean) * rstd * g1v[j];
    *(float4*)xr       = make_float4(nx[0], nx[1], nx[2], nx[3]);
    *(float4*)(xr + 4) = make_float4(nx[4], nx[5], nx[6], nx[7]);
    float s2 = 0.f;
#pragma unroll
    for (int j = 0; j < 8; ++j) s2 += nx[j];
    float mean2 = wave_sum(s2) * (1.f / 512.f);
    float q2 = 0.f;
#pragma unroll
    for (int j = 0; j < 8; ++j) { float e = nx[j] - mean2; q2 += e * e; }
    float var2 = wave_sum(q2) * (1.f / 512.f);
    float rstd2 = rsqrtf(var2 + 1e-5f);
    float g2v[8];
    ld8(g2, (size_t)g2off + c0, f, g2v);
    v8bf o;
#pragma unroll
    for (int j = 0; j < 8; ++j) o[j] = tobf((nx[j] - mean2) * rstd2 * g2v[j]);
    *(v8bf*)(xn + (size_t)row * 512 + c0) = o;
}

// -- x += t ; xn = (stable? stableLN : LN)(x)*g  (one row per WAVE) -----------
__global__ __launch_bounds__(256)
void add_ln_k(const bf16* __restrict__ tin, const void* __restrict__ g, int goff,
              const int* __restrict__ flag, int stable,
              float* __restrict__ x, bf16* __restrict__ xn)
{
    int f = *flag;
    int row = blockIdx.x * 4 + (threadIdx.x >> 6);
    int lane = threadIdx.x & 63;
    int c0 = lane * 8;
    float nx[8];
    {
        v8bf a = *(const v8bf*)(tin + (size_t)row * 512 + c0);
        float* xr = x + (size_t)row * 512 + c0;
        float4 xa = *(float4*)xr, xb = *(float4*)(xr + 4);
        float xv[8] = {xa.x, xa.y, xa.z, xa.w, xb.x, xb.y, xb.z, xb.w};
#pragma unroll
        for (int j = 0; j < 8; ++j) nx[j] = xv[j] + (float)a[j];
        *(float4*)xr       = make_float4(nx[0], nx[1], nx[2], nx[3]);
        *(float4*)(xr + 4) = make_float4(nx[4], nx[5], nx[6], nx[7]);
    }
    float v[8];
#pragma unroll
    for (int j = 0; j < 8; ++j) v[j] = nx[j];
    if (stable) {
        float m = v[0];
#pragma unroll
        for (int j = 1; j < 8; ++j) m = fmaxf(m, v[j]);
        float mx = wave_max(m);
#pragma unroll
        for (int j = 0; j < 8; ++j) v[j] /= mx;
    }
    float s = 0.f;
#pragma unroll
    for (int j = 0; j < 8; ++j) s += v[j];
    float mean = wave_sum(s) * (1.f / 512.f);
    float q = 0.f;
#pragma unroll
    for (int j = 0; j < 8; ++j) { float d = v[j] - mean; q += d * d; }
    float var = wave_sum(q) * (1.f / 512.f);
    float rstd = rsqrtf(var + 1e-5f);
    float gv[8];
    ld8(g, (size_t)goff + c0, f, gv);
    v8bf o;
#pragma unroll
    for (int j = 0; j < 8; ++j) o[j] = tobf((v[j] - mean) * rstd * gv[j]);
    *(v8bf*)(xn + (size_t)row * 512 + c0) = o;
}

// ---------------- rotary cos/sin table: tab[n*16+p] = (cos, sin) -------------
__global__ __launch_bounds__(256)
void rotab_k(float2* __restrict__ tab)
{
    int idx = blockIdx.x * 256 + threadIdx.x;
    if (idx >= 16384) return;
    int n = idx >> 4, p = idx & 15;
    float ang = (float)n * expf((float)p * -0.5756462732f);
    tab[idx] = make_float2(cosf(ang), sinf(ang));
}

// ---------------- rel-pos bias table (pre-offset by -16: fixed softmax max) --
// qn,kn are l2-normalized to norm 4 => s = qn.kn <= 16 (Cauchy-Schwarz), and
// |bias| << 1, so exp(s + bias - 16) <= ~1.11. Softmax is shift-invariant, so
// folding the -16 here lets attention skip online-max tracking entirely.
__global__ __launch_bounds__(256)
void bias_k(const void* __restrict__ rpe, const int* __restrict__ flag, float* __restrict__ tab)
{
    int f = *flag;
    int idx = blockIdx.x * 256 + threadIdx.x;
    if (idx >= 8 * 1025) return;
    int h = idx / 1025, dist = idx % 1025;
    int bkt;
    if (dist < 16) bkt = dist;
    else {
        bkt = 16 + (int)(logf((float)dist / 16.f) / logf(8.f) * 16.f);
        if (bkt > 31) bkt = 31;
    }
    tab[idx] = ldin(rpe, bkt * 8 + h, f) - 16.f;
}

// ---------------- merged q + k/v prep (qkv stride 640, rotary via table) -----
// blocks [0,2048): q rows, 16 per block (4/wave, 16 lanes x 4 els each).
// blocks [2048,3136): k/v rows j in [0,1088) x b (4352, 4/block, 1/wave).
__global__ __launch_bounds__(256)
void qkvprep_k(const bf16* __restrict__ qkv, const void* __restrict__ nkv, int nkoff,
               const int* __restrict__ flag, const float2* __restrict__ rtab,
               bf16* __restrict__ Q, bf16* __restrict__ K, bf16* __restrict__ Vt)
{
    int t = threadIdx.x, lane = t & 63;
    int bid = blockIdx.x;
    if (bid < 2048) {
        int rid = bid * 16 + (t >> 4);            // one row per 16-lane group
        int h = rid & 7;
        int n = (rid >> 3) & 1023;
        int b = rid >> 13;
        int g16 = t & 15;
        int d0 = g16 * 4;
        v4bf a = *(const v4bf*)(qkv + (size_t)((b << 10) | n) * 640 + h * 64 + d0);
        float v[4];
#pragma unroll
        for (int j = 0; j < 4; ++j) v[j] = (float)a[j] * 16.f;
        if (d0 < 32) {                            // rotary, pairs in-lane
            float4 cs = *(const float4*)((const float*)rtab + (size_t)n * 32 + (size_t)(d0 >> 1) * 2);
            float r0 = v[0] * cs.x - v[1] * cs.y;
            float r1 = v[1] * cs.x + v[0] * cs.y;
            float r2 = v[2] * cs.z - v[3] * cs.w;
            float r3 = v[3] * cs.z + v[2] * cs.w;
            v[0] = r0; v[1] = r1; v[2] = r2; v[3] = r3;
        }
        float ss = v[0]*v[0] + v[1]*v[1] + v[2]*v[2] + v[3]*v[3];
#pragma unroll
        for (int o = 1; o < 16; o <<= 1) ss += __shfl_xor(ss, o, 64);
        float sc = 4.f / fmaxf(sqrtf(ss), 1e-12f);
        v4bf ov;
#pragma unroll
        for (int j = 0; j < 4; ++j) ov[j] = tobf(v[j] * sc);
        *(v4bf*)(Q + (((size_t)(b * 8 + h)) * 1024 + n) * 64 + d0) = ov;
    } else {
        int f = *flag;
        int rid = (bid - 2048) * 4 + (t >> 6);
        if (rid >= 4 * 1088) return;
        int j = rid % 1088;
        int b = rid / 1088;
        if (j >= 1025) {
            K[((size_t)b * 1088 + j) * 64 + lane] = f2bf(0.f);
            Vt[((size_t)b * 64 + lane) * 1088 + j] = f2bf(0.f);
            return;
        }
        float kv, vv;
        if (j == 0) {
            kv = ldin(nkv, nkoff + lane, f);
            vv = ldin(nkv, nkoff + 64 + lane, f);
        } else {
            int n = j - 1;
            const bf16* src = qkv + (size_t)(b * 1024 + n) * 640 + 512;
            kv = bf2f(src[lane]);
            vv = bf2f(src[64 + lane]);
            if (lane < 32) {
                float2 cs = rtab[n * 16 + (lane >> 1)];
                float other = __shfl_xor(kv, 1, 64);
                float rot = (lane & 1) ? other : -other;
                kv = kv * cs.x + rot * cs.y;
            }
        }
        float nrm = sqrtf(wave_sum(kv * kv));
        kv = kv / fmaxf(nrm, 1e-12f) * 4.f;
        K[((size_t)b * 1088 + j) * 64 + lane] = f2bf(kv);
        Vt[((size_t)b * 64 + lane) * 1088 + j] = f2bf(vv);
    }
}

// ---------------- MFMA flash attention, NO SPLIT, FIXED-MAX softmax ----------
// grid (B*H=32, 16 qtiles), block 256 = 4 waves (16 q-rows each). Each block
// walks all its K/V chunks (longest tiles dispatched first). Bias table is
// pre-offset by -16 so no online max / rescale: p = exp(s + bias'), l is a
// per-lane f32 partial reduced once at the end; output normalized in-register
// (f32 throughout) and written directly -- no partials, no combine pass.
__global__ __launch_bounds__(256)
void attn_mfma(const bf16* __restrict__ Q, const bf16* __restrict__ Kg,
               const bf16* __restrict__ Vtg, const float* __restrict__ bias,
               bf16* __restrict__ O)
{
    __shared__ bf16 Ks[64][72];
    __shared__ bf16 Vts[64][72];
    __shared__ bf16 Ps[4][16][72];
    __shared__ float bs[1088];
    const int bh = blockIdx.x, b = bh >> 3, h = bh & 7;
    const int yy = (int)gridDim.y - 1 - (int)blockIdx.y;   // longest first
    const int i0 = yy * 64;
    const int t = threadIdx.x, lane = t & 63, w = t >> 6;
    const int col = lane & 15, quad = lane >> 4, fk = quad * 8;
    const float* bt = bias + h * 1025;
    const bf16* Kb = Kg + (size_t)b * 1088 * 64;
    const bf16* Vb = Vtg + (size_t)b * 64 * 1088;

    // stage bias row into LDS: dist range needed is [0, i0+63]
    for (int idx = t; idx < i0 + 64; idx += 256) bs[idx] = bt[idx];

    v8bf qf[2];
    const bf16* qrow = Q + ((size_t)bh * 1024 + i0 + w * 16 + col) * 64;
    qf[0] = *(const v8bf*)(qrow + fk);
    qf[1] = *(const v8bf*)(qrow + 32 + fk);

    v4f oacc[4];
#pragma unroll
    for (int dt = 0; dt < 4; ++dt) { v4f z = {0.f,0.f,0.f,0.f}; oacc[dt] = z; }
    float lpart[4] = {0.f, 0.f, 0.f, 0.f};

    const int nch = yy + 2;
    const int rr0 = t >> 3, co0 = (t & 7) * 8;          // rep 0 staging coords
    const int rr1 = (t + 256) >> 3, co1 = co0;          // rep 1 staging coords

    v8bf kr[2], vr[2];
    {
        kr[0] = *(const v8bf*)(Kb + (size_t)rr0 * 64 + co0);
        vr[0] = *(const v8bf*)(Vb + (size_t)rr0 * 1088 + co0);
        kr[1] = *(const v8bf*)(Kb + (size_t)rr1 * 64 + co1);
        vr[1] = *(const v8bf*)(Vb + (size_t)rr1 * 1088 + co1);
    }

    for (int ch = 0; ch < nch; ++ch) {
        const int j0 = ch * 64;
        __syncthreads();                                 // prev compute done w/ LDS
        *(v8bf*)(&Ks[rr0][co0])  = kr[0];
        *(v8bf*)(&Vts[rr0][co0]) = vr[0];
        *(v8bf*)(&Ks[rr1][co1])  = kr[1];
        *(v8bf*)(&Vts[rr1][co1]) = vr[1];
        if (ch + 1 < nch) {                              // prefetch next chunk
            int j0n = (ch + 1) * 64;
            kr[0] = *(const v8bf*)(Kb + (size_t)(j0n + rr0) * 64 + co0);
            vr[0] = *(const v8bf*)(Vb + (size_t)rr0 * 1088 + j0n + co0);
            kr[1] = *(const v8bf*)(Kb + (size_t)(j0n + rr1) * 64 + co1);
            vr[1] = *(const v8bf*)(Vb + (size_t)rr1 * 1088 + j0n + co1);
        }
        __syncthreads();

        // QK^T
        v4f sreg[4];
#pragma unroll
        for (int nt = 0; nt < 4; ++nt) {
            v4f z = {0.f,0.f,0.f,0.f};
            v8bf kf0 = *(const v8bf*)(&Ks[nt * 16 + col][fk]);
            v8bf kf1 = *(const v8bf*)(&Ks[nt * 16 + col][32 + fk]);
            z = __builtin_amdgcn_mfma_f32_16x16x32_bf16(qf[0], kf0, z, 0, 0, 0);
            z = __builtin_amdgcn_mfma_f32_16x16x32_bf16(qf[1], kf1, z, 0, 0, 0);
            sreg[nt] = z;
        }

        // p = exp(s + bias - 16); no max tracking, no cross-lane ops.
        if (ch < yy) {
            // fully-interior chunk: no causal/pad mask, dist always >= 1
#pragma unroll
            for (int reg = 0; reg < 4; ++reg) {
                int i = i0 + w * 16 + quad * 4 + reg;
                int dbase = i - j0 - col;
#pragma unroll
                for (int nt = 0; nt < 4; ++nt) {
                    float pp = __expf(sreg[nt][reg] + bs[dbase - nt * 16]);
                    lpart[reg] += pp;
                    Ps[w][quad * 4 + reg][nt * 16 + col] = f2bf(pp);
                }
            }
        } else {
#pragma unroll
            for (int reg = 0; reg < 4; ++reg) {
                int i = i0 + w * 16 + quad * 4 + reg;
#pragma unroll
                for (int nt = 0; nt < 4; ++nt) {
                    int j = j0 + nt * 16 + col;
                    float pp = 0.f;
                    if (j <= i + 1 && j < 1025) {
                        int dist = i - j; if (dist < 0) dist = 0;
                        pp = __expf(sreg[nt][reg] + bs[dist]);
                    }
                    lpart[reg] += pp;
                    Ps[w][quad * 4 + reg][nt * 16 + col] = f2bf(pp);
                }
            }
        }

        // PV
        v8bf pf[2];
        pf[0] = *(const v8bf*)(&Ps[w][col][fk]);
        pf[1] = *(const v8bf*)(&Ps[w][col][32 + fk]);
#pragma unroll
        for (int dt = 0; dt < 4; ++dt) {
#pragma unroll
            for (int ks = 0; ks < 2; ++ks) {
                v8bf vf = *(const v8bf*)(&Vts[dt * 16 + col][ks * 32 + fk]);
                oacc[dt] = __builtin_amdgcn_mfma_f32_16x16x32_bf16(pf[ks], vf, oacc[dt], 0, 0, 0);
            }
        }
    }

    // single deferred l reduction (16 cols per row) + normalized direct write
#pragma unroll
    for (int reg = 0; reg < 4; ++reg) {
#pragma unroll
        for (int o = 1; o < 16; o <<= 1) lpart[reg] += __shfl_xor(lpart[reg], o, 64);
        float inv = 1.f / lpart[reg];
        int i = i0 + w * 16 + quad * 4 + reg;
        bf16* orow = O + ((size_t)(b * 1024 + i)) * 512 + h * 64;
#pragma unroll
        for (int dt = 0; dt < 4; ++dt)
            orow[dt * 16 + col] = f2bf(oacc[dt][reg] * inv);
    }
}

// =============================================================================
extern "C" void kernel_launch(void* const* d_in, const int* in_sizes, int n_in,
                              void* d_out, int out_size, void* d_ws, size_t ws_size,
                              hipStream_t stream)
{
    const void* x_in     = d_in[0];
    const void* rpe      = d_in[1];
    const void* g_attn   = d_in[2];
    const void* null_kv  = d_in[3];
    const void* Wq       = d_in[4];
    const void* Wkv      = d_in[5];
    const void* Wo       = d_in[6];
    const void* g_attn_o = d_in[7];
    const void* g_ff     = d_in[8];
    const void* W1       = d_in[9];
    const void* W2       = d_in[10];
    const void* g_final  = d_in[11];
    const void* W_proj   = d_in[12];

    char* wp = (char*)d_ws;
    auto alloc = [&](size_t bytes) {
        char* p = wp; wp += (bytes + 255) & ~(size_t)255; return p;
    };
    float* xf    = (float*)alloc(4096ull * 512 * 4);
    bf16*  xn    = (bf16*) alloc(4096ull * 512 * 2);
    bf16*  tb    = (bf16*) alloc(4096ull * 512 * 2);
    bf16*  ub    = (bf16*) alloc(4096ull * 4096 * 2);
    bf16*  Kb    = (bf16*) alloc(4ull * 1088 * 64 * 2);
    bf16*  Vtb   = (bf16*) alloc(4ull * 64 * 1088 * 2);
    float* btab  = (float*)alloc(8ull * 1025 * 4);
    float2* rtab = (float2*)alloc(16384ull * 8);
    int*   dfl   = (int*)  alloc(256);
    bf16*  WqkvT = (bf16*) alloc(6ull * 640 * 512 * 2);
    bf16*  WoT   = (bf16*) alloc(6ull * 512 * 512 * 2);
    bf16*  W1T   = (bf16*) alloc(6ull * 4096 * 512 * 2);
    bf16*  W2T   = (bf16*) alloc(6ull * 512 * 2048 * 2);
    bf16*  WpT   = (bf16*) alloc(512ull * 512 * 2);
    // aliased into ub (16,777,216 elems; all dead before gemm256_silu writes ub)
    bf16*  qkvb  = ub;                        // 2,621,440 elems
    bf16*  Qb    = ub + 2621440;              // 2,097,152
    bf16*  ob    = ub + 4718592;              // 2,097,152

    detect_k<<<1, 256, 0, stream>>>((const unsigned short*)x_in, dfl);
    transpose2_k<<<dim3(16, 16, 6),  dim3(32, 8), 0, stream>>>(Wq, WqkvT, 512, 512, 512ull*512, 640ull*512, dfl);
    transpose2_k<<<dim3(4, 16, 6),   dim3(32, 8), 0, stream>>>(Wkv, WqkvT + 512ull*512, 512, 128, 512ull*128, 640ull*512, dfl);
    transpose2_k<<<dim3(16, 16, 6),  dim3(32, 8), 0, stream>>>(Wo, WoT, 512, 512, 512ull*512, 512ull*512, dfl);
    transposeW1_k<<<dim3(128, 16, 6), dim3(32, 8), 0, stream>>>(W1, W1T, dfl);
    transpose2_k<<<dim3(16, 64, 6),  dim3(32, 8), 0, stream>>>(W2, W2T, 2048, 512, 2048ull*512, 2048ull*512, dfl);
    transpose2_k<<<dim3(16, 16, 1),  dim3(32, 8), 0, stream>>>(W_proj, WpT, 512, 512, 512ull*512, 512ull*512, dfl);
    bias_k<<<33, 256, 0, stream>>>(rpe, dfl, btab);
    rotab_k<<<64, 256, 0, stream>>>(rtab);
    xinit_ln_k<<<1024, 256, 0, stream>>>(x_in, g_attn, dfl, xf, xn);

    for (int l = 0; l < 6; ++l) {
        gemm64<<<dim3(64, 10), 256, 0, stream>>>(xn, WqkvT + (size_t)l * 640 * 512, qkvb, 4096, 640, 512, 512);
        qkvprep_k<<<3136, 256, 0, stream>>>(qkvb, null_kv, l * 128, dfl, rtab, Qb, Kb, Vtb);
        attn_mfma<<<dim3(32, 16), 256, 0, stream>>>(Qb, Kb, Vtb, btab, ob);
        gemm64<<<dim3(64, 8), 256, 0, stream>>>(ob, WoT + (size_t)l * 512 * 512, tb, 4096, 512, 512, 512);
        addln_ln_k<<<1024, 256, 0, stream>>>(tb, g_attn_o, l * 512, g_ff, l * 512, dfl, xf, xn);
        gemm256_silu<<<dim3(16, 16), 512, 0, stream>>>(xn, W1T + (size_t)l * 4096 * 512, ub, 512, 512);
        gemm64<<<dim3(64, 8), 256, 0, stream>>>(ub, W2T + (size_t)l * 512 * 2048, tb, 4096, 512, 2048, 2048);
        if (l < 5)
            add_ln_k<<<1024, 256, 0, stream>>>(tb, g_attn, (l + 1) * 512, dfl, 0, xf, xn);
        else
            add_ln_k<<<1024, 256, 0, stream>>>(tb, g_final, 0, dfl, 1, xf, xn);
    }
    gemm64_out<<<dim3(64, 8), 256, 0, stream>>>(xn, WpT, d_out, 4096, 512, 512, 512, dfl);
}